// Round 2
// baseline (3240.710 us; speedup 1.0000x reference)
//
#include <hip/hip_runtime.h>
#include <cstdint>
#include <cstddef>

#define NB 64      // batch
#define NN 1000    // nodes
#define NE 16000   // edges

__device__ __forceinline__ float lrelu(float x) { return x > 0.f ? x : 0.01f * x; }

// ---------------- CSR build ----------------
__global__ void k_deg(const int* __restrict__ edges, int* __restrict__ deg) {
    int e = blockIdx.x * 256 + threadIdx.x;
    if (e < NE) {
        atomicAdd(&deg[edges[e]], 1);        // src
        atomicAdd(&deg[edges[NE + e]], 1);   // dst
    }
}

__global__ void k_scan(const int* __restrict__ deg, int* __restrict__ offs) {
    __shared__ int s[1024];
    int t = threadIdx.x;
    s[t] = (t < NN) ? deg[t] : 0;
    __syncthreads();
    for (int d = 1; d < 1024; d <<= 1) {
        int v = (t >= d) ? s[t - d] : 0;
        __syncthreads();
        s[t] += v;
        __syncthreads();
    }
    if (t < NN) offs[t + 1] = s[t];
    if (t == 0) offs[0] = 0;
}

// deterministic fill, role-sorted: all src-role incidences first (edge order),
// then all dst-role incidences (edge order). Each entry stores `other` node.
__global__ void k_fill(const int* __restrict__ edges, const int* __restrict__ offs,
                       int* __restrict__ adj, int* __restrict__ cntA) {
    int n = blockIdx.x;
    int lane = threadIdx.x;  // 64 threads = 1 wave
    int base = offs[n];

    // pass 1: count src-role incidences
    int cA = 0;
    for (int e0 = 0; e0 < NE; e0 += 64) {
        int e = e0 + lane;
        int s = (e < NE) ? edges[e] : -1;
        unsigned long long ms = __ballot(s == n);
        cA += __popcll(ms);
    }
    if (lane == 0) cntA[n] = cA;

    // pass 2: fill
    unsigned long long below = (lane == 63) ? 0x7fffffffffffffffull
                                            : ((1ull << lane) - 1ull);
    int runA = 0, runB = 0;
    for (int e0 = 0; e0 < NE; e0 += 64) {
        int e = e0 + lane;
        int s = -1, d = -1;
        if (e < NE) { s = edges[e]; d = edges[NE + e]; }
        unsigned long long ms = __ballot(s == n);
        unsigned long long md = __ballot(d == n);
        if (s == n) adj[base + runA + __popcll(ms & below)] = d;           // n=src, other=dst
        if (d == n) adj[base + cA + runB + __popcll(md & below)] = s;      // n=dst, other=src
        runA += __popcll(ms);
        runB += __popcll(md);
    }
}

// ---------------- pass-0 node prep: vertices -> A,B projections ----------------
__global__ void k_prep0(const float* __restrict__ vert,
                        const float* __restrict__ xW, const float* __restrict__ xb,
                        const float* __restrict__ yW, const float* __restrict__ yb,
                        const float* __restrict__ tW, const float* __restrict__ tb,
                        const float* __restrict__ cW1, const float* __restrict__ cb1,
                        const float* __restrict__ cW2, const float* __restrict__ cb2,
                        const float* __restrict__ vW1, const float* __restrict__ vb1,
                        const float* __restrict__ vW2, const float* __restrict__ vb2,
                        const float* __restrict__ eW1, const float* __restrict__ eb1,
                        float* __restrict__ Ap, float* __restrict__ Bp) {
    int idx = blockIdx.x * blockDim.x + threadIdx.x;  // 64000 threads
    int n = idx >> 6, b = idx & 63;
    const float* vp = vert + ((size_t)b * NN + n) * 11;
    float vv[11];
#pragma unroll
    for (int i = 0; i < 11; i++) vv[i] = vp[i];

    float config[64];
#pragma unroll
    for (int half = 0; half < 2; half++) {
        float f[24];
        const float* o = vv + (half ? 6 : 3);
        {
            const float* Ws[3] = {xW, yW, tW};
            const float* bs[3] = {xb, yb, tb};
#pragma unroll
            for (int i = 0; i < 3; i++) {
                float p0 = vv[i], p1 = o[i];
#pragma unroll
                for (int c = 0; c < 8; c++)
                    f[i * 8 + c] = lrelu(Ws[i][c * 2] * p0 + Ws[i][c * 2 + 1] * p1 + bs[i][c]);
            }
        }
        float h[32];
#pragma unroll
        for (int oc = 0; oc < 32; oc++) {
            float s = cb1[oc];
#pragma unroll
            for (int c = 0; c < 24; c++) s += cW1[oc * 24 + c] * f[c];
            h[oc] = lrelu(s);
        }
#pragma unroll
        for (int oc = 0; oc < 32; oc++) {
            float s = cb2[oc];
#pragma unroll
            for (int c = 0; c < 32; c++) s += cW2[oc * 32 + c] * h[c];
            config[half * 32 + oc] = lrelu(s);
        }
    }
    float v1[32];
#pragma unroll
    for (int oc = 0; oc < 32; oc++) {
        float s = vb1[oc];
#pragma unroll
        for (int c = 0; c < 64; c++) s += vW1[oc * 64 + c] * config[c];
        v1[oc] = lrelu(s);
    }
    float vf[34];
#pragma unroll
    for (int oc = 0; oc < 32; oc++) {
        float s = vb2[oc];
#pragma unroll
        for (int c = 0; c < 32; c++) s += vW2[oc * 32 + c] * v1[c];
        vf[oc] = lrelu(s);
    }
    vf[32] = vv[9]; vf[33] = vv[10];

    size_t outb = ((size_t)n * NB + b) * 32;
#pragma unroll
    for (int oc = 0; oc < 32; oc++) {
        float sa = eb1[oc], sb = 0.f;
#pragma unroll
        for (int c = 0; c < 34; c++) {
            sa += eW1[oc * 68 + c] * vf[c];
            sb += eW1[oc * 68 + 34 + c] * vf[c];
        }
        Ap[outb + oc] = sa;
        Bp[outb + oc] = sb;
    }
}

// ---------------- per-iteration node prep: nv -> h -> A,B ----------------
__global__ void k_prep(const float* __restrict__ nv, const float* __restrict__ vert,
                       const float* __restrict__ aW1, const float* __restrict__ ab1,
                       const float* __restrict__ aW2, const float* __restrict__ ab2,
                       const float* __restrict__ eW1, const float* __restrict__ eb1,
                       float* __restrict__ Ap, float* __restrict__ Bp) {
    int idx = blockIdx.x * blockDim.x + threadIdx.x;
    int n = idx >> 6, b = idx & 63;
    const float* xp = nv + ((size_t)n * NB + b) * 32;
    float x[32];
#pragma unroll
    for (int c = 0; c < 32; c++) x[c] = xp[c];
    float h[32];
#pragma unroll
    for (int oc = 0; oc < 32; oc++) {
        float s = ab1[oc];
#pragma unroll
        for (int c = 0; c < 32; c++) s += aW1[oc * 32 + c] * x[c];
        h[oc] = lrelu(s);
    }
    float vf[34];
#pragma unroll
    for (int oc = 0; oc < 32; oc++) {
        float s = ab2[oc];
#pragma unroll
        for (int c = 0; c < 32; c++) s += aW2[oc * 32 + c] * h[c];
        vf[oc] = lrelu(s);
    }
    const float* vp = vert + ((size_t)b * NN + n) * 11;
    vf[32] = vp[9]; vf[33] = vp[10];

    size_t outb = ((size_t)n * NB + b) * 32;
#pragma unroll
    for (int oc = 0; oc < 32; oc++) {
        float sa = eb1[oc], sb = 0.f;
#pragma unroll
        for (int c = 0; c < 34; c++) {
            sa += eW1[oc * 68 + c] * vf[c];
            sb += eW1[oc * 68 + 34 + c] * vf[c];
        }
        Ap[outb + oc] = sa;
        Bp[outb + oc] = sb;
    }
}

// ---------------- edge pass: node-centric, role-split (two phases) ----------------
__global__ __launch_bounds__(256, 4) void k_edge(
    const float* __restrict__ Ap, const float* __restrict__ Bp,
    const int* __restrict__ offs, const int* __restrict__ cntA,
    const int* __restrict__ adj,
    const float* __restrict__ W2, const float* __restrict__ b2,
    float* __restrict__ nv, int pass0) {
    __shared__ float red[4][64 * 33];
    int n = blockIdx.x;
    int w = threadIdx.x >> 6;     // wave id 0..3
    int lane = threadIdx.x & 63;  // = batch b

    int off0 = offs[n], off1 = offs[n + 1];
    int mid = off0 + cntA[n];
    int deg = off1 - off0;

    float acc[32];
#pragma unroll
    for (int c = 0; c < 32; c++) acc[c] = 0.f;

    // phase 1: n is src -> h1 = lrelu(A[n] + B[other])
    {
        float base[32];
        const float* ap = Ap + ((size_t)n * NB + lane) * 32;
#pragma unroll
        for (int c = 0; c < 32; c++) base[c] = ap[c];
        for (int p = off0 + w; p < mid; p += 4) {
            int other = adj[p];
            const float* og = Bp + ((size_t)other * NB + lane) * 32;
            float h1[32];
#pragma unroll
            for (int c = 0; c < 32; c++) h1[c] = lrelu(base[c] + og[c]);
#pragma unroll
            for (int oc = 0; oc < 32; oc++) {
                float s = b2[oc];
#pragma unroll
                for (int k = 0; k < 32; k++) s += W2[oc * 32 + k] * h1[k];
                acc[oc] += lrelu(s);
            }
        }
    }
    // phase 2: n is dst -> h1 = lrelu(A[other] + B[n])
    {
        float base[32];
        const float* bp = Bp + ((size_t)n * NB + lane) * 32;
#pragma unroll
        for (int c = 0; c < 32; c++) base[c] = bp[c];
        for (int p = mid + w; p < off1; p += 4) {
            int other = adj[p];
            const float* og = Ap + ((size_t)other * NB + lane) * 32;
            float h1[32];
#pragma unroll
            for (int c = 0; c < 32; c++) h1[c] = lrelu(base[c] + og[c]);
#pragma unroll
            for (int oc = 0; oc < 32; oc++) {
                float s = b2[oc];
#pragma unroll
                for (int k = 0; k < 32; k++) s += W2[oc * 32 + k] * h1[k];
                acc[oc] += lrelu(s);
            }
        }
    }

    // cross-wave reduce via LDS (padded rows: bank-conflict-free)
#pragma unroll
    for (int c = 0; c < 32; c++) red[w][lane * 33 + c] = acc[c];
    __syncthreads();

    int t = threadIdx.x;
    size_t nb = (size_t)n * (NB * 32);
    if (deg > 0) {
        float inv = 1.f / (float)deg;
#pragma unroll
        for (int j = 0; j < 8; j++) {
            int idx = t * 8 + j;
            int bb = idx >> 5, cc = idx & 31;
            float s = red[0][bb * 33 + cc] + red[1][bb * 33 + cc] +
                      red[2][bb * 33 + cc] + red[3][bb * 33 + cc];
            s *= inv;
            if (!pass0) s += nv[nb + idx];
            nv[nb + idx] = s;
        }
    } else if (pass0) {
#pragma unroll
        for (int j = 0; j < 8; j++) nv[nb + t * 8 + j] = 0.f;
    }
}

// ---------------- final readout ----------------
__global__ void k_final(const float* __restrict__ nv,
                        const float* __restrict__ oW1, const float* __restrict__ ob1,
                        const float* __restrict__ oW2, const float* __restrict__ ob2,
                        const float* __restrict__ gW, const float* __restrict__ gb,
                        float* __restrict__ out) {
    int b = blockIdx.x;
    int t = threadIdx.x;  // 256
    float part = 0.f;
    for (int n = t; n < NN; n += 256) {
        const float* xp = nv + ((size_t)n * NB + b) * 32;
        float x[32];
#pragma unroll
        for (int c = 0; c < 32; c++) x[c] = xp[c];
        float h[32];
#pragma unroll
        for (int oc = 0; oc < 32; oc++) {
            float s = ob1[oc];
#pragma unroll
            for (int c = 0; c < 32; c++) s += oW1[oc * 32 + c] * x[c];
            h[oc] = lrelu(s);
        }
        float s = ob2[0];
#pragma unroll
        for (int k = 0; k < 32; k++) s += oW2[k] * h[k];
        part += lrelu(s) * gW[n];
    }
    __shared__ float rs[256];
    rs[t] = part;
    __syncthreads();
    for (int d = 128; d > 0; d >>= 1) {
        if (t < d) rs[t] += rs[t + d];
        __syncthreads();
    }
    if (t == 0) out[b] = 1.f / (1.f + expf(-(rs[0] + gb[0])));
}

extern "C" void kernel_launch(void* const* d_in, const int* in_sizes, int n_in,
                              void* d_out, int out_size, void* d_ws, size_t ws_size,
                              hipStream_t stream) {
    (void)in_sizes; (void)n_in; (void)out_size; (void)ws_size;
    const float* vert = (const float*)d_in[0];
    const int* edges  = (const int*)d_in[1];
    const float* xW   = (const float*)d_in[2];
    const float* xb   = (const float*)d_in[3];
    const float* yW   = (const float*)d_in[4];
    const float* yb   = (const float*)d_in[5];
    const float* tW   = (const float*)d_in[6];
    const float* tb   = (const float*)d_in[7];
    const float* cW1  = (const float*)d_in[8];
    const float* cb1  = (const float*)d_in[9];
    const float* cW2  = (const float*)d_in[10];
    const float* cb2  = (const float*)d_in[11];
    const float* vW1  = (const float*)d_in[12];
    const float* vb1  = (const float*)d_in[13];
    const float* vW2  = (const float*)d_in[14];
    const float* vb2  = (const float*)d_in[15];
    const float* eW1  = (const float*)d_in[16];
    const float* eb1  = (const float*)d_in[17];
    const float* eW2  = (const float*)d_in[18];
    const float* eb2  = (const float*)d_in[19];
    const float* aW1  = (const float*)d_in[20];
    const float* ab1  = (const float*)d_in[21];
    const float* aW2  = (const float*)d_in[22];
    const float* ab2  = (const float*)d_in[23];
    const float* oW1  = (const float*)d_in[24];
    const float* ob1  = (const float*)d_in[25];
    const float* oW2  = (const float*)d_in[26];
    const float* ob2  = (const float*)d_in[27];
    const float* gW   = (const float*)d_in[28];
    const float* gb   = (const float*)d_in[29];
    float* out = (float*)d_out;

    char* w = (char*)d_ws;
    float* Ap = (float*)(w);
    float* Bp = (float*)(w + 8u * 1024 * 1024);
    float* nv = (float*)(w + 16u * 1024 * 1024);
    int* deg  = (int*)(w + 24u * 1024 * 1024);
    int* offs = deg + 1024;
    int* cntA = offs + 1024;
    int* adj  = cntA + 1024;

    hipMemsetAsync(deg, 0, NN * sizeof(int), stream);
    k_deg<<<(NE + 255) / 256, 256, 0, stream>>>(edges, deg);
    k_scan<<<1, 1024, 0, stream>>>(deg, offs);
    k_fill<<<NN, 64, 0, stream>>>(edges, offs, adj, cntA);

    k_prep0<<<(NB * NN) / 256, 256, 0, stream>>>(vert, xW, xb, yW, yb, tW, tb,
                                                 cW1, cb1, cW2, cb2, vW1, vb1, vW2, vb2,
                                                 eW1, eb1, Ap, Bp);
    k_edge<<<NN, 256, 0, stream>>>(Ap, Bp, offs, cntA, adj, eW2, eb2, nv, 1);

    for (int it = 0; it < 5; it++) {
        k_prep<<<(NB * NN) / 256, 256, 0, stream>>>(nv, vert, aW1, ab1, aW2, ab2,
                                                    eW1, eb1, Ap, Bp);
        k_edge<<<NN, 256, 0, stream>>>(Ap, Bp, offs, cntA, adj, eW2, eb2, nv, 0);
    }

    k_final<<<NB, 256, 0, stream>>>(nv, oW1, ob1, oW2, ob2, gW, gb, out);
}

// Round 3
// 876.703 us; speedup vs baseline: 3.6965x; 3.6965x over previous
//
#include <hip/hip_runtime.h>
#include <hip/hip_bf16.h>
#include <cstdint>
#include <cstddef>

#define NB 64      // batch
#define NN 1000    // nodes
#define NE 16000   // edges

typedef __attribute__((ext_vector_type(8))) short short8;
typedef __attribute__((ext_vector_type(16))) float f32x16;

__device__ __forceinline__ float lrelu(float x) { return fmaxf(x, 0.01f * x); }

__device__ __forceinline__ float bf2f(short s) {
    unsigned int u = ((unsigned int)(unsigned short)s) << 16;
    return __builtin_bit_cast(float, u);
}
__device__ __forceinline__ short f2bf(float f) {
    __hip_bfloat16 h = __float2bfloat16(f);
    return __builtin_bit_cast(short, h);
}

union S8 { short8 v; short e[8]; };

// Fragment layout per node (2048 bf16 = 4KB):
//   value (k=oc 0..31, b 0..63) lives at:
//   kh=oc>>4, g=(oc>>3)&1, j=oc&7, bh=b>>5, bl=b&31
//   short index = n*2048 + ((kh*2+bh)*64 + g*32 + bl)*8 + j
// MFMA B-operand: lane l of fragment (kh,bh) holds k=kh*16+(l>>5)*8+j, b=bh*32+(l&31)

// ---------------- CSR build ----------------
__global__ void k_deg(const int* __restrict__ edges, int* __restrict__ deg) {
    int e = blockIdx.x * 256 + threadIdx.x;
    if (e < NE) {
        atomicAdd(&deg[edges[e]], 1);
        atomicAdd(&deg[edges[NE + e]], 1);
    }
}

__global__ void k_scan(const int* __restrict__ deg, int* __restrict__ offs) {
    __shared__ int s[1024];
    int t = threadIdx.x;
    s[t] = (t < NN) ? deg[t] : 0;
    __syncthreads();
    for (int d = 1; d < 1024; d <<= 1) {
        int v = (t >= d) ? s[t - d] : 0;
        __syncthreads();
        s[t] += v;
        __syncthreads();
    }
    if (t < NN) offs[t + 1] = s[t];
    if (t == 0) offs[0] = 0;
}

// deterministic role-sorted fill: src-role incidences first, then dst-role
__global__ void k_fill(const int* __restrict__ edges, const int* __restrict__ offs,
                       int* __restrict__ adj, int* __restrict__ cntA) {
    int n = blockIdx.x;
    int lane = threadIdx.x;
    int base = offs[n];
    int cA = 0;
    for (int e0 = 0; e0 < NE; e0 += 64) {
        int e = e0 + lane;
        int s = (e < NE) ? edges[e] : -1;
        cA += __popcll(__ballot(s == n));
    }
    if (lane == 0) cntA[n] = cA;
    unsigned long long below = (lane == 63) ? 0x7fffffffffffffffull
                                            : ((1ull << lane) - 1ull);
    int runA = 0, runB = 0;
    for (int e0 = 0; e0 < NE; e0 += 64) {
        int e = e0 + lane;
        int s = -1, d = -1;
        if (e < NE) { s = edges[e]; d = edges[NE + e]; }
        unsigned long long ms = __ballot(s == n);
        unsigned long long md = __ballot(d == n);
        if (s == n) adj[base + runA + __popcll(ms & below)] = d;
        if (d == n) adj[base + cA + runB + __popcll(md & below)] = s;
        runA += __popcll(ms);
        runB += __popcll(md);
    }
}

// store sa/sb (32 each) for (n,b) into fragment layout
__device__ __forceinline__ void store_frags(short* __restrict__ Ap, short* __restrict__ Bp,
                                            int n, int b, const float* sa, const float* sb) {
    int bh = b >> 5, bl = b & 31;
    size_t nodeb = (size_t)n * 2048;
#pragma unroll
    for (int kh = 0; kh < 2; kh++) {
#pragma unroll
        for (int g = 0; g < 2; g++) {
            size_t off = nodeb + ((size_t)(kh * 2 + bh) * 64 + g * 32 + bl) * 8;
            S8 pa, pb;
#pragma unroll
            for (int j = 0; j < 8; j++) {
                pa.e[j] = f2bf(sa[kh * 16 + g * 8 + j]);
                pb.e[j] = f2bf(sb[kh * 16 + g * 8 + j]);
            }
            *(short8*)(Ap + off) = pa.v;
            *(short8*)(Bp + off) = pb.v;
        }
    }
}

// ---------------- pass-0 node prep ----------------
__global__ void k_prep0(const float* __restrict__ vert,
                        const float* __restrict__ xW, const float* __restrict__ xb,
                        const float* __restrict__ yW, const float* __restrict__ yb,
                        const float* __restrict__ tW, const float* __restrict__ tb,
                        const float* __restrict__ cW1, const float* __restrict__ cb1,
                        const float* __restrict__ cW2, const float* __restrict__ cb2,
                        const float* __restrict__ vW1, const float* __restrict__ vb1,
                        const float* __restrict__ vW2, const float* __restrict__ vb2,
                        const float* __restrict__ eW1, const float* __restrict__ eb1,
                        short* __restrict__ Ap, short* __restrict__ Bp) {
    int idx = blockIdx.x * blockDim.x + threadIdx.x;
    int n = idx >> 6, b = idx & 63;
    const float* vp = vert + ((size_t)b * NN + n) * 11;
    float vv[11];
#pragma unroll
    for (int i = 0; i < 11; i++) vv[i] = vp[i];

    float config[64];
#pragma unroll
    for (int half = 0; half < 2; half++) {
        float f[24];
        const float* o = vv + (half ? 6 : 3);
        {
            const float* Ws[3] = {xW, yW, tW};
            const float* bs[3] = {xb, yb, tb};
#pragma unroll
            for (int i = 0; i < 3; i++) {
                float p0 = vv[i], p1 = o[i];
#pragma unroll
                for (int c = 0; c < 8; c++)
                    f[i * 8 + c] = lrelu(Ws[i][c * 2] * p0 + Ws[i][c * 2 + 1] * p1 + bs[i][c]);
            }
        }
        float h[32];
#pragma unroll
        for (int oc = 0; oc < 32; oc++) {
            float s = cb1[oc];
#pragma unroll
            for (int c = 0; c < 24; c++) s += cW1[oc * 24 + c] * f[c];
            h[oc] = lrelu(s);
        }
#pragma unroll
        for (int oc = 0; oc < 32; oc++) {
            float s = cb2[oc];
#pragma unroll
            for (int c = 0; c < 32; c++) s += cW2[oc * 32 + c] * h[c];
            config[half * 32 + oc] = lrelu(s);
        }
    }
    float v1[32];
#pragma unroll
    for (int oc = 0; oc < 32; oc++) {
        float s = vb1[oc];
#pragma unroll
        for (int c = 0; c < 64; c++) s += vW1[oc * 64 + c] * config[c];
        v1[oc] = lrelu(s);
    }
    float vf[34];
#pragma unroll
    for (int oc = 0; oc < 32; oc++) {
        float s = vb2[oc];
#pragma unroll
        for (int c = 0; c < 32; c++) s += vW2[oc * 32 + c] * v1[c];
        vf[oc] = lrelu(s);
    }
    vf[32] = vv[9]; vf[33] = vv[10];

    float sa[32], sb[32];
#pragma unroll
    for (int oc = 0; oc < 32; oc++) {
        float a = eb1[oc], bb = 0.f;
#pragma unroll
        for (int c = 0; c < 34; c++) {
            a  += eW1[oc * 68 + c] * vf[c];
            bb += eW1[oc * 68 + 34 + c] * vf[c];
        }
        sa[oc] = a; sb[oc] = bb;
    }
    store_frags(Ap, Bp, n, b, sa, sb);
}

// ---------------- per-iteration node prep ----------------
__global__ void k_prep(const float* __restrict__ nv, const float* __restrict__ vert,
                       const float* __restrict__ aW1, const float* __restrict__ ab1,
                       const float* __restrict__ aW2, const float* __restrict__ ab2,
                       const float* __restrict__ eW1, const float* __restrict__ eb1,
                       short* __restrict__ Ap, short* __restrict__ Bp) {
    int idx = blockIdx.x * blockDim.x + threadIdx.x;
    int n = idx >> 6, b = idx & 63;
    const float* xp = nv + ((size_t)n * NB + b) * 32;
    float x[32];
#pragma unroll
    for (int c = 0; c < 32; c++) x[c] = xp[c];
    float h[32];
#pragma unroll
    for (int oc = 0; oc < 32; oc++) {
        float s = ab1[oc];
#pragma unroll
        for (int c = 0; c < 32; c++) s += aW1[oc * 32 + c] * x[c];
        h[oc] = lrelu(s);
    }
    float vf[34];
#pragma unroll
    for (int oc = 0; oc < 32; oc++) {
        float s = ab2[oc];
#pragma unroll
        for (int c = 0; c < 32; c++) s += aW2[oc * 32 + c] * h[c];
        vf[oc] = lrelu(s);
    }
    const float* vp = vert + ((size_t)b * NN + n) * 11;
    vf[32] = vp[9]; vf[33] = vp[10];

    float sa[32], sb[32];
#pragma unroll
    for (int oc = 0; oc < 32; oc++) {
        float a = eb1[oc], bb = 0.f;
#pragma unroll
        for (int c = 0; c < 34; c++) {
            a  += eW1[oc * 68 + c] * vf[c];
            bb += eW1[oc * 68 + 34 + c] * vf[c];
        }
        sa[oc] = a; sb[oc] = bb;
    }
    store_frags(Ap, Bp, n, b, sa, sb);
}

// ---------------- edge pass: MFMA, node-centric, role-split ----------------
__global__ void k_edge(
    const short* __restrict__ Ap, const short* __restrict__ Bp,
    const int* __restrict__ offs, const int* __restrict__ cntA,
    const int* __restrict__ adj,
    const float* __restrict__ W2, const float* __restrict__ b2,
    float* __restrict__ nv, int pass0) {
    __shared__ float red[4][64 * 33];
    int n = blockIdx.x;
    int w = threadIdx.x >> 6;
    int lane = threadIdx.x & 63;
    int row = lane & 31, kg = lane >> 5;

    int off0 = offs[n], off1 = offs[n + 1];
    int mid = off0 + cntA[n];
    int deg = off1 - off0;

    // W2 as MFMA A-fragments: lane holds A[row][k=kh*16+kg*8+j]
    S8 w2f[2];
#pragma unroll
    for (int kh = 0; kh < 2; kh++)
#pragma unroll
        for (int j = 0; j < 8; j++)
            w2f[kh].e[j] = f2bf(W2[row * 32 + kh * 16 + kg * 8 + j]);

    // b2 gathered per C-reg: row(r) = (r&3)+8*(r>>2)+4*kg
    float b2v[16];
#pragma unroll
    for (int r = 0; r < 16; r++)
        b2v[r] = b2[(r & 3) + 8 * (r >> 2) + 4 * kg];

    f32x16 acc0 = {};
    f32x16 acc1 = {};
    const f32x16 zero = {};

#pragma unroll
    for (int phase = 0; phase < 2; phase++) {
        const short* basePtr = phase ? Bp : Ap;
        const short* ogPtr   = phase ? Ap : Bp;
        int pstart = phase ? mid : off0;
        int pend   = phase ? off1 : mid;

        // unpack this node's base fragments to f32
        float bf[4][8];
        {
            const short8* np = (const short8*)(basePtr + (size_t)n * 2048);
#pragma unroll
            for (int f = 0; f < 4; f++) {
                S8 t; t.v = np[f * 64 + lane];
#pragma unroll
                for (int j = 0; j < 8; j++) bf[f][j] = bf2f(t.e[j]);
            }
        }
        for (int p = pstart + w; p < pend; p += 4) {
            int other = adj[p];
            const short8* op = (const short8*)(ogPtr + (size_t)other * 2048);
#pragma unroll
            for (int bh = 0; bh < 2; bh++) {
                S8 h1[2];
#pragma unroll
                for (int kh = 0; kh < 2; kh++) {
                    int f = kh * 2 + bh;
                    S8 o; o.v = op[f * 64 + lane];
#pragma unroll
                    for (int j = 0; j < 8; j++) {
                        float x = bf[f][j] + bf2f(o.e[j]);
                        h1[kh].e[j] = f2bf(fmaxf(x, 0.01f * x));
                    }
                }
                f32x16 d = __builtin_amdgcn_mfma_f32_32x32x16_bf16(w2f[0].v, h1[0].v, zero, 0, 0, 0);
                d = __builtin_amdgcn_mfma_f32_32x32x16_bf16(w2f[1].v, h1[1].v, d, 0, 0, 0);
                if (bh == 0) {
#pragma unroll
                    for (int r = 0; r < 16; r++) {
                        float m = d[r] + b2v[r];
                        acc0[r] += fmaxf(m, 0.01f * m);
                    }
                } else {
#pragma unroll
                    for (int r = 0; r < 16; r++) {
                        float m = d[r] + b2v[r];
                        acc1[r] += fmaxf(m, 0.01f * m);
                    }
                }
            }
        }
    }

    // scatter C fragments to LDS in (b, oc) layout, padded stride 33
#pragma unroll
    for (int bh = 0; bh < 2; bh++) {
        int b = bh * 32 + row;
#pragma unroll
        for (int r = 0; r < 16; r++) {
            int oc = (r & 3) + 8 * (r >> 2) + 4 * kg;
            red[w][b * 33 + oc] = bh ? acc1[r] : acc0[r];
        }
    }
    __syncthreads();

    int t = threadIdx.x;
    size_t nb = (size_t)n * (NB * 32);
    if (deg > 0) {
        float inv = 1.f / (float)deg;
#pragma unroll
        for (int j = 0; j < 8; j++) {
            int idx = t * 8 + j;
            int bb = idx >> 5, cc = idx & 31;
            float s = red[0][bb * 33 + cc] + red[1][bb * 33 + cc] +
                      red[2][bb * 33 + cc] + red[3][bb * 33 + cc];
            s *= inv;
            if (!pass0) s += nv[nb + idx];
            nv[nb + idx] = s;
        }
    } else if (pass0) {
#pragma unroll
        for (int j = 0; j < 8; j++) nv[nb + t * 8 + j] = 0.f;
    }
}

// ---------------- final readout ----------------
__global__ void k_final(const float* __restrict__ nv,
                        const float* __restrict__ oW1, const float* __restrict__ ob1,
                        const float* __restrict__ oW2, const float* __restrict__ ob2,
                        const float* __restrict__ gW, const float* __restrict__ gb,
                        float* __restrict__ out) {
    int b = blockIdx.x;
    int t = threadIdx.x;
    float part = 0.f;
    for (int n = t; n < NN; n += 256) {
        const float* xp = nv + ((size_t)n * NB + b) * 32;
        float x[32];
#pragma unroll
        for (int c = 0; c < 32; c++) x[c] = xp[c];
        float h[32];
#pragma unroll
        for (int oc = 0; oc < 32; oc++) {
            float s = ob1[oc];
#pragma unroll
            for (int c = 0; c < 32; c++) s += oW1[oc * 32 + c] * x[c];
            h[oc] = lrelu(s);
        }
        float s = ob2[0];
#pragma unroll
        for (int k = 0; k < 32; k++) s += oW2[k] * h[k];
        part += lrelu(s) * gW[n];
    }
    __shared__ float rs[256];
    rs[t] = part;
    __syncthreads();
    for (int d = 128; d > 0; d >>= 1) {
        if (t < d) rs[t] += rs[t + d];
        __syncthreads();
    }
    if (t == 0) out[b] = 1.f / (1.f + expf(-(rs[0] + gb[0])));
}

extern "C" void kernel_launch(void* const* d_in, const int* in_sizes, int n_in,
                              void* d_out, int out_size, void* d_ws, size_t ws_size,
                              hipStream_t stream) {
    (void)in_sizes; (void)n_in; (void)out_size; (void)ws_size;
    const float* vert = (const float*)d_in[0];
    const int* edges  = (const int*)d_in[1];
    const float* xW   = (const float*)d_in[2];
    const float* xb   = (const float*)d_in[3];
    const float* yW   = (const float*)d_in[4];
    const float* yb   = (const float*)d_in[5];
    const float* tW   = (const float*)d_in[6];
    const float* tb   = (const float*)d_in[7];
    const float* cW1  = (const float*)d_in[8];
    const float* cb1  = (const float*)d_in[9];
    const float* cW2  = (const float*)d_in[10];
    const float* cb2  = (const float*)d_in[11];
    const float* vW1  = (const float*)d_in[12];
    const float* vb1  = (const float*)d_in[13];
    const float* vW2  = (const float*)d_in[14];
    const float* vb2  = (const float*)d_in[15];
    const float* eW1  = (const float*)d_in[16];
    const float* eb1  = (const float*)d_in[17];
    const float* eW2  = (const float*)d_in[18];
    const float* eb2  = (const float*)d_in[19];
    const float* aW1  = (const float*)d_in[20];
    const float* ab1  = (const float*)d_in[21];
    const float* aW2  = (const float*)d_in[22];
    const float* ab2  = (const float*)d_in[23];
    const float* oW1  = (const float*)d_in[24];
    const float* ob1  = (const float*)d_in[25];
    const float* oW2  = (const float*)d_in[26];
    const float* ob2  = (const float*)d_in[27];
    const float* gW   = (const float*)d_in[28];
    const float* gb   = (const float*)d_in[29];
    float* out = (float*)d_out;

    char* w = (char*)d_ws;
    short* Ap = (short*)(w);                          // 4 MB used
    short* Bp = (short*)(w + 8u * 1024 * 1024);       // 4 MB used
    float* nv = (float*)(w + 16u * 1024 * 1024);      // 8 MB
    int* deg  = (int*)(w + 24u * 1024 * 1024);
    int* offs = deg + 1024;
    int* cntA = offs + 1024;
    int* adj  = cntA + 1024;

    hipMemsetAsync(deg, 0, NN * sizeof(int), stream);
    k_deg<<<(NE + 255) / 256, 256, 0, stream>>>(edges, deg);
    k_scan<<<1, 1024, 0, stream>>>(deg, offs);
    k_fill<<<NN, 64, 0, stream>>>(edges, offs, adj, cntA);

    k_prep0<<<(NB * NN) / 256, 256, 0, stream>>>(vert, xW, xb, yW, yb, tW, tb,
                                                 cW1, cb1, cW2, cb2, vW1, vb1, vW2, vb2,
                                                 eW1, eb1, Ap, Bp);
    k_edge<<<NN, 256, 0, stream>>>(Ap, Bp, offs, cntA, adj, eW2, eb2, nv, 1);

    for (int it = 0; it < 5; it++) {
        k_prep<<<(NB * NN) / 256, 256, 0, stream>>>(nv, vert, aW1, ab1, aW2, ab2,
                                                    eW1, eb1, Ap, Bp);
        k_edge<<<NN, 256, 0, stream>>>(Ap, Bp, offs, cntA, adj, eW2, eb2, nv, 0);
    }

    k_final<<<NB, 256, 0, stream>>>(nv, oW1, ob1, oW2, ob2, gW, gb, out);
}

// Round 4
// 827.455 us; speedup vs baseline: 3.9165x; 1.0595x over previous
//
#include <hip/hip_runtime.h>
#include <hip/hip_bf16.h>
#include <cstdint>
#include <cstddef>

#define NB 64      // batch
#define NN 1000    // nodes
#define NE 16000   // edges
#define ADJCAP 256

typedef __attribute__((ext_vector_type(8))) short short8;
typedef __attribute__((ext_vector_type(16))) float f32x16;

__device__ __forceinline__ float lrelu(float x) { return fmaxf(x, 0.01f * x); }

__device__ __forceinline__ float bf2f(short s) {
    unsigned int u = ((unsigned int)(unsigned short)s) << 16;
    return __builtin_bit_cast(float, u);
}
__device__ __forceinline__ short f2bf(float f) {
    __hip_bfloat16 h = __float2bfloat16(f);
    return __builtin_bit_cast(short, h);
}

union S8 { short8 v; short e[8]; };

// Fragment layout per node (2048 bf16 = 4KB):
//   value (k=oc 0..31, b 0..63): kh=oc>>4, g=(oc>>3)&1, j=oc&7, bh=b>>5, bl=b&31
//   short index = n*2048 + ((kh*2+bh)*64 + g*32 + bl)*8 + j
// MFMA B-operand: lane l of fragment (kh,bh) holds k=kh*16+(l>>5)*8+j, b=bh*32+(l&31)

// ---------------- vert transpose: [b][n][11] -> vt[n][i][b] ----------------
__global__ void k_tr(const float* __restrict__ vert, float* __restrict__ vt) {
    __shared__ float s[2816];
    int n0 = blockIdx.x * 4;
    int t = threadIdx.x;
    int b = t >> 2, r = t & 3;
    const float* vp = vert + ((size_t)b * NN + n0 + r) * 11;
#pragma unroll
    for (int i = 0; i < 11; i++) s[r * 704 + i * 64 + b] = vp[i];
    __syncthreads();
    float* o = vt + (size_t)n0 * 704;
#pragma unroll
    for (int j = 0; j < 11; j++) o[j * 256 + t] = s[j * 256 + t];
}

// ---------------- CSR build ----------------
__global__ void k_deg(const int* __restrict__ edges, int* __restrict__ deg) {
    int e = blockIdx.x * 256 + threadIdx.x;
    if (e < NE) {
        atomicAdd(&deg[edges[e]], 1);
        atomicAdd(&deg[edges[NE + e]], 1);
    }
}

__global__ void k_scan(const int* __restrict__ deg, int* __restrict__ offs,
                       int* __restrict__ cursor) {
    __shared__ int s[1024];
    int t = threadIdx.x;
    int d = (t < NN) ? deg[t] : 0;
    s[t] = d;
    __syncthreads();
    for (int k = 1; k < 1024; k <<= 1) {
        int v = (t >= k) ? s[t - k] : 0;
        __syncthreads();
        s[t] += v;
        __syncthreads();
    }
    if (t < NN) {
        offs[t + 1] = s[t];
        cursor[t] = s[t] - d;   // exclusive prefix
    }
    if (t == 0) offs[0] = 0;
}

// atomic fill of packed incidences: (role<<30)|(edge<<10)|other
__global__ void k_fillA(const int* __restrict__ edges, int* __restrict__ cursor,
                        int* __restrict__ adj) {
    int e = blockIdx.x * 256 + threadIdx.x;
    if (e < NE) {
        int s = edges[e], d = edges[NE + e];
        int p1 = atomicAdd(&cursor[s], 1);
        adj[p1] = (e << 10) | d;               // role 0: s is src, other=dst
        int p2 = atomicAdd(&cursor[d], 1);
        adj[p2] = (1 << 30) | (e << 10) | s;   // role 1: d is dst, other=src
    }
}

// canonical per-node sort (ascending packed key == role-major, edge-id order)
__global__ void k_sort(const int* __restrict__ offs, int* __restrict__ adj,
                       int* __restrict__ cntA) {
    int n = blockIdx.x * 256 + threadIdx.x;
    if (n >= NN) return;
    int o0 = offs[n], o1 = offs[n + 1];
    for (int i = o0 + 1; i < o1; i++) {
        int key = adj[i];
        int j = i - 1;
        while (j >= o0 && adj[j] > key) { adj[j + 1] = adj[j]; j--; }
        adj[j + 1] = key;
    }
    int c = 0;
    for (int i = o0; i < o1; i++) c += ((adj[i] >> 30) & 1) ? 0 : 1;
    cntA[n] = c;
}

// store sa/sb (32 each) for (n,b) into fragment layout
__device__ __forceinline__ void store_frags(short* __restrict__ Ap, short* __restrict__ Bp,
                                            int n, int b, const float* sa, const float* sb) {
    int bh = b >> 5, bl = b & 31;
    size_t nodeb = (size_t)n * 2048;
#pragma unroll
    for (int kh = 0; kh < 2; kh++) {
#pragma unroll
        for (int g = 0; g < 2; g++) {
            size_t off = nodeb + ((size_t)(kh * 2 + bh) * 64 + g * 32 + bl) * 8;
            S8 pa, pb;
#pragma unroll
            for (int j = 0; j < 8; j++) {
                pa.e[j] = f2bf(sa[kh * 16 + g * 8 + j]);
                pb.e[j] = f2bf(sb[kh * 16 + g * 8 + j]);
            }
            *(short8*)(Ap + off) = pa.v;
            *(short8*)(Bp + off) = pb.v;
        }
    }
}

// ---------------- pass-0 node prep (reads transposed vt) ----------------
__global__ void k_prep0(const float* __restrict__ vt,
                        const float* __restrict__ xW, const float* __restrict__ xb,
                        const float* __restrict__ yW, const float* __restrict__ yb,
                        const float* __restrict__ tW, const float* __restrict__ tb,
                        const float* __restrict__ cW1, const float* __restrict__ cb1,
                        const float* __restrict__ cW2, const float* __restrict__ cb2,
                        const float* __restrict__ vW1, const float* __restrict__ vb1,
                        const float* __restrict__ vW2, const float* __restrict__ vb2,
                        const float* __restrict__ eW1, const float* __restrict__ eb1,
                        short* __restrict__ Ap, short* __restrict__ Bp) {
    int idx = blockIdx.x * blockDim.x + threadIdx.x;
    int n = idx >> 6, b = idx & 63;
    const float* vn = vt + (size_t)n * 704;
    float vv[11];
#pragma unroll
    for (int i = 0; i < 11; i++) vv[i] = vn[i * 64 + b];

    float config[64];
#pragma unroll
    for (int half = 0; half < 2; half++) {
        float f[24];
        const float* o = vv + (half ? 6 : 3);
        {
            const float* Ws[3] = {xW, yW, tW};
            const float* bs[3] = {xb, yb, tb};
#pragma unroll
            for (int i = 0; i < 3; i++) {
                float p0 = vv[i], p1 = o[i];
#pragma unroll
                for (int c = 0; c < 8; c++)
                    f[i * 8 + c] = lrelu(Ws[i][c * 2] * p0 + Ws[i][c * 2 + 1] * p1 + bs[i][c]);
            }
        }
        float h[32];
#pragma unroll
        for (int oc = 0; oc < 32; oc++) {
            float s = cb1[oc];
#pragma unroll
            for (int c = 0; c < 24; c++) s += cW1[oc * 24 + c] * f[c];
            h[oc] = lrelu(s);
        }
#pragma unroll
        for (int oc = 0; oc < 32; oc++) {
            float s = cb2[oc];
#pragma unroll
            for (int c = 0; c < 32; c++) s += cW2[oc * 32 + c] * h[c];
            config[half * 32 + oc] = lrelu(s);
        }
    }
    float v1[32];
#pragma unroll
    for (int oc = 0; oc < 32; oc++) {
        float s = vb1[oc];
#pragma unroll
        for (int c = 0; c < 64; c++) s += vW1[oc * 64 + c] * config[c];
        v1[oc] = lrelu(s);
    }
    float vf[34];
#pragma unroll
    for (int oc = 0; oc < 32; oc++) {
        float s = vb2[oc];
#pragma unroll
        for (int c = 0; c < 32; c++) s += vW2[oc * 32 + c] * v1[c];
        vf[oc] = lrelu(s);
    }
    vf[32] = vv[9]; vf[33] = vv[10];

    float sa[32], sb[32];
#pragma unroll
    for (int oc = 0; oc < 32; oc++) {
        float a = eb1[oc], bb = 0.f;
#pragma unroll
        for (int c = 0; c < 34; c++) {
            a  += eW1[oc * 68 + c] * vf[c];
            bb += eW1[oc * 68 + 34 + c] * vf[c];
        }
        sa[oc] = a; sb[oc] = bb;
    }
    store_frags(Ap, Bp, n, b, sa, sb);
}

// ---------------- per-iteration node prep ----------------
__global__ void k_prep(const float* __restrict__ nv, const float* __restrict__ vt,
                       const float* __restrict__ aW1, const float* __restrict__ ab1,
                       const float* __restrict__ aW2, const float* __restrict__ ab2,
                       const float* __restrict__ eW1, const float* __restrict__ eb1,
                       short* __restrict__ Ap, short* __restrict__ Bp) {
    int idx = blockIdx.x * blockDim.x + threadIdx.x;
    int n = idx >> 6, b = idx & 63;
    const float4* xp = (const float4*)(nv + ((size_t)n * NB + b) * 32);
    float x[32];
#pragma unroll
    for (int q = 0; q < 8; q++) {
        float4 v = xp[q];
        x[q * 4] = v.x; x[q * 4 + 1] = v.y; x[q * 4 + 2] = v.z; x[q * 4 + 3] = v.w;
    }
    float h[32];
#pragma unroll
    for (int oc = 0; oc < 32; oc++) {
        float s = ab1[oc];
#pragma unroll
        for (int c = 0; c < 32; c++) s += aW1[oc * 32 + c] * x[c];
        h[oc] = lrelu(s);
    }
    float vf[34];
#pragma unroll
    for (int oc = 0; oc < 32; oc++) {
        float s = ab2[oc];
#pragma unroll
        for (int c = 0; c < 32; c++) s += aW2[oc * 32 + c] * h[c];
        vf[oc] = lrelu(s);
    }
    const float* vn = vt + (size_t)n * 704;
    vf[32] = vn[9 * 64 + b]; vf[33] = vn[10 * 64 + b];

    float sa[32], sb[32];
#pragma unroll
    for (int oc = 0; oc < 32; oc++) {
        float a = eb1[oc], bb = 0.f;
#pragma unroll
        for (int c = 0; c < 34; c++) {
            a  += eW1[oc * 68 + c] * vf[c];
            bb += eW1[oc * 68 + 34 + c] * vf[c];
        }
        sa[oc] = a; sb[oc] = bb;
    }
    store_frags(Ap, Bp, n, b, sa, sb);
}

// ---------------- edge pass: MFMA + LDS-adj + double-buffered og loads ----------------
#define VISIT(C0, C1, C2, C3) do {                                                        \
    S8 h10, h11;                                                                          \
    _Pragma("unroll") for (int j = 0; j < 8; j++) {                                       \
        float x0 = bfv[0][j] + bf2f(C0.e[j]); h10.e[j] = f2bf(fmaxf(x0, 0.01f * x0)); }   \
    _Pragma("unroll") for (int j = 0; j < 8; j++) {                                       \
        float x1 = bfv[2][j] + bf2f(C2.e[j]); h11.e[j] = f2bf(fmaxf(x1, 0.01f * x1)); }   \
    f32x16 d = __builtin_amdgcn_mfma_f32_32x32x16_bf16(w2f0.v, h10.v, zero, 0, 0, 0);     \
    d = __builtin_amdgcn_mfma_f32_32x32x16_bf16(w2f1.v, h11.v, d, 0, 0, 0);               \
    _Pragma("unroll") for (int r = 0; r < 16; r++) {                                      \
        float m = d[r] + b2v[r]; acc0[r] += fmaxf(m, 0.01f * m); }                        \
    _Pragma("unroll") for (int j = 0; j < 8; j++) {                                       \
        float x0 = bfv[1][j] + bf2f(C1.e[j]); h10.e[j] = f2bf(fmaxf(x0, 0.01f * x0)); }   \
    _Pragma("unroll") for (int j = 0; j < 8; j++) {                                       \
        float x1 = bfv[3][j] + bf2f(C3.e[j]); h11.e[j] = f2bf(fmaxf(x1, 0.01f * x1)); }   \
    d = __builtin_amdgcn_mfma_f32_32x32x16_bf16(w2f0.v, h10.v, zero, 0, 0, 0);            \
    d = __builtin_amdgcn_mfma_f32_32x32x16_bf16(w2f1.v, h11.v, d, 0, 0, 0);               \
    _Pragma("unroll") for (int r = 0; r < 16; r++) {                                      \
        float m = d[r] + b2v[r]; acc1[r] += fmaxf(m, 0.01f * m); }                        \
} while (0)

__global__ __launch_bounds__(256) void k_edge(
    const short* __restrict__ Ap, const short* __restrict__ Bp,
    const int* __restrict__ offs, const int* __restrict__ cntA,
    const int* __restrict__ adjg,
    const float* __restrict__ W2, const float* __restrict__ b2,
    float* __restrict__ nv, int pass0) {
    __shared__ float red[4][64 * 33];
    __shared__ int adjl[ADJCAP];
    int n = blockIdx.x;
    int w = threadIdx.x >> 6;
    int lane = threadIdx.x & 63;
    int row = lane & 31, kg = lane >> 5;

    int off0 = offs[n], off1 = offs[n + 1];
    int deg = off1 - off0;
    int cA = cntA[n];

    for (int i = threadIdx.x; i < deg && i < ADJCAP; i += 256)
        adjl[i] = adjg[off0 + i] & 1023;
    __syncthreads();

    // W2 as MFMA A-fragments
    S8 w2f0, w2f1;
#pragma unroll
    for (int j = 0; j < 8; j++) {
        w2f0.e[j] = f2bf(W2[row * 32 + kg * 8 + j]);
        w2f1.e[j] = f2bf(W2[row * 32 + 16 + kg * 8 + j]);
    }
    float b2v[16];
#pragma unroll
    for (int r = 0; r < 16; r++)
        b2v[r] = b2[(r & 3) + 8 * (r >> 2) + 4 * kg];

    f32x16 acc0 = {};
    f32x16 acc1 = {};
    const f32x16 zero = {};

#pragma unroll
    for (int phase = 0; phase < 2; phase++) {
        const short* basePtr = phase ? Bp : Ap;
        const short8* ogBase = (const short8*)(phase ? Ap : Bp);
        int lstart = phase ? cA : 0;
        int lend   = phase ? deg : cA;

        float bfv[4][8];
        {
            const short8* np = (const short8*)(basePtr + (size_t)n * 2048);
#pragma unroll
            for (int f = 0; f < 4; f++) {
                S8 t; t.v = np[f * 64 + lane];
#pragma unroll
                for (int j = 0; j < 8; j++) bfv[f][j] = bf2f(t.e[j]);
            }
        }

        int li = lstart + w;
        S8 c0 = {}, c1 = {}, c2 = {}, c3 = {};
        if (li < lend) {
            int o = (li < ADJCAP) ? adjl[li] : (adjg[off0 + li] & 1023);
            const short8* op = ogBase + (size_t)o * 256;
            c0.v = op[lane]; c1.v = op[64 + lane];
            c2.v = op[128 + lane]; c3.v = op[192 + lane];
        }
        while (li < lend) {
            int ln = li + 4;
            S8 n0 = {}, n1 = {}, n2 = {}, n3 = {};
            if (ln < lend) {
                int o = (ln < ADJCAP) ? adjl[ln] : (adjg[off0 + ln] & 1023);
                const short8* op = ogBase + (size_t)o * 256;
                n0.v = op[lane]; n1.v = op[64 + lane];
                n2.v = op[128 + lane]; n3.v = op[192 + lane];
            }
            VISIT(c0, c1, c2, c3);
            c0 = n0; c1 = n1; c2 = n2; c3 = n3;
            li = ln;
        }
    }

    // scatter C fragments to LDS in (b, oc) layout, padded stride 33
#pragma unroll
    for (int bh = 0; bh < 2; bh++) {
        int b = bh * 32 + row;
#pragma unroll
        for (int r = 0; r < 16; r++) {
            int oc = (r & 3) + 8 * (r >> 2) + 4 * kg;
            red[w][b * 33 + oc] = bh ? acc1[r] : acc0[r];
        }
    }
    __syncthreads();

    int t = threadIdx.x;
    size_t nb = (size_t)n * (NB * 32);
    if (deg > 0) {
        float inv = 1.f / (float)deg;
#pragma unroll
        for (int j = 0; j < 8; j++) {
            int idx = t * 8 + j;
            int bb = idx >> 5, cc = idx & 31;
            float s = red[0][bb * 33 + cc] + red[1][bb * 33 + cc] +
                      red[2][bb * 33 + cc] + red[3][bb * 33 + cc];
            s *= inv;
            if (!pass0) s += nv[nb + idx];
            nv[nb + idx] = s;
        }
    } else if (pass0) {
#pragma unroll
        for (int j = 0; j < 8; j++) nv[nb + t * 8 + j] = 0.f;
    }
}

// ---------------- final readout (2-stage, coalesced) ----------------
__global__ void k_final1(const float* __restrict__ nv,
                         const float* __restrict__ oW1, const float* __restrict__ ob1,
                         const float* __restrict__ oW2, const float* __restrict__ ob2,
                         float* __restrict__ fv) {
    int idx = blockIdx.x * 256 + threadIdx.x;  // 64000
    int n = idx >> 6, b = idx & 63;
    const float4* xp = (const float4*)(nv + ((size_t)n * NB + b) * 32);
    float x[32];
#pragma unroll
    for (int q = 0; q < 8; q++) {
        float4 v = xp[q];
        x[q * 4] = v.x; x[q * 4 + 1] = v.y; x[q * 4 + 2] = v.z; x[q * 4 + 3] = v.w;
    }
    float h[32];
#pragma unroll
    for (int oc = 0; oc < 32; oc++) {
        float s = ob1[oc];
#pragma unroll
        for (int c = 0; c < 32; c++) s += oW1[oc * 32 + c] * x[c];
        h[oc] = lrelu(s);
    }
    float s = ob2[0];
#pragma unroll
    for (int k = 0; k < 32; k++) s += oW2[k] * h[k];
    fv[idx] = lrelu(s);
}

__global__ void k_final2(const float* __restrict__ fv, const float* __restrict__ gW,
                         const float* __restrict__ gb, float* __restrict__ out) {
    int b = blockIdx.x;
    int t = threadIdx.x;
    float part = 0.f;
    for (int n = t; n < NN; n += 256) part += fv[n * 64 + b] * gW[n];
    __shared__ float rs[256];
    rs[t] = part;
    __syncthreads();
    for (int d = 128; d > 0; d >>= 1) {
        if (t < d) rs[t] += rs[t + d];
        __syncthreads();
    }
    if (t == 0) out[b] = 1.f / (1.f + expf(-(rs[0] + gb[0])));
}

extern "C" void kernel_launch(void* const* d_in, const int* in_sizes, int n_in,
                              void* d_out, int out_size, void* d_ws, size_t ws_size,
                              hipStream_t stream) {
    (void)in_sizes; (void)n_in; (void)out_size; (void)ws_size;
    const float* vert = (const float*)d_in[0];
    const int* edges  = (const int*)d_in[1];
    const float* xW   = (const float*)d_in[2];
    const float* xb   = (const float*)d_in[3];
    const float* yW   = (const float*)d_in[4];
    const float* yb   = (const float*)d_in[5];
    const float* tW   = (const float*)d_in[6];
    const float* tb   = (const float*)d_in[7];
    const float* cW1  = (const float*)d_in[8];
    const float* cb1  = (const float*)d_in[9];
    const float* cW2  = (const float*)d_in[10];
    const float* cb2  = (const float*)d_in[11];
    const float* vW1  = (const float*)d_in[12];
    const float* vb1  = (const float*)d_in[13];
    const float* vW2  = (const float*)d_in[14];
    const float* vb2  = (const float*)d_in[15];
    const float* eW1  = (const float*)d_in[16];
    const float* eb1  = (const float*)d_in[17];
    const float* eW2  = (const float*)d_in[18];
    const float* eb2  = (const float*)d_in[19];
    const float* aW1  = (const float*)d_in[20];
    const float* ab1  = (const float*)d_in[21];
    const float* aW2  = (const float*)d_in[22];
    const float* ab2  = (const float*)d_in[23];
    const float* oW1  = (const float*)d_in[24];
    const float* ob1  = (const float*)d_in[25];
    const float* oW2  = (const float*)d_in[26];
    const float* ob2  = (const float*)d_in[27];
    const float* gW   = (const float*)d_in[28];
    const float* gb   = (const float*)d_in[29];
    float* out = (float*)d_out;

    char* w = (char*)d_ws;
    short* Ap = (short*)(w);                          // 4.1 MB
    short* Bp = (short*)(w + (5u << 20));             // 4.1 MB
    float* nv = (float*)(w + (10u << 20));            // 8.2 MB
    float* vt = (float*)(w + (19u << 20));            // 2.8 MB
    float* fv = (float*)(w + (22u << 20));            // 256 KB
    int* deg    = (int*)(w + (23u << 20));
    int* offs   = deg + 1024;
    int* cursor = offs + 1024;
    int* cntA   = cursor + 1024;
    int* adj    = cntA + 1024;                        // 32000 ints

    hipMemsetAsync(deg, 0, NN * sizeof(int), stream);
    k_tr<<<NN / 4, 256, 0, stream>>>(vert, vt);
    k_deg<<<(NE + 255) / 256, 256, 0, stream>>>(edges, deg);
    k_scan<<<1, 1024, 0, stream>>>(deg, offs, cursor);
    k_fillA<<<(NE + 255) / 256, 256, 0, stream>>>(edges, cursor, adj);
    k_sort<<<4, 256, 0, stream>>>(offs, adj, cntA);

    k_prep0<<<(NB * NN) / 256, 256, 0, stream>>>(vt, xW, xb, yW, yb, tW, tb,
                                                 cW1, cb1, cW2, cb2, vW1, vb1, vW2, vb2,
                                                 eW1, eb1, Ap, Bp);
    k_edge<<<NN, 256, 0, stream>>>(Ap, Bp, offs, cntA, adj, eW2, eb2, nv, 1);

    for (int it = 0; it < 5; it++) {
        k_prep<<<(NB * NN) / 256, 256, 0, stream>>>(nv, vt, aW1, ab1, aW2, ab2,
                                                    eW1, eb1, Ap, Bp);
        k_edge<<<NN, 256, 0, stream>>>(Ap, Bp, offs, cntA, adj, eW2, eb2, nv, 0);
    }

    k_final1<<<(NB * NN) / 256, 256, 0, stream>>>(nv, oW1, ob1, oW2, ob2, fv);
    k_final2<<<NB, 256, 0, stream>>>(fv, gW, gb, out);
}

// Round 5
// 696.290 us; speedup vs baseline: 4.6542x; 1.1884x over previous
//
#include <hip/hip_runtime.h>
#include <hip/hip_bf16.h>
#include <cstdint>
#include <cstddef>

#define NB 64      // batch
#define NN 1000    // nodes
#define NE 16000   // edges
#define ADJCAP 256

typedef __attribute__((ext_vector_type(8))) short short8;
typedef __attribute__((ext_vector_type(16))) float f32x16;

__device__ __forceinline__ float lrelu(float x) { return fmaxf(x, 0.01f * x); }

__device__ __forceinline__ float bf2f(short s) {
    unsigned int u = ((unsigned int)(unsigned short)s) << 16;
    return __builtin_bit_cast(float, u);
}
__device__ __forceinline__ short f2bf(float f) {
    __hip_bfloat16 h = __float2bfloat16(f);
    return __builtin_bit_cast(short, h);
}

union S8 { short8 v; short e[8]; };

// Fragment layout per node (2048 bf16 = 4KB):
//   value (k=oc 0..31, b 0..63): kh=oc>>4, g=(oc>>3)&1, j=oc&7, bh=b>>5, bl=b&31
//   short index = n*2048 + ((kh*2+bh)*64 + g*32 + bl)*8 + j
// MFMA B-operand: lane l of fragment (kh,bh) holds k=kh*16+(l>>5)*8+j, b=bh*32+(l&31)

// ---------------- vert transpose: [b][n][11] -> vt[n][i][b] ----------------
__global__ void k_tr(const float* __restrict__ vert, float* __restrict__ vt) {
    __shared__ float s[2816];
    int n0 = blockIdx.x * 4;
    int t = threadIdx.x;
    int b = t >> 2, r = t & 3;
    const float* vp = vert + ((size_t)b * NN + n0 + r) * 11;
#pragma unroll
    for (int i = 0; i < 11; i++) s[r * 704 + i * 64 + b] = vp[i];
    __syncthreads();
    float* o = vt + (size_t)n0 * 704;
#pragma unroll
    for (int j = 0; j < 11; j++) o[j * 256 + t] = s[j * 256 + t];
}

// ---------------- CSR build ----------------
__global__ void k_deg(const int* __restrict__ edges, int* __restrict__ deg) {
    int e = blockIdx.x * 256 + threadIdx.x;
    if (e < NE) {
        atomicAdd(&deg[edges[e]], 1);
        atomicAdd(&deg[edges[NE + e]], 1);
    }
}

__global__ void k_scan(const int* __restrict__ deg, int* __restrict__ offs,
                       int* __restrict__ cursor) {
    __shared__ int s[1024];
    int t = threadIdx.x;
    int d = (t < NN) ? deg[t] : 0;
    s[t] = d;
    __syncthreads();
    for (int k = 1; k < 1024; k <<= 1) {
        int v = (t >= k) ? s[t - k] : 0;
        __syncthreads();
        s[t] += v;
        __syncthreads();
    }
    if (t < NN) {
        offs[t + 1] = s[t];
        cursor[t] = s[t] - d;   // exclusive prefix
    }
    if (t == 0) offs[0] = 0;
}

// atomic fill of packed incidences: (role<<30)|(edge<<10)|other
__global__ void k_fillA(const int* __restrict__ edges, int* __restrict__ cursor,
                        int* __restrict__ adj) {
    int e = blockIdx.x * 256 + threadIdx.x;
    if (e < NE) {
        int s = edges[e], d = edges[NE + e];
        int p1 = atomicAdd(&cursor[s], 1);
        adj[p1] = (e << 10) | d;               // role 0: s is src, other=dst
        int p2 = atomicAdd(&cursor[d], 1);
        adj[p2] = (1 << 30) | (e << 10) | s;   // role 1: d is dst, other=src
    }
}

// wave-parallel canonical rank sort: keys unique, rank = #{smaller keys}.
// Result identical to sorting ascending by packed key (role-major, edge order),
// independent of the atomic fill order.
__global__ void k_sort(const int* __restrict__ offs, int* __restrict__ adj,
                       int* __restrict__ cntA) {
    __shared__ int keys[4][ADJCAP];
    int w = threadIdx.x >> 6;
    int lane = threadIdx.x & 63;
    int n = blockIdx.x * 4 + w;
    int o0 = offs[n], o1 = offs[n + 1];
    int deg = o1 - o0;
    int cap = (deg < ADJCAP) ? deg : ADJCAP;
    for (int i = lane; i < cap; i += 64) keys[w][i] = adj[o0 + i];
    __syncthreads();
    if (deg <= ADJCAP) {
        for (int i = lane; i < deg; i += 64) {
            int k = keys[w][i];
            int r = 0;
            for (int j = 0; j < deg; j++) r += (keys[w][j] < k) ? 1 : 0;
            adj[o0 + r] = k;
        }
        if (lane == 0) {
            int c = 0;
            for (int j = 0; j < deg; j++) c += ((keys[w][j] >> 30) & 1) ? 0 : 1;
            cntA[n] = c;
        }
    } else if (lane == 0) {
        // fallback (never expected at these sizes)
        for (int i = o0 + 1; i < o1; i++) {
            int key = adj[i];
            int j = i - 1;
            while (j >= o0 && adj[j] > key) { adj[j + 1] = adj[j]; j--; }
            adj[j + 1] = key;
        }
        int c = 0;
        for (int i = o0; i < o1; i++) c += ((adj[i] >> 30) & 1) ? 0 : 1;
        cntA[n] = c;
    }
}

// one-wave setup: pre-pack W2 MFMA A-fragments (bf16) and b2 in C-layout
__global__ void k_wsetup(const float* __restrict__ W2, const float* __restrict__ b2,
                         short* __restrict__ W2f, float* __restrict__ B2f) {
    int lane = threadIdx.x;  // 64
    int row = lane & 31, kg = lane >> 5;
    S8 a0, a1;
#pragma unroll
    for (int j = 0; j < 8; j++) {
        a0.e[j] = f2bf(W2[row * 32 + kg * 8 + j]);
        a1.e[j] = f2bf(W2[row * 32 + 16 + kg * 8 + j]);
    }
    ((short8*)W2f)[lane] = a0.v;
    ((short8*)W2f)[64 + lane] = a1.v;
#pragma unroll
    for (int r = 0; r < 16; r++)
        B2f[lane * 16 + r] = b2[(r & 3) + 8 * (r >> 2) + 4 * kg];
}

// store sa/sb (32 each) for (n,b) into fragment layout
__device__ __forceinline__ void store_frags(short* __restrict__ Ap, short* __restrict__ Bp,
                                            int n, int b, const float* sa, const float* sb) {
    int bh = b >> 5, bl = b & 31;
    size_t nodeb = (size_t)n * 2048;
#pragma unroll
    for (int kh = 0; kh < 2; kh++) {
#pragma unroll
        for (int g = 0; g < 2; g++) {
            size_t off = nodeb + ((size_t)(kh * 2 + bh) * 64 + g * 32 + bl) * 8;
            S8 pa, pb;
#pragma unroll
            for (int j = 0; j < 8; j++) {
                pa.e[j] = f2bf(sa[kh * 16 + g * 8 + j]);
                pb.e[j] = f2bf(sb[kh * 16 + g * 8 + j]);
            }
            *(short8*)(Ap + off) = pa.v;
            *(short8*)(Bp + off) = pb.v;
        }
    }
}

// ---------------- pass-0 node prep (reads transposed vt) ----------------
__global__ void k_prep0(const float* __restrict__ vt,
                        const float* __restrict__ xW, const float* __restrict__ xb,
                        const float* __restrict__ yW, const float* __restrict__ yb,
                        const float* __restrict__ tW, const float* __restrict__ tb,
                        const float* __restrict__ cW1, const float* __restrict__ cb1,
                        const float* __restrict__ cW2, const float* __restrict__ cb2,
                        const float* __restrict__ vW1, const float* __restrict__ vb1,
                        const float* __restrict__ vW2, const float* __restrict__ vb2,
                        const float* __restrict__ eW1, const float* __restrict__ eb1,
                        short* __restrict__ Ap, short* __restrict__ Bp) {
    int idx = blockIdx.x * blockDim.x + threadIdx.x;
    int n = idx >> 6, b = idx & 63;
    const float* vn = vt + (size_t)n * 704;
    float vv[11];
#pragma unroll
    for (int i = 0; i < 11; i++) vv[i] = vn[i * 64 + b];

    float config[64];
#pragma unroll
    for (int half = 0; half < 2; half++) {
        float f[24];
        const float* o = vv + (half ? 6 : 3);
        {
            const float* Ws[3] = {xW, yW, tW};
            const float* bs[3] = {xb, yb, tb};
#pragma unroll
            for (int i = 0; i < 3; i++) {
                float p0 = vv[i], p1 = o[i];
#pragma unroll
                for (int c = 0; c < 8; c++)
                    f[i * 8 + c] = lrelu(Ws[i][c * 2] * p0 + Ws[i][c * 2 + 1] * p1 + bs[i][c]);
            }
        }
        float h[32];
#pragma unroll
        for (int oc = 0; oc < 32; oc++) {
            float s = cb1[oc];
#pragma unroll
            for (int c = 0; c < 24; c++) s += cW1[oc * 24 + c] * f[c];
            h[oc] = lrelu(s);
        }
#pragma unroll
        for (int oc = 0; oc < 32; oc++) {
            float s = cb2[oc];
#pragma unroll
            for (int c = 0; c < 32; c++) s += cW2[oc * 32 + c] * h[c];
            config[half * 32 + oc] = lrelu(s);
        }
    }
    float v1[32];
#pragma unroll
    for (int oc = 0; oc < 32; oc++) {
        float s = vb1[oc];
#pragma unroll
        for (int c = 0; c < 64; c++) s += vW1[oc * 64 + c] * config[c];
        v1[oc] = lrelu(s);
    }
    float vf[34];
#pragma unroll
    for (int oc = 0; oc < 32; oc++) {
        float s = vb2[oc];
#pragma unroll
        for (int c = 0; c < 32; c++) s += vW2[oc * 32 + c] * v1[c];
        vf[oc] = lrelu(s);
    }
    vf[32] = vv[9]; vf[33] = vv[10];

    float sa[32], sb[32];
#pragma unroll
    for (int oc = 0; oc < 32; oc++) {
        float a = eb1[oc], bb = 0.f;
#pragma unroll
        for (int c = 0; c < 34; c++) {
            a  += eW1[oc * 68 + c] * vf[c];
            bb += eW1[oc * 68 + 34 + c] * vf[c];
        }
        sa[oc] = a; sb[oc] = bb;
    }
    store_frags(Ap, Bp, n, b, sa, sb);
}

// ---------------- per-iteration node prep ----------------
__global__ void k_prep(const float* __restrict__ nv, const float* __restrict__ vt,
                       const float* __restrict__ aW1, const float* __restrict__ ab1,
                       const float* __restrict__ aW2, const float* __restrict__ ab2,
                       const float* __restrict__ eW1, const float* __restrict__ eb1,
                       short* __restrict__ Ap, short* __restrict__ Bp) {
    int idx = blockIdx.x * blockDim.x + threadIdx.x;
    int n = idx >> 6, b = idx & 63;
    const float4* xp = (const float4*)(nv + ((size_t)n * NB + b) * 32);
    float x[32];
#pragma unroll
    for (int q = 0; q < 8; q++) {
        float4 v = xp[q];
        x[q * 4] = v.x; x[q * 4 + 1] = v.y; x[q * 4 + 2] = v.z; x[q * 4 + 3] = v.w;
    }
    float h[32];
#pragma unroll
    for (int oc = 0; oc < 32; oc++) {
        float s = ab1[oc];
#pragma unroll
        for (int c = 0; c < 32; c++) s += aW1[oc * 32 + c] * x[c];
        h[oc] = lrelu(s);
    }
    float vf[34];
#pragma unroll
    for (int oc = 0; oc < 32; oc++) {
        float s = ab2[oc];
#pragma unroll
        for (int c = 0; c < 32; c++) s += aW2[oc * 32 + c] * h[c];
        vf[oc] = lrelu(s);
    }
    const float* vn = vt + (size_t)n * 704;
    vf[32] = vn[9 * 64 + b]; vf[33] = vn[10 * 64 + b];

    float sa[32], sb[32];
#pragma unroll
    for (int oc = 0; oc < 32; oc++) {
        float a = eb1[oc], bb = 0.f;
#pragma unroll
        for (int c = 0; c < 34; c++) {
            a  += eW1[oc * 68 + c] * vf[c];
            bb += eW1[oc * 68 + 34 + c] * vf[c];
        }
        sa[oc] = a; sb[oc] = bb;
    }
    store_frags(Ap, Bp, n, b, sa, sb);
}

// ---------------- edge pass: MFMA + LDS-adj + double-buffered og loads ----------------
#define VISIT(C0, C1, C2, C3) do {                                                        \
    S8 h10, h11;                                                                          \
    _Pragma("unroll") for (int j = 0; j < 8; j++) {                                       \
        float x0 = bfv[0][j] + bf2f(C0.e[j]); h10.e[j] = f2bf(fmaxf(x0, 0.01f * x0)); }   \
    _Pragma("unroll") for (int j = 0; j < 8; j++) {                                       \
        float x1 = bfv[2][j] + bf2f(C2.e[j]); h11.e[j] = f2bf(fmaxf(x1, 0.01f * x1)); }   \
    f32x16 d = __builtin_amdgcn_mfma_f32_32x32x16_bf16(w2f0.v, h10.v, zero, 0, 0, 0);     \
    d = __builtin_amdgcn_mfma_f32_32x32x16_bf16(w2f1.v, h11.v, d, 0, 0, 0);               \
    _Pragma("unroll") for (int r = 0; r < 16; r++) {                                      \
        float m = d[r] + b2v[r]; acc0[r] += fmaxf(m, 0.01f * m); }                        \
    _Pragma("unroll") for (int j = 0; j < 8; j++) {                                       \
        float x0 = bfv[1][j] + bf2f(C1.e[j]); h10.e[j] = f2bf(fmaxf(x0, 0.01f * x0)); }   \
    _Pragma("unroll") for (int j = 0; j < 8; j++) {                                       \
        float x1 = bfv[3][j] + bf2f(C3.e[j]); h11.e[j] = f2bf(fmaxf(x1, 0.01f * x1)); }   \
    d = __builtin_amdgcn_mfma_f32_32x32x16_bf16(w2f0.v, h10.v, zero, 0, 0, 0);            \
    d = __builtin_amdgcn_mfma_f32_32x32x16_bf16(w2f1.v, h11.v, d, 0, 0, 0);               \
    _Pragma("unroll") for (int r = 0; r < 16; r++) {                                      \
        float m = d[r] + b2v[r]; acc1[r] += fmaxf(m, 0.01f * m); }                        \
} while (0)

__global__ __launch_bounds__(256) void k_edge(
    const short* __restrict__ Ap, const short* __restrict__ Bp,
    const int* __restrict__ offs, const int* __restrict__ cntA,
    const int* __restrict__ adjg,
    const short* __restrict__ W2f, const float* __restrict__ B2f,
    float* __restrict__ nv, int pass0) {
    __shared__ float red[4][64 * 33];
    __shared__ int adjl[ADJCAP];
    int n = blockIdx.x;
    int w = threadIdx.x >> 6;
    int lane = threadIdx.x & 63;
    int row = lane & 31, kg = lane >> 5;

    int off0 = offs[n], off1 = offs[n + 1];
    int deg = off1 - off0;
    int cA = cntA[n];

    for (int i = threadIdx.x; i < deg && i < ADJCAP; i += 256)
        adjl[i] = adjg[off0 + i] & 1023;
    __syncthreads();

    // pre-packed W2 A-fragments + b2 (C layout)
    S8 w2f0, w2f1;
    w2f0.v = ((const short8*)W2f)[lane];
    w2f1.v = ((const short8*)W2f)[64 + lane];
    float b2v[16];
    {
        const float4* bp4 = (const float4*)(B2f + lane * 16);
#pragma unroll
        for (int q = 0; q < 4; q++) {
            float4 v = bp4[q];
            b2v[q * 4] = v.x; b2v[q * 4 + 1] = v.y;
            b2v[q * 4 + 2] = v.z; b2v[q * 4 + 3] = v.w;
        }
    }

    f32x16 acc0 = {};
    f32x16 acc1 = {};
    const f32x16 zero = {};

#pragma unroll
    for (int phase = 0; phase < 2; phase++) {
        const short* basePtr = phase ? Bp : Ap;
        const short8* ogBase = (const short8*)(phase ? Ap : Bp);
        int lstart = phase ? cA : 0;
        int lend   = phase ? deg : cA;

        float bfv[4][8];
        {
            const short8* np = (const short8*)(basePtr + (size_t)n * 2048);
#pragma unroll
            for (int f = 0; f < 4; f++) {
                S8 t; t.v = np[f * 64 + lane];
#pragma unroll
                for (int j = 0; j < 8; j++) bfv[f][j] = bf2f(t.e[j]);
            }
        }

        int li = lstart + w;
        S8 c0 = {}, c1 = {}, c2 = {}, c3 = {};
        if (li < lend) {
            int o = (li < ADJCAP) ? adjl[li] : (adjg[off0 + li] & 1023);
            const short8* op = ogBase + (size_t)o * 256;
            c0.v = op[lane]; c1.v = op[64 + lane];
            c2.v = op[128 + lane]; c3.v = op[192 + lane];
        }
        while (li < lend) {
            int ln = li + 4;
            S8 n0 = {}, n1 = {}, n2 = {}, n3 = {};
            if (ln < lend) {
                int o = (ln < ADJCAP) ? adjl[ln] : (adjg[off0 + ln] & 1023);
                const short8* op = ogBase + (size_t)o * 256;
                n0.v = op[lane]; n1.v = op[64 + lane];
                n2.v = op[128 + lane]; n3.v = op[192 + lane];
            }
            VISIT(c0, c1, c2, c3);
            c0 = n0; c1 = n1; c2 = n2; c3 = n3;
            li = ln;
        }
    }

    // scatter C fragments to LDS in (b, oc) layout, padded stride 33
#pragma unroll
    for (int bh = 0; bh < 2; bh++) {
        int b = bh * 32 + row;
#pragma unroll
        for (int r = 0; r < 16; r++) {
            int oc = (r & 3) + 8 * (r >> 2) + 4 * kg;
            red[w][b * 33 + oc] = bh ? acc1[r] : acc0[r];
        }
    }
    __syncthreads();

    int t = threadIdx.x;
    size_t nb = (size_t)n * (NB * 32);
    if (deg > 0) {
        float inv = 1.f / (float)deg;
#pragma unroll
        for (int j = 0; j < 8; j++) {
            int idx = t * 8 + j;
            int bb = idx >> 5, cc = idx & 31;
            float s = red[0][bb * 33 + cc] + red[1][bb * 33 + cc] +
                      red[2][bb * 33 + cc] + red[3][bb * 33 + cc];
            s *= inv;
            if (!pass0) s += nv[nb + idx];
            nv[nb + idx] = s;
        }
    } else if (pass0) {
#pragma unroll
        for (int j = 0; j < 8; j++) nv[nb + t * 8 + j] = 0.f;
    }
}

// ---------------- final readout (2-stage, coalesced) ----------------
__global__ void k_final1(const float* __restrict__ nv,
                         const float* __restrict__ oW1, const float* __restrict__ ob1,
                         const float* __restrict__ oW2, const float* __restrict__ ob2,
                         float* __restrict__ fv) {
    int idx = blockIdx.x * 256 + threadIdx.x;  // 64000
    int n = idx >> 6, b = idx & 63;
    const float4* xp = (const float4*)(nv + ((size_t)n * NB + b) * 32);
    float x[32];
#pragma unroll
    for (int q = 0; q < 8; q++) {
        float4 v = xp[q];
        x[q * 4] = v.x; x[q * 4 + 1] = v.y; x[q * 4 + 2] = v.z; x[q * 4 + 3] = v.w;
    }
    float h[32];
#pragma unroll
    for (int oc = 0; oc < 32; oc++) {
        float s = ob1[oc];
#pragma unroll
        for (int c = 0; c < 32; c++) s += oW1[oc * 32 + c] * x[c];
        h[oc] = lrelu(s);
    }
    float s = ob2[0];
#pragma unroll
    for (int k = 0; k < 32; k++) s += oW2[k] * h[k];
    fv[idx] = lrelu(s);
}

__global__ void k_final2(const float* __restrict__ fv, const float* __restrict__ gW,
                         const float* __restrict__ gb, float* __restrict__ out) {
    int b = blockIdx.x;
    int t = threadIdx.x;
    float part = 0.f;
    for (int n = t; n < NN; n += 256) part += fv[n * 64 + b] * gW[n];
    __shared__ float rs[256];
    rs[t] = part;
    __syncthreads();
    for (int d = 128; d > 0; d >>= 1) {
        if (t < d) rs[t] += rs[t + d];
        __syncthreads();
    }
    if (t == 0) out[b] = 1.f / (1.f + expf(-(rs[0] + gb[0])));
}

extern "C" void kernel_launch(void* const* d_in, const int* in_sizes, int n_in,
                              void* d_out, int out_size, void* d_ws, size_t ws_size,
                              hipStream_t stream) {
    (void)in_sizes; (void)n_in; (void)out_size; (void)ws_size;
    const float* vert = (const float*)d_in[0];
    const int* edges  = (const int*)d_in[1];
    const float* xW   = (const float*)d_in[2];
    const float* xb   = (const float*)d_in[3];
    const float* yW   = (const float*)d_in[4];
    const float* yb   = (const float*)d_in[5];
    const float* tW   = (const float*)d_in[6];
    const float* tb   = (const float*)d_in[7];
    const float* cW1  = (const float*)d_in[8];
    const float* cb1  = (const float*)d_in[9];
    const float* cW2  = (const float*)d_in[10];
    const float* cb2  = (const float*)d_in[11];
    const float* vW1  = (const float*)d_in[12];
    const float* vb1  = (const float*)d_in[13];
    const float* vW2  = (const float*)d_in[14];
    const float* vb2  = (const float*)d_in[15];
    const float* eW1  = (const float*)d_in[16];
    const float* eb1  = (const float*)d_in[17];
    const float* eW2  = (const float*)d_in[18];
    const float* eb2  = (const float*)d_in[19];
    const float* aW1  = (const float*)d_in[20];
    const float* ab1  = (const float*)d_in[21];
    const float* aW2  = (const float*)d_in[22];
    const float* ab2  = (const float*)d_in[23];
    const float* oW1  = (const float*)d_in[24];
    const float* ob1  = (const float*)d_in[25];
    const float* oW2  = (const float*)d_in[26];
    const float* ob2  = (const float*)d_in[27];
    const float* gW   = (const float*)d_in[28];
    const float* gb   = (const float*)d_in[29];
    float* out = (float*)d_out;

    char* w = (char*)d_ws;
    short* Ap  = (short*)(w);                          // 4.1 MB
    short* Bp  = (short*)(w + (5u << 20));             // 4.1 MB
    float* nv  = (float*)(w + (10u << 20));            // 8.2 MB
    float* vt  = (float*)(w + (19u << 20));            // 2.8 MB
    float* fv  = (float*)(w + (22u << 20));            // 256 KB
    short* W2f = (short*)(w + (22u << 20) + (512u << 10)); // 2 KB
    float* B2f = (float*)(w + (22u << 20) + (520u << 10)); // 4 KB
    int* deg    = (int*)(w + (23u << 20));
    int* offs   = deg + 1024;
    int* cursor = offs + 1024;
    int* cntA   = cursor + 1024;
    int* adj    = cntA + 1024;                         // 32000 ints

    hipMemsetAsync(deg, 0, NN * sizeof(int), stream);
    k_tr<<<NN / 4, 256, 0, stream>>>(vert, vt);
    k_deg<<<(NE + 255) / 256, 256, 0, stream>>>(edges, deg);
    k_scan<<<1, 1024, 0, stream>>>(deg, offs, cursor);
    k_fillA<<<(NE + 255) / 256, 256, 0, stream>>>(edges, cursor, adj);
    k_sort<<<NN / 4, 256, 0, stream>>>(offs, adj, cntA);
    k_wsetup<<<1, 64, 0, stream>>>(eW2, eb2, W2f, B2f);

    k_prep0<<<(NB * NN) / 256, 256, 0, stream>>>(vt, xW, xb, yW, yb, tW, tb,
                                                 cW1, cb1, cW2, cb2, vW1, vb1, vW2, vb2,
                                                 eW1, eb1, Ap, Bp);
    k_edge<<<NN, 256, 0, stream>>>(Ap, Bp, offs, cntA, adj, W2f, B2f, nv, 1);

    for (int it = 0; it < 5; it++) {
        k_prep<<<(NB * NN) / 256, 256, 0, stream>>>(nv, vt, aW1, ab1, aW2, ab2,
                                                    eW1, eb1, Ap, Bp);
        k_edge<<<NN, 256, 0, stream>>>(Ap, Bp, offs, cntA, adj, W2f, B2f, nv, 0);
    }

    k_final1<<<(NB * NN) / 256, 256, 0, stream>>>(nv, oW1, ob1, oW2, ob2, fv);
    k_final2<<<NB, 256, 0, stream>>>(fv, gW, gb, out);
}

// Round 6
// 693.769 us; speedup vs baseline: 4.6712x; 1.0036x over previous
//
#include <hip/hip_runtime.h>
#include <hip/hip_bf16.h>
#include <cstdint>
#include <cstddef>

#define NB 64      // batch
#define NN 1000    // nodes
#define NE 16000   // edges
#define ADJCAP 256

typedef __attribute__((ext_vector_type(8))) short short8;
typedef __attribute__((ext_vector_type(16))) float f32x16;

__device__ __forceinline__ float lrelu(float x) { return fmaxf(x, 0.01f * x); }

__device__ __forceinline__ float bf2f(short s) {
    unsigned int u = ((unsigned int)(unsigned short)s) << 16;
    return __builtin_bit_cast(float, u);
}
__device__ __forceinline__ short f2bf(float f) {
    __hip_bfloat16 h = __float2bfloat16(f);
    return __builtin_bit_cast(short, h);
}

union S8 { short8 v; short e[8]; };

// Fragment layout per node (2048 bf16 = 4KB):
//   value (k=oc 0..31, b 0..63): kh=oc>>4, g=(oc>>3)&1, j=oc&7, bh=b>>5, bl=b&31
//   short index = n*2048 + ((kh*2+bh)*64 + g*32 + bl)*8 + j
// MFMA B-operand: lane l of fragment (kh,bh) holds k=kh*16+(l>>5)*8+j, b=bh*32+(l&31)

// ---------------- vert transpose: [b][n][11] -> vt[n][i][b] ----------------
__global__ void k_tr(const float* __restrict__ vert, float* __restrict__ vt) {
    __shared__ float s[2816];
    int n0 = blockIdx.x * 4;
    int t = threadIdx.x;
    int b = t >> 2, r = t & 3;
    const float* vp = vert + ((size_t)b * NN + n0 + r) * 11;
#pragma unroll
    for (int i = 0; i < 11; i++) s[r * 704 + i * 64 + b] = vp[i];
    __syncthreads();
    float* o = vt + (size_t)n0 * 704;
#pragma unroll
    for (int j = 0; j < 11; j++) o[j * 256 + t] = s[j * 256 + t];
}

// ---------------- CSR build ----------------
__global__ void k_deg(const int* __restrict__ edges, int* __restrict__ deg) {
    int e = blockIdx.x * 256 + threadIdx.x;
    if (e < NE) {
        atomicAdd(&deg[edges[e]], 1);
        atomicAdd(&deg[edges[NE + e]], 1);
    }
}

__global__ void k_scan(const int* __restrict__ deg, int* __restrict__ offs,
                       int* __restrict__ cursor) {
    __shared__ int s[1024];
    int t = threadIdx.x;
    int d = (t < NN) ? deg[t] : 0;
    s[t] = d;
    __syncthreads();
    for (int k = 1; k < 1024; k <<= 1) {
        int v = (t >= k) ? s[t - k] : 0;
        __syncthreads();
        s[t] += v;
        __syncthreads();
    }
    if (t < NN) {
        offs[t + 1] = s[t];
        cursor[t] = s[t] - d;   // exclusive prefix
    }
    if (t == 0) offs[0] = 0;
}

// atomic fill of packed incidences: (role<<30)|(edge<<10)|other
__global__ void k_fillA(const int* __restrict__ edges, int* __restrict__ cursor,
                        int* __restrict__ adj) {
    int e = blockIdx.x * 256 + threadIdx.x;
    if (e < NE) {
        int s = edges[e], d = edges[NE + e];
        int p1 = atomicAdd(&cursor[s], 1);
        adj[p1] = (e << 10) | d;               // role 0: s is src, other=dst
        int p2 = atomicAdd(&cursor[d], 1);
        adj[p2] = (1 << 30) | (e << 10) | s;   // role 1: d is dst, other=src
    }
}

// wave-parallel canonical rank sort: keys unique, rank = #{smaller keys}.
__global__ void k_sort(const int* __restrict__ offs, int* __restrict__ adj,
                       int* __restrict__ cntA) {
    __shared__ int keys[4][ADJCAP];
    int w = threadIdx.x >> 6;
    int lane = threadIdx.x & 63;
    int n = blockIdx.x * 4 + w;
    int o0 = offs[n], o1 = offs[n + 1];
    int deg = o1 - o0;
    int cap = (deg < ADJCAP) ? deg : ADJCAP;
    for (int i = lane; i < cap; i += 64) keys[w][i] = adj[o0 + i];
    __syncthreads();
    if (deg <= ADJCAP) {
        for (int i = lane; i < deg; i += 64) {
            int k = keys[w][i];
            int r = 0;
            for (int j = 0; j < deg; j++) r += (keys[w][j] < k) ? 1 : 0;
            adj[o0 + r] = k;
        }
        if (lane == 0) {
            int c = 0;
            for (int j = 0; j < deg; j++) c += ((keys[w][j] >> 30) & 1) ? 0 : 1;
            cntA[n] = c;
        }
    } else if (lane == 0) {
        for (int i = o0 + 1; i < o1; i++) {
            int key = adj[i];
            int j = i - 1;
            while (j >= o0 && adj[j] > key) { adj[j + 1] = adj[j]; j--; }
            adj[j + 1] = key;
        }
        int c = 0;
        for (int i = o0; i < o1; i++) c += ((adj[i] >> 30) & 1) ? 0 : 1;
        cntA[n] = c;
    }
}

// one-wave setup: pre-pack W2 MFMA A-fragments (bf16) and b2 in C-layout
__global__ void k_wsetup(const float* __restrict__ W2, const float* __restrict__ b2,
                         short* __restrict__ W2f, float* __restrict__ B2f) {
    int lane = threadIdx.x;  // 64
    int row = lane & 31, kg = lane >> 5;
    S8 a0, a1;
#pragma unroll
    for (int j = 0; j < 8; j++) {
        a0.e[j] = f2bf(W2[row * 32 + kg * 8 + j]);
        a1.e[j] = f2bf(W2[row * 32 + 16 + kg * 8 + j]);
    }
    ((short8*)W2f)[lane] = a0.v;
    ((short8*)W2f)[64 + lane] = a1.v;
#pragma unroll
    for (int r = 0; r < 16; r++)
        B2f[lane * 16 + r] = b2[(r & 3) + 8 * (r >> 2) + 4 * kg];
}

// store sa/sb (32 each) for (n,b) into fragment layout
__device__ __forceinline__ void store_frags(short* __restrict__ Ap, short* __restrict__ Bp,
                                            int n, int b, const float* sa, const float* sb) {
    int bh = b >> 5, bl = b & 31;
    size_t nodeb = (size_t)n * 2048;
#pragma unroll
    for (int kh = 0; kh < 2; kh++) {
#pragma unroll
        for (int g = 0; g < 2; g++) {
            size_t off = nodeb + ((size_t)(kh * 2 + bh) * 64 + g * 32 + bl) * 8;
            S8 pa, pb;
#pragma unroll
            for (int j = 0; j < 8; j++) {
                pa.e[j] = f2bf(sa[kh * 16 + g * 8 + j]);
                pb.e[j] = f2bf(sb[kh * 16 + g * 8 + j]);
            }
            *(short8*)(Ap + off) = pa.v;
            *(short8*)(Bp + off) = pb.v;
        }
    }
}

// ---------------- pass-0 node prep (reads transposed vt) ----------------
__global__ __launch_bounds__(256, 2) void k_prep0(
                        const float* __restrict__ vt,
                        const float* __restrict__ xW, const float* __restrict__ xb,
                        const float* __restrict__ yW, const float* __restrict__ yb,
                        const float* __restrict__ tW, const float* __restrict__ tb,
                        const float* __restrict__ cW1, const float* __restrict__ cb1,
                        const float* __restrict__ cW2, const float* __restrict__ cb2,
                        const float* __restrict__ vW1, const float* __restrict__ vb1,
                        const float* __restrict__ vW2, const float* __restrict__ vb2,
                        const float* __restrict__ eW1, const float* __restrict__ eb1,
                        short* __restrict__ Ap, short* __restrict__ Bp) {
    int idx = blockIdx.x * blockDim.x + threadIdx.x;
    int n = idx >> 6, b = idx & 63;
    const float* vn = vt + (size_t)n * 704;
    float vv[11];
#pragma unroll
    for (int i = 0; i < 11; i++) vv[i] = vn[i * 64 + b];

    // accumulate v1 per config-half so config goes dead immediately
    float v1a[32];
#pragma unroll
    for (int oc = 0; oc < 32; oc++) v1a[oc] = vb1[oc];

#pragma unroll
    for (int half = 0; half < 2; half++) {
        float f[24];
        const float* o = vv + (half ? 6 : 3);
        {
            const float* Ws[3] = {xW, yW, tW};
            const float* bs[3] = {xb, yb, tb};
#pragma unroll
            for (int i = 0; i < 3; i++) {
                float p0 = vv[i], p1 = o[i];
#pragma unroll
                for (int c = 0; c < 8; c++)
                    f[i * 8 + c] = lrelu(Ws[i][c * 2] * p0 + Ws[i][c * 2 + 1] * p1 + bs[i][c]);
            }
        }
        float h[32];
#pragma unroll
        for (int oc = 0; oc < 32; oc++) {
            float s = cb1[oc];
#pragma unroll
            for (int c = 0; c < 24; c++) s += cW1[oc * 24 + c] * f[c];
            h[oc] = lrelu(s);
        }
        float cfg[32];
#pragma unroll
        for (int oc = 0; oc < 32; oc++) {
            float s = cb2[oc];
#pragma unroll
            for (int c = 0; c < 32; c++) s += cW2[oc * 32 + c] * h[c];
            cfg[oc] = lrelu(s);
        }
#pragma unroll
        for (int oc = 0; oc < 32; oc++) {
            float s = v1a[oc];
#pragma unroll
            for (int c = 0; c < 32; c++) s += vW1[oc * 64 + half * 32 + c] * cfg[c];
            v1a[oc] = s;
        }
    }
    float v1[32];
#pragma unroll
    for (int oc = 0; oc < 32; oc++) v1[oc] = lrelu(v1a[oc]);

    float vf[34];
#pragma unroll
    for (int oc = 0; oc < 32; oc++) {
        float s = vb2[oc];
#pragma unroll
        for (int c = 0; c < 32; c++) s += vW2[oc * 32 + c] * v1[c];
        vf[oc] = lrelu(s);
    }
    vf[32] = vv[9]; vf[33] = vv[10];

    float sa[32], sb[32];
#pragma unroll
    for (int oc = 0; oc < 32; oc++) {
        float a = eb1[oc], bb = 0.f;
#pragma unroll
        for (int c = 0; c < 34; c++) {
            a  += eW1[oc * 68 + c] * vf[c];
            bb += eW1[oc * 68 + 34 + c] * vf[c];
        }
        sa[oc] = a; sb[oc] = bb;
    }
    store_frags(Ap, Bp, n, b, sa, sb);
}

// ---------------- per-iteration node prep ----------------
__global__ __launch_bounds__(256, 2) void k_prep(
                       const float* __restrict__ nv, const float* __restrict__ vt,
                       const float* __restrict__ aW1, const float* __restrict__ ab1,
                       const float* __restrict__ aW2, const float* __restrict__ ab2,
                       const float* __restrict__ eW1, const float* __restrict__ eb1,
                       short* __restrict__ Ap, short* __restrict__ Bp) {
    int idx = blockIdx.x * blockDim.x + threadIdx.x;
    int n = idx >> 6, b = idx & 63;
    const float4* xp = (const float4*)(nv + ((size_t)n * NB + b) * 32);
    float x[32];
#pragma unroll
    for (int q = 0; q < 8; q++) {
        float4 v = xp[q];
        x[q * 4] = v.x; x[q * 4 + 1] = v.y; x[q * 4 + 2] = v.z; x[q * 4 + 3] = v.w;
    }
    float h[32];
#pragma unroll
    for (int oc = 0; oc < 32; oc++) {
        float s = ab1[oc];
#pragma unroll
        for (int c = 0; c < 32; c++) s += aW1[oc * 32 + c] * x[c];
        h[oc] = lrelu(s);
    }
    float vf[34];
#pragma unroll
    for (int oc = 0; oc < 32; oc++) {
        float s = ab2[oc];
#pragma unroll
        for (int c = 0; c < 32; c++) s += aW2[oc * 32 + c] * h[c];
        vf[oc] = lrelu(s);
    }
    const float* vn = vt + (size_t)n * 704;
    vf[32] = vn[9 * 64 + b]; vf[33] = vn[10 * 64 + b];

    float sa[32], sb[32];
#pragma unroll
    for (int oc = 0; oc < 32; oc++) {
        float a = eb1[oc], bb = 0.f;
#pragma unroll
        for (int c = 0; c < 34; c++) {
            a  += eW1[oc * 68 + c] * vf[c];
            bb += eW1[oc * 68 + 34 + c] * vf[c];
        }
        sa[oc] = a; sb[oc] = bb;
    }
    store_frags(Ap, Bp, n, b, sa, sb);
}

// ---------------- edge pass: MFMA + LDS-adj + double-buffered og loads ----------------
#define VISIT(C0, C1, C2, C3) do {                                                        \
    S8 h10, h11;                                                                          \
    _Pragma("unroll") for (int j = 0; j < 8; j++) {                                       \
        float x0 = bfv[0][j] + bf2f(C0.e[j]); h10.e[j] = f2bf(fmaxf(x0, 0.01f * x0)); }   \
    _Pragma("unroll") for (int j = 0; j < 8; j++) {                                       \
        float x1 = bfv[2][j] + bf2f(C2.e[j]); h11.e[j] = f2bf(fmaxf(x1, 0.01f * x1)); }   \
    f32x16 d = __builtin_amdgcn_mfma_f32_32x32x16_bf16(w2f0.v, h10.v, zero, 0, 0, 0);     \
    d = __builtin_amdgcn_mfma_f32_32x32x16_bf16(w2f1.v, h11.v, d, 0, 0, 0);               \
    _Pragma("unroll") for (int r = 0; r < 16; r++) {                                      \
        float m = d[r] + b2v[r]; acc0[r] += fmaxf(m, 0.01f * m); }                        \
    _Pragma("unroll") for (int j = 0; j < 8; j++) {                                       \
        float x0 = bfv[1][j] + bf2f(C1.e[j]); h10.e[j] = f2bf(fmaxf(x0, 0.01f * x0)); }   \
    _Pragma("unroll") for (int j = 0; j < 8; j++) {                                       \
        float x1 = bfv[3][j] + bf2f(C3.e[j]); h11.e[j] = f2bf(fmaxf(x1, 0.01f * x1)); }   \
    d = __builtin_amdgcn_mfma_f32_32x32x16_bf16(w2f0.v, h10.v, zero, 0, 0, 0);            \
    d = __builtin_amdgcn_mfma_f32_32x32x16_bf16(w2f1.v, h11.v, d, 0, 0, 0);               \
    _Pragma("unroll") for (int r = 0; r < 16; r++) {                                      \
        float m = d[r] + b2v[r]; acc1[r] += fmaxf(m, 0.01f * m); }                        \
} while (0)

__global__ __launch_bounds__(256) void k_edge(
    const short* __restrict__ Ap, const short* __restrict__ Bp,
    const int* __restrict__ offs, const int* __restrict__ cntA,
    const int* __restrict__ adjg,
    const short* __restrict__ W2f, const float* __restrict__ B2f,
    float* __restrict__ nv, int pass0) {
    __shared__ float red[4][64 * 33];
    __shared__ int adjl[ADJCAP];
    int n = blockIdx.x;
    int w = threadIdx.x >> 6;
    int lane = threadIdx.x & 63;
    int row = lane & 31, kg = lane >> 5;

    int off0 = offs[n], off1 = offs[n + 1];
    int deg = off1 - off0;
    int cA = cntA[n];

    for (int i = threadIdx.x; i < deg && i < ADJCAP; i += 256)
        adjl[i] = adjg[off0 + i] & 1023;
    __syncthreads();

    // pre-packed W2 A-fragments + b2 (C layout)
    S8 w2f0, w2f1;
    w2f0.v = ((const short8*)W2f)[lane];
    w2f1.v = ((const short8*)W2f)[64 + lane];
    float b2v[16];
    {
        const float4* bp4 = (const float4*)(B2f + lane * 16);
#pragma unroll
        for (int q = 0; q < 4; q++) {
            float4 v = bp4[q];
            b2v[q * 4] = v.x; b2v[q * 4 + 1] = v.y;
            b2v[q * 4 + 2] = v.z; b2v[q * 4 + 3] = v.w;
        }
    }

    f32x16 acc0 = {};
    f32x16 acc1 = {};
    const f32x16 zero = {};

#pragma unroll
    for (int phase = 0; phase < 2; phase++) {
        const short* basePtr = phase ? Bp : Ap;
        const short8* ogBase = (const short8*)(phase ? Ap : Bp);
        int lstart = phase ? cA : 0;
        int lend   = phase ? deg : cA;

        float bfv[4][8];
        {
            const short8* np = (const short8*)(basePtr + (size_t)n * 2048);
#pragma unroll
            for (int f = 0; f < 4; f++) {
                S8 t; t.v = np[f * 64 + lane];
#pragma unroll
                for (int j = 0; j < 8; j++) bfv[f][j] = bf2f(t.e[j]);
            }
        }

        int li = lstart + w;
        S8 c0 = {}, c1 = {}, c2 = {}, c3 = {};
        if (li < lend) {
            int o = (li < ADJCAP) ? adjl[li] : (adjg[off0 + li] & 1023);
            const short8* op = ogBase + (size_t)o * 256;
            c0.v = op[lane]; c1.v = op[64 + lane];
            c2.v = op[128 + lane]; c3.v = op[192 + lane];
        }
        while (li < lend) {
            int ln = li + 4;
            S8 n0 = {}, n1 = {}, n2 = {}, n3 = {};
            if (ln < lend) {
                int o = (ln < ADJCAP) ? adjl[ln] : (adjg[off0 + ln] & 1023);
                const short8* op = ogBase + (size_t)o * 256;
                n0.v = op[lane]; n1.v = op[64 + lane];
                n2.v = op[128 + lane]; n3.v = op[192 + lane];
            }
            VISIT(c0, c1, c2, c3);
            c0 = n0; c1 = n1; c2 = n2; c3 = n3;
            li = ln;
        }
    }

    // scatter C fragments to LDS in (b, oc) layout, padded stride 33
#pragma unroll
    for (int bh = 0; bh < 2; bh++) {
        int b = bh * 32 + row;
#pragma unroll
        for (int r = 0; r < 16; r++) {
            int oc = (r & 3) + 8 * (r >> 2) + 4 * kg;
            red[w][b * 33 + oc] = bh ? acc1[r] : acc0[r];
        }
    }
    __syncthreads();

    int t = threadIdx.x;
    size_t nb = (size_t)n * (NB * 32);
    if (deg > 0) {
        float inv = 1.f / (float)deg;
#pragma unroll
        for (int j = 0; j < 8; j++) {
            int idx = t * 8 + j;
            int bb = idx >> 5, cc = idx & 31;
            float s = red[0][bb * 33 + cc] + red[1][bb * 33 + cc] +
                      red[2][bb * 33 + cc] + red[3][bb * 33 + cc];
            s *= inv;
            if (!pass0) s += nv[nb + idx];
            nv[nb + idx] = s;
        }
    } else if (pass0) {
#pragma unroll
        for (int j = 0; j < 8; j++) nv[nb + t * 8 + j] = 0.f;
    }
}

// ---------------- final readout (2-stage, coalesced) ----------------
__global__ __launch_bounds__(256, 2) void k_final1(
                         const float* __restrict__ nv,
                         const float* __restrict__ oW1, const float* __restrict__ ob1,
                         const float* __restrict__ oW2, const float* __restrict__ ob2,
                         float* __restrict__ fv) {
    int idx = blockIdx.x * 256 + threadIdx.x;  // 64000
    int n = idx >> 6, b = idx & 63;
    const float4* xp = (const float4*)(nv + ((size_t)n * NB + b) * 32);
    float x[32];
#pragma unroll
    for (int q = 0; q < 8; q++) {
        float4 v = xp[q];
        x[q * 4] = v.x; x[q * 4 + 1] = v.y; x[q * 4 + 2] = v.z; x[q * 4 + 3] = v.w;
    }
    float h[32];
#pragma unroll
    for (int oc = 0; oc < 32; oc++) {
        float s = ob1[oc];
#pragma unroll
        for (int c = 0; c < 32; c++) s += oW1[oc * 32 + c] * x[c];
        h[oc] = lrelu(s);
    }
    float s = ob2[0];
#pragma unroll
    for (int k = 0; k < 32; k++) s += oW2[k] * h[k];
    fv[idx] = lrelu(s);
}

__global__ void k_final2(const float* __restrict__ fv, const float* __restrict__ gW,
                         const float* __restrict__ gb, float* __restrict__ out) {
    int b = blockIdx.x;
    int t = threadIdx.x;
    float part = 0.f;
    for (int n = t; n < NN; n += 256) part += fv[n * 64 + b] * gW[n];
    __shared__ float rs[256];
    rs[t] = part;
    __syncthreads();
    for (int d = 128; d > 0; d >>= 1) {
        if (t < d) rs[t] += rs[t + d];
        __syncthreads();
    }
    if (t == 0) out[b] = 1.f / (1.f + expf(-(rs[0] + gb[0])));
}

extern "C" void kernel_launch(void* const* d_in, const int* in_sizes, int n_in,
                              void* d_out, int out_size, void* d_ws, size_t ws_size,
                              hipStream_t stream) {
    (void)in_sizes; (void)n_in; (void)out_size; (void)ws_size;
    const float* vert = (const float*)d_in[0];
    const int* edges  = (const int*)d_in[1];
    const float* xW   = (const float*)d_in[2];
    const float* xb   = (const float*)d_in[3];
    const float* yW   = (const float*)d_in[4];
    const float* yb   = (const float*)d_in[5];
    const float* tW   = (const float*)d_in[6];
    const float* tb   = (const float*)d_in[7];
    const float* cW1  = (const float*)d_in[8];
    const float* cb1  = (const float*)d_in[9];
    const float* cW2  = (const float*)d_in[10];
    const float* cb2  = (const float*)d_in[11];
    const float* vW1  = (const float*)d_in[12];
    const float* vb1  = (const float*)d_in[13];
    const float* vW2  = (const float*)d_in[14];
    const float* vb2  = (const float*)d_in[15];
    const float* eW1  = (const float*)d_in[16];
    const float* eb1  = (const float*)d_in[17];
    const float* eW2  = (const float*)d_in[18];
    const float* eb2  = (const float*)d_in[19];
    const float* aW1  = (const float*)d_in[20];
    const float* ab1  = (const float*)d_in[21];
    const float* aW2  = (const float*)d_in[22];
    const float* ab2  = (const float*)d_in[23];
    const float* oW1  = (const float*)d_in[24];
    const float* ob1  = (const float*)d_in[25];
    const float* oW2  = (const float*)d_in[26];
    const float* ob2  = (const float*)d_in[27];
    const float* gW   = (const float*)d_in[28];
    const float* gb   = (const float*)d_in[29];
    float* out = (float*)d_out;

    char* w = (char*)d_ws;
    short* Ap  = (short*)(w);                          // 4.1 MB
    short* Bp  = (short*)(w + (5u << 20));             // 4.1 MB
    float* nv  = (float*)(w + (10u << 20));            // 8.2 MB
    float* vt  = (float*)(w + (19u << 20));            // 2.8 MB
    float* fv  = (float*)(w + (22u << 20));            // 256 KB
    short* W2f = (short*)(w + (22u << 20) + (512u << 10)); // 2 KB
    float* B2f = (float*)(w + (22u << 20) + (520u << 10)); // 4 KB
    int* deg    = (int*)(w + (23u << 20));
    int* offs   = deg + 1024;
    int* cursor = offs + 1024;
    int* cntA   = cursor + 1024;
    int* adj    = cntA + 1024;                         // 32000 ints

    hipMemsetAsync(deg, 0, NN * sizeof(int), stream);
    k_tr<<<NN / 4, 256, 0, stream>>>(vert, vt);
    k_deg<<<(NE + 255) / 256, 256, 0, stream>>>(edges, deg);
    k_scan<<<1, 1024, 0, stream>>>(deg, offs, cursor);
    k_fillA<<<(NE + 255) / 256, 256, 0, stream>>>(edges, cursor, adj);
    k_sort<<<NN / 4, 256, 0, stream>>>(offs, adj, cntA);
    k_wsetup<<<1, 64, 0, stream>>>(eW2, eb2, W2f, B2f);

    k_prep0<<<(NB * NN) / 256, 256, 0, stream>>>(vt, xW, xb, yW, yb, tW, tb,
                                                 cW1, cb1, cW2, cb2, vW1, vb1, vW2, vb2,
                                                 eW1, eb1, Ap, Bp);
    k_edge<<<NN, 256, 0, stream>>>(Ap, Bp, offs, cntA, adj, W2f, B2f, nv, 1);

    for (int it = 0; it < 5; it++) {
        k_prep<<<(NB * NN) / 256, 256, 0, stream>>>(nv, vt, aW1, ab1, aW2, ab2,
                                                    eW1, eb1, Ap, Bp);
        k_edge<<<NN, 256, 0, stream>>>(Ap, Bp, offs, cntA, adj, W2f, B2f, nv, 0);
    }

    k_final1<<<(NB * NN) / 256, 256, 0, stream>>>(nv, oW1, ob1, oW2, ob2, fv);
    k_final2<<<NB, 256, 0, stream>>>(fv, gW, gb, out);
}

// Round 7
// 393.091 us; speedup vs baseline: 8.2442x; 1.7649x over previous
//
#include <hip/hip_runtime.h>
#include <hip/hip_bf16.h>
#include <cstdint>
#include <cstddef>

#define NB 64      // batch
#define NN 1000    // nodes
#define NE 16000   // edges
#define ADJCAP 256

typedef __attribute__((ext_vector_type(8))) short short8;
typedef __attribute__((ext_vector_type(16))) float f32x16;

__device__ __forceinline__ float lrelu(float x) { return fmaxf(x, 0.01f * x); }

__device__ __forceinline__ float bf2f(short s) {
    unsigned int u = ((unsigned int)(unsigned short)s) << 16;
    return __builtin_bit_cast(float, u);
}
__device__ __forceinline__ short f2bf(float f) {
    __hip_bfloat16 h = __float2bfloat16(f);
    return __builtin_bit_cast(short, h);
}

union S8 { short8 v; short e[8]; };

// Fragment layout per node (2048 bf16 = 4KB):
//   value (k 0..31, b 0..63): fragment f=kh*2+bh, within-fragment lane=g*32+bl
//   short8 index = n*256 + f*64 + lane ; lane holds k=kh*16+(lane>>5)*8+j, b=bh*32+(lane&31)
// C layout (32x32 mfma): col=lane&31, row(r)=(r&3)+8*(r>>2)+4*(lane>>5)

// wpk (pre-packed weights) byte offsets:
//  0     W2f   (short8[128])   eW2 A-frags
//  2048  aW1f  (short8[128])
//  4096  aW2f  (short8[128])
//  6144  eAf   (short8[128])   eW1[:, 0:32]  A-frags
//  8192  eBf   (short8[128])   eW1[:,34:66]  A-frags
//  10240 vo1f  (short8[128])
//  12288 B2f   (float[1024])   eb2  in C layout
//  16384 aB1c  (float[1024])
//  20480 aB2c  (float[1024])
//  24576 eB1c  (float[1024])   eb1 (sa bias)
//  28672 vo1bc (float[1024])
//  32768 Ea32  (float[1024])   eW1[row][32] in C layout
//  36864 Ea33  (float[1024])
//  40960 Eb32  (float[1024])   eW1[row][66]
//  45056 Eb33  (float[1024])   eW1[row][67]

// ---------------- vert transpose: [b][n][11] -> vt[n][i][b] ----------------
__global__ void k_tr(const float* __restrict__ vert, float* __restrict__ vt) {
    __shared__ float s[2816];
    int n0 = blockIdx.x * 4;
    int t = threadIdx.x;
    int b = t >> 2, r = t & 3;
    const float* vp = vert + ((size_t)b * NN + n0 + r) * 11;
#pragma unroll
    for (int i = 0; i < 11; i++) s[r * 704 + i * 64 + b] = vp[i];
    __syncthreads();
    float* o = vt + (size_t)n0 * 704;
#pragma unroll
    for (int j = 0; j < 11; j++) o[j * 256 + t] = s[j * 256 + t];
}

// ---------------- CSR build ----------------
__global__ void k_deg(const int* __restrict__ edges, int* __restrict__ deg) {
    int e = blockIdx.x * 256 + threadIdx.x;
    if (e < NE) {
        atomicAdd(&deg[edges[e]], 1);
        atomicAdd(&deg[edges[NE + e]], 1);
    }
}

__global__ void k_scan(const int* __restrict__ deg, int* __restrict__ offs,
                       int* __restrict__ cursor) {
    __shared__ int s[1024];
    int t = threadIdx.x;
    int d = (t < NN) ? deg[t] : 0;
    s[t] = d;
    __syncthreads();
    for (int k = 1; k < 1024; k <<= 1) {
        int v = (t >= k) ? s[t - k] : 0;
        __syncthreads();
        s[t] += v;
        __syncthreads();
    }
    if (t < NN) {
        offs[t + 1] = s[t];
        cursor[t] = s[t] - d;
    }
    if (t == 0) offs[0] = 0;
}

__global__ void k_fillA(const int* __restrict__ edges, int* __restrict__ cursor,
                        int* __restrict__ adj) {
    int e = blockIdx.x * 256 + threadIdx.x;
    if (e < NE) {
        int s = edges[e], d = edges[NE + e];
        int p1 = atomicAdd(&cursor[s], 1);
        adj[p1] = (e << 10) | d;
        int p2 = atomicAdd(&cursor[d], 1);
        adj[p2] = (1 << 30) | (e << 10) | s;
    }
}

// wave-parallel canonical rank sort (keys unique -> deterministic order)
__global__ void k_sort(const int* __restrict__ offs, int* __restrict__ adj,
                       int* __restrict__ cntA) {
    __shared__ int keys[4][ADJCAP];
    int w = threadIdx.x >> 6;
    int lane = threadIdx.x & 63;
    int n = blockIdx.x * 4 + w;
    int o0 = offs[n], o1 = offs[n + 1];
    int deg = o1 - o0;
    int cap = (deg < ADJCAP) ? deg : ADJCAP;
    for (int i = lane; i < cap; i += 64) keys[w][i] = adj[o0 + i];
    __syncthreads();
    if (deg <= ADJCAP) {
        for (int i = lane; i < deg; i += 64) {
            int k = keys[w][i];
            int r = 0;
            for (int j = 0; j < deg; j++) r += (keys[w][j] < k) ? 1 : 0;
            adj[o0 + r] = k;
        }
        if (lane == 0) {
            int c = 0;
            for (int j = 0; j < deg; j++) c += ((keys[w][j] >> 30) & 1) ? 0 : 1;
            cntA[n] = c;
        }
    } else if (lane == 0) {
        for (int i = o0 + 1; i < o1; i++) {
            int key = adj[i];
            int j = i - 1;
            while (j >= o0 && adj[j] > key) { adj[j + 1] = adj[j]; j--; }
            adj[j + 1] = key;
        }
        int c = 0;
        for (int i = o0; i < o1; i++) c += ((adj[i] >> 30) & 1) ? 0 : 1;
        cntA[n] = c;
    }
}

// ---------------- weight pre-pack (one wave) ----------------
__global__ void k_wsetup2(const float* __restrict__ eW2, const float* __restrict__ eb2,
                          const float* __restrict__ aW1, const float* __restrict__ ab1,
                          const float* __restrict__ aW2, const float* __restrict__ ab2,
                          const float* __restrict__ eW1, const float* __restrict__ eb1,
                          const float* __restrict__ oW1, const float* __restrict__ ob1,
                          char* __restrict__ wpk) {
    int l = threadIdx.x;  // 64
    int row = l & 31, kg = l >> 5;

    auto packA = [&](const float* W, int ldw, int coff, short8* dst) {
#pragma unroll
        for (int kh = 0; kh < 2; kh++) {
            S8 a;
#pragma unroll
            for (int j = 0; j < 8; j++)
                a.e[j] = f2bf(W[row * ldw + coff + kh * 16 + kg * 8 + j]);
            dst[kh * 64 + l] = a.v;
        }
    };
    packA(eW2, 32, 0, (short8*)(wpk + 0));
    packA(aW1, 32, 0, (short8*)(wpk + 2048));
    packA(aW2, 32, 0, (short8*)(wpk + 4096));
    packA(eW1, 68, 0, (short8*)(wpk + 6144));
    packA(eW1, 68, 34, (short8*)(wpk + 8192));
    packA(oW1, 32, 0, (short8*)(wpk + 10240));

    float* B2f   = (float*)(wpk + 12288);
    float* aB1c  = (float*)(wpk + 16384);
    float* aB2c  = (float*)(wpk + 20480);
    float* eB1c  = (float*)(wpk + 24576);
    float* vo1bc = (float*)(wpk + 28672);
    float* Ea32  = (float*)(wpk + 32768);
    float* Ea33  = (float*)(wpk + 36864);
    float* Eb32  = (float*)(wpk + 40960);
    float* Eb33  = (float*)(wpk + 45056);
#pragma unroll
    for (int r = 0; r < 16; r++) {
        int rr = (r & 3) + 8 * (r >> 2) + 4 * kg;
        B2f[l * 16 + r]   = eb2[rr];
        aB1c[l * 16 + r]  = ab1[rr];
        aB2c[l * 16 + r]  = ab2[rr];
        eB1c[l * 16 + r]  = eb1[rr];
        vo1bc[l * 16 + r] = ob1[rr];
        Ea32[l * 16 + r]  = eW1[rr * 68 + 32];
        Ea33[l * 16 + r]  = eW1[rr * 68 + 33];
        Eb32[l * 16 + r]  = eW1[rr * 68 + 66];
        Eb33[l * 16 + r]  = eW1[rr * 68 + 67];
    }
}

// store sa/sb (32 each) for (n,b) into fragment layout
__device__ __forceinline__ void store_frags(short* __restrict__ Ap, short* __restrict__ Bp,
                                            int n, int b, const float* sa, const float* sb) {
    int bh = b >> 5, bl = b & 31;
    size_t nodeb = (size_t)n * 2048;
#pragma unroll
    for (int kh = 0; kh < 2; kh++) {
#pragma unroll
        for (int g = 0; g < 2; g++) {
            size_t off = nodeb + ((size_t)(kh * 2 + bh) * 64 + g * 32 + bl) * 8;
            S8 pa, pb;
#pragma unroll
            for (int j = 0; j < 8; j++) {
                pa.e[j] = f2bf(sa[kh * 16 + g * 8 + j]);
                pb.e[j] = f2bf(sb[kh * 16 + g * 8 + j]);
            }
            *(short8*)(Ap + off) = pa.v;
            *(short8*)(Bp + off) = pb.v;
        }
    }
}

// ---------------- pass-0 node prep (reads transposed vt) ----------------
__global__ __launch_bounds__(256, 2) void k_prep0(
                        const float* __restrict__ vt,
                        const float* __restrict__ xW, const float* __restrict__ xb,
                        const float* __restrict__ yW, const float* __restrict__ yb,
                        const float* __restrict__ tW, const float* __restrict__ tb,
                        const float* __restrict__ cW1, const float* __restrict__ cb1,
                        const float* __restrict__ cW2, const float* __restrict__ cb2,
                        const float* __restrict__ vW1, const float* __restrict__ vb1,
                        const float* __restrict__ vW2, const float* __restrict__ vb2,
                        const float* __restrict__ eW1, const float* __restrict__ eb1,
                        short* __restrict__ Ap, short* __restrict__ Bp) {
    int idx = blockIdx.x * blockDim.x + threadIdx.x;
    int n = idx >> 6, b = idx & 63;
    const float* vn = vt + (size_t)n * 704;
    float vv[11];
#pragma unroll
    for (int i = 0; i < 11; i++) vv[i] = vn[i * 64 + b];

    float v1a[32];
#pragma unroll
    for (int oc = 0; oc < 32; oc++) v1a[oc] = vb1[oc];

#pragma unroll
    for (int half = 0; half < 2; half++) {
        float f[24];
        const float* o = vv + (half ? 6 : 3);
        {
            const float* Ws[3] = {xW, yW, tW};
            const float* bs[3] = {xb, yb, tb};
#pragma unroll
            for (int i = 0; i < 3; i++) {
                float p0 = vv[i], p1 = o[i];
#pragma unroll
                for (int c = 0; c < 8; c++)
                    f[i * 8 + c] = lrelu(Ws[i][c * 2] * p0 + Ws[i][c * 2 + 1] * p1 + bs[i][c]);
            }
        }
        float h[32];
#pragma unroll
        for (int oc = 0; oc < 32; oc++) {
            float s = cb1[oc];
#pragma unroll
            for (int c = 0; c < 24; c++) s += cW1[oc * 24 + c] * f[c];
            h[oc] = lrelu(s);
        }
        float cfg[32];
#pragma unroll
        for (int oc = 0; oc < 32; oc++) {
            float s = cb2[oc];
#pragma unroll
            for (int c = 0; c < 32; c++) s += cW2[oc * 32 + c] * h[c];
            cfg[oc] = lrelu(s);
        }
#pragma unroll
        for (int oc = 0; oc < 32; oc++) {
            float s = v1a[oc];
#pragma unroll
            for (int c = 0; c < 32; c++) s += vW1[oc * 64 + half * 32 + c] * cfg[c];
            v1a[oc] = s;
        }
    }
    float v1[32];
#pragma unroll
    for (int oc = 0; oc < 32; oc++) v1[oc] = lrelu(v1a[oc]);

    float vf[34];
#pragma unroll
    for (int oc = 0; oc < 32; oc++) {
        float s = vb2[oc];
#pragma unroll
        for (int c = 0; c < 32; c++) s += vW2[oc * 32 + c] * v1[c];
        vf[oc] = lrelu(s);
    }
    vf[32] = vv[9]; vf[33] = vv[10];

    float sa[32], sb[32];
#pragma unroll
    for (int oc = 0; oc < 32; oc++) {
        float a = eb1[oc], bb = 0.f;
#pragma unroll
        for (int c = 0; c < 34; c++) {
            a  += eW1[oc * 68 + c] * vf[c];
            bb += eW1[oc * 68 + 34 + c] * vf[c];
        }
        sa[oc] = a; sb[oc] = bb;
    }
    store_frags(Ap, Bp, n, b, sa, sb);
}

// ---------------- fused edge pass + node prep (or vo readout) ----------------
#define VISIT(C0, C1, C2, C3) do {                                                        \
    S8 h10, h11;                                                                          \
    _Pragma("unroll") for (int j = 0; j < 8; j++) {                                       \
        float x0 = bfv[0][j] + bf2f(C0.e[j]); h10.e[j] = f2bf(fmaxf(x0, 0.01f * x0)); }   \
    _Pragma("unroll") for (int j = 0; j < 8; j++) {                                       \
        float x1 = bfv[2][j] + bf2f(C2.e[j]); h11.e[j] = f2bf(fmaxf(x1, 0.01f * x1)); }   \
    f32x16 d = __builtin_amdgcn_mfma_f32_32x32x16_bf16(w2f0.v, h10.v, zero, 0, 0, 0);     \
    d = __builtin_amdgcn_mfma_f32_32x32x16_bf16(w2f1.v, h11.v, d, 0, 0, 0);               \
    _Pragma("unroll") for (int r = 0; r < 16; r++) {                                      \
        float m = d[r] + b2v[r]; acc0[r] += fmaxf(m, 0.01f * m); }                        \
    _Pragma("unroll") for (int j = 0; j < 8; j++) {                                       \
        float x0 = bfv[1][j] + bf2f(C1.e[j]); h10.e[j] = f2bf(fmaxf(x0, 0.01f * x0)); }   \
    _Pragma("unroll") for (int j = 0; j < 8; j++) {                                       \
        float x1 = bfv[3][j] + bf2f(C3.e[j]); h11.e[j] = f2bf(fmaxf(x1, 0.01f * x1)); }   \
    d = __builtin_amdgcn_mfma_f32_32x32x16_bf16(w2f0.v, h10.v, zero, 0, 0, 0);            \
    d = __builtin_amdgcn_mfma_f32_32x32x16_bf16(w2f1.v, h11.v, d, 0, 0, 0);               \
    _Pragma("unroll") for (int r = 0; r < 16; r++) {                                      \
        float m = d[r] + b2v[r]; acc1[r] += fmaxf(m, 0.01f * m); }                        \
} while (0)

__global__ __launch_bounds__(256) void k_edge(
    const short* __restrict__ Apr, const short* __restrict__ Bpr,
    short* __restrict__ Apw, short* __restrict__ Bpw,
    const int* __restrict__ offs, const int* __restrict__ cntA,
    const int* __restrict__ adjg, const char* __restrict__ wpk,
    const float* __restrict__ vt, float* __restrict__ nv, float* __restrict__ fv,
    const float* __restrict__ oW2, const float* __restrict__ ob2,
    int pass0, int mode) {
    __shared__ float red[4][2112];
    __shared__ int adjl[ADJCAP];
    int n = blockIdx.x;
    int w = threadIdx.x >> 6;
    int lane = threadIdx.x & 63;
    int row = lane & 31, kg = lane >> 5;

    int off0 = offs[n], off1 = offs[n + 1];
    int deg = off1 - off0;
    int cA = cntA[n];

    for (int i = threadIdx.x; i < deg && i < ADJCAP; i += 256)
        adjl[i] = adjg[off0 + i] & 1023;
    __syncthreads();

    // ---- edge accumulation ----
    S8 w2f0, w2f1;
    w2f0.v = ((const short8*)wpk)[lane];
    w2f1.v = ((const short8*)wpk)[64 + lane];
    float b2v[16];
    {
        const float4* bp4 = (const float4*)((const float*)(wpk + 12288) + lane * 16);
#pragma unroll
        for (int q = 0; q < 4; q++) {
            float4 v = bp4[q];
            b2v[q * 4] = v.x; b2v[q * 4 + 1] = v.y;
            b2v[q * 4 + 2] = v.z; b2v[q * 4 + 3] = v.w;
        }
    }

    f32x16 acc0 = {};
    f32x16 acc1 = {};
    const f32x16 zero = {};

#pragma unroll
    for (int phase = 0; phase < 2; phase++) {
        const short* basePtr = phase ? Bpr : Apr;
        const short8* ogBase = (const short8*)(phase ? Apr : Bpr);
        int lstart = phase ? cA : 0;
        int lend   = phase ? deg : cA;

        float bfv[4][8];
        {
            const short8* np = (const short8*)(basePtr + (size_t)n * 2048);
#pragma unroll
            for (int f = 0; f < 4; f++) {
                S8 t; t.v = np[f * 64 + lane];
#pragma unroll
                for (int j = 0; j < 8; j++) bfv[f][j] = bf2f(t.e[j]);
            }
        }

        int li = lstart + w;
        S8 c0 = {}, c1 = {}, c2 = {}, c3 = {};
        if (li < lend) {
            int o = (li < ADJCAP) ? adjl[li] : (adjg[off0 + li] & 1023);
            const short8* op = ogBase + (size_t)o * 256;
            c0.v = op[lane]; c1.v = op[64 + lane];
            c2.v = op[128 + lane]; c3.v = op[192 + lane];
        }
        while (li < lend) {
            int ln = li + 4;
            S8 n0 = {}, n1 = {}, n2 = {}, n3 = {};
            if (ln < lend) {
                int o = (ln < ADJCAP) ? adjl[ln] : (adjg[off0 + ln] & 1023);
                const short8* op = ogBase + (size_t)o * 256;
                n0.v = op[lane]; n1.v = op[64 + lane];
                n2.v = op[128 + lane]; n3.v = op[192 + lane];
            }
            VISIT(c0, c1, c2, c3);
            c0 = n0; c1 = n1; c2 = n2; c3 = n3;
            li = ln;
        }
    }

    // ---- cross-wave reduce, nv update, stash new nv in red[0] as (b,oc) ----
#pragma unroll
    for (int bh = 0; bh < 2; bh++) {
        int b = bh * 32 + row;
#pragma unroll
        for (int r = 0; r < 16; r++) {
            int oc = (r & 3) + 8 * (r >> 2) + 4 * kg;
            red[w][b * 33 + oc] = bh ? acc1[r] : acc0[r];
        }
    }
    __syncthreads();

    {
        int t = threadIdx.x;
        size_t nb = (size_t)n * (NB * 32);
        float inv = (deg > 0) ? 1.f / (float)deg : 0.f;
#pragma unroll
        for (int j = 0; j < 8; j++) {
            int idx = t * 8 + j;
            int bb = idx >> 5, cc = idx & 31;
            float s;
            if (deg > 0) {
                s = (red[0][bb * 33 + cc] + red[1][bb * 33 + cc] +
                     red[2][bb * 33 + cc] + red[3][bb * 33 + cc]) * inv;
                if (!pass0) s += nv[nb + idx];
            } else {
                s = pass0 ? 0.f : nv[nb + idx];
            }
            nv[nb + idx] = s;
            red[0][bb * 33 + cc] = s;
        }
    }
    __syncthreads();

    // ---- fused node prep (waves 0,1; each owns one 32-col half) ----
    if (w < 2) {
        int bh = w;
        int lane31 = lane & 31;
        int g8 = (lane >> 5) * 8;
        float* loc = red[2 + w];
        const float* cb;   // C-layout table base helper
        S8 a0, a1;

        // x fragments from red[0]
        S8 xf0, xf1;
#pragma unroll
        for (int j = 0; j < 8; j++) {
            xf0.e[j] = f2bf(red[0][(bh * 32 + lane31) * 33 + g8 + j]);
            xf1.e[j] = f2bf(red[0][(bh * 32 + lane31) * 33 + 16 + g8 + j]);
        }

        if (mode == 0) {
            // layer 1: h = lrelu(aW1 x + ab1)
            a0.v = ((const short8*)(wpk + 2048))[lane];
            a1.v = ((const short8*)(wpk + 2048))[64 + lane];
            f32x16 C = {};
            C = __builtin_amdgcn_mfma_f32_32x32x16_bf16(a0.v, xf0.v, C, 0, 0, 0);
            C = __builtin_amdgcn_mfma_f32_32x32x16_bf16(a1.v, xf1.v, C, 0, 0, 0);
            cb = (const float*)(wpk + 16384) + lane * 16;
#pragma unroll
            for (int r = 0; r < 16; r++) { float m = C[r] + cb[r]; C[r] = fmaxf(m, 0.01f * m); }
#pragma unroll
            for (int r = 0; r < 16; r++) {
                int oc = (r & 3) + 8 * (r >> 2) + 4 * kg;
                loc[lane31 * 33 + oc] = C[r];
            }
            // layer 2: vf = lrelu(aW2 h + ab2)
            S8 hf0, hf1;
#pragma unroll
            for (int j = 0; j < 8; j++) {
                hf0.e[j] = f2bf(loc[lane31 * 33 + g8 + j]);
                hf1.e[j] = f2bf(loc[lane31 * 33 + 16 + g8 + j]);
            }
            a0.v = ((const short8*)(wpk + 4096))[lane];
            a1.v = ((const short8*)(wpk + 4096))[64 + lane];
            f32x16 V = {};
            V = __builtin_amdgcn_mfma_f32_32x32x16_bf16(a0.v, hf0.v, V, 0, 0, 0);
            V = __builtin_amdgcn_mfma_f32_32x32x16_bf16(a1.v, hf1.v, V, 0, 0, 0);
            cb = (const float*)(wpk + 20480) + lane * 16;
#pragma unroll
            for (int r = 0; r < 16; r++) { float m = V[r] + cb[r]; V[r] = fmaxf(m, 0.01f * m); }
#pragma unroll
            for (int r = 0; r < 16; r++) {
                int oc = (r & 3) + 8 * (r >> 2) + 4 * kg;
                loc[lane31 * 33 + oc] = V[r];
            }
            S8 vf0, vf1;
#pragma unroll
            for (int j = 0; j < 8; j++) {
                vf0.e[j] = f2bf(loc[lane31 * 33 + g8 + j]);
                vf1.e[j] = f2bf(loc[lane31 * 33 + 16 + g8 + j]);
            }
            float c0 = vt[(size_t)n * 704 + 9 * 64 + bh * 32 + lane31];
            float c1 = vt[(size_t)n * 704 + 10 * 64 + bh * 32 + lane31];

            // sa = eW1[:,0:32] vf + eW1[:,32]*c0 + eW1[:,33]*c1 + eb1
            a0.v = ((const short8*)(wpk + 6144))[lane];
            a1.v = ((const short8*)(wpk + 6144))[64 + lane];
            f32x16 SA = {};
            SA = __builtin_amdgcn_mfma_f32_32x32x16_bf16(a0.v, vf0.v, SA, 0, 0, 0);
            SA = __builtin_amdgcn_mfma_f32_32x32x16_bf16(a1.v, vf1.v, SA, 0, 0, 0);
            {
                const float* eb = (const float*)(wpk + 24576) + lane * 16;
                const float* e2 = (const float*)(wpk + 32768) + lane * 16;
                const float* e3 = (const float*)(wpk + 36864) + lane * 16;
#pragma unroll
                for (int r = 0; r < 16; r++) SA[r] += eb[r] + e2[r] * c0 + e3[r] * c1;
            }
#pragma unroll
            for (int r = 0; r < 16; r++) {
                int oc = (r & 3) + 8 * (r >> 2) + 4 * kg;
                loc[lane31 * 33 + oc] = SA[r];
            }
            {
                S8 p0, p1;
#pragma unroll
                for (int j = 0; j < 8; j++) {
                    p0.e[j] = f2bf(loc[lane31 * 33 + g8 + j]);
                    p1.e[j] = f2bf(loc[lane31 * 33 + 16 + g8 + j]);
                }
                ((short8*)(Apw + (size_t)n * 2048))[bh * 64 + lane] = p0.v;
                ((short8*)(Apw + (size_t)n * 2048))[(2 + bh) * 64 + lane] = p1.v;
            }
            // sb = eW1[:,34:66] vf + eW1[:,66]*c0 + eW1[:,67]*c1
            a0.v = ((const short8*)(wpk + 8192))[lane];
            a1.v = ((const short8*)(wpk + 8192))[64 + lane];
            f32x16 SB = {};
            SB = __builtin_amdgcn_mfma_f32_32x32x16_bf16(a0.v, vf0.v, SB, 0, 0, 0);
            SB = __builtin_amdgcn_mfma_f32_32x32x16_bf16(a1.v, vf1.v, SB, 0, 0, 0);
            {
                const float* e2 = (const float*)(wpk + 40960) + lane * 16;
                const float* e3 = (const float*)(wpk + 45056) + lane * 16;
#pragma unroll
                for (int r = 0; r < 16; r++) SB[r] += e2[r] * c0 + e3[r] * c1;
            }
#pragma unroll
            for (int r = 0; r < 16; r++) {
                int oc = (r & 3) + 8 * (r >> 2) + 4 * kg;
                loc[lane31 * 33 + oc] = SB[r];
            }
            {
                S8 p0, p1;
#pragma unroll
                for (int j = 0; j < 8; j++) {
                    p0.e[j] = f2bf(loc[lane31 * 33 + g8 + j]);
                    p1.e[j] = f2bf(loc[lane31 * 33 + 16 + g8 + j]);
                }
                ((short8*)(Bpw + (size_t)n * 2048))[bh * 64 + lane] = p0.v;
                ((short8*)(Bpw + (size_t)n * 2048))[(2 + bh) * 64 + lane] = p1.v;
            }
        } else {
            // vo readout: h = lrelu(vo1 x + vob1); fv = lrelu(vo2.h + vob2)
            a0.v = ((const short8*)(wpk + 10240))[lane];
            a1.v = ((const short8*)(wpk + 10240))[64 + lane];
            f32x16 C = {};
            C = __builtin_amdgcn_mfma_f32_32x32x16_bf16(a0.v, xf0.v, C, 0, 0, 0);
            C = __builtin_amdgcn_mfma_f32_32x32x16_bf16(a1.v, xf1.v, C, 0, 0, 0);
            cb = (const float*)(wpk + 28672) + lane * 16;
#pragma unroll
            for (int r = 0; r < 16; r++) { float m = C[r] + cb[r]; C[r] = fmaxf(m, 0.01f * m); }
#pragma unroll
            for (int r = 0; r < 16; r++) {
                int oc = (r & 3) + 8 * (r >> 2) + 4 * kg;
                loc[lane31 * 33 + oc] = C[r];
            }
            float s = 0.f;
#pragma unroll
            for (int o = 0; o < 16; o++) {
                int oc = (lane >> 5) * 16 + o;
                s += oW2[oc] * loc[lane31 * 33 + oc];
            }
            s += __shfl_xor(s, 32);
            if (lane < 32) {
                float v = s + ob2[0];
                fv[n * 64 + bh * 32 + lane31] = fmaxf(v, 0.01f * v);
            }
        }
    }
}

// ---------------- final reduce over nodes ----------------
__global__ void k_final2(const float* __restrict__ fv, const float* __restrict__ gW,
                         const float* __restrict__ gb, float* __restrict__ out) {
    int b = blockIdx.x;
    int t = threadIdx.x;
    float part = 0.f;
    for (int n = t; n < NN; n += 256) part += fv[n * 64 + b] * gW[n];
    __shared__ float rs[256];
    rs[t] = part;
    __syncthreads();
    for (int d = 128; d > 0; d >>= 1) {
        if (t < d) rs[t] += rs[t + d];
        __syncthreads();
    }
    if (t == 0) out[b] = 1.f / (1.f + expf(-(rs[0] + gb[0])));
}

extern "C" void kernel_launch(void* const* d_in, const int* in_sizes, int n_in,
                              void* d_out, int out_size, void* d_ws, size_t ws_size,
                              hipStream_t stream) {
    (void)in_sizes; (void)n_in; (void)out_size; (void)ws_size;
    const float* vert = (const float*)d_in[0];
    const int* edges  = (const int*)d_in[1];
    const float* xW   = (const float*)d_in[2];
    const float* xb   = (const float*)d_in[3];
    const float* yW   = (const float*)d_in[4];
    const float* yb   = (const float*)d_in[5];
    const float* tW   = (const float*)d_in[6];
    const float* tb   = (const float*)d_in[7];
    const float* cW1  = (const float*)d_in[8];
    const float* cb1  = (const float*)d_in[9];
    const float* cW2  = (const float*)d_in[10];
    const float* cb2  = (const float*)d_in[11];
    const float* vW1  = (const float*)d_in[12];
    const float* vb1  = (const float*)d_in[13];
    const float* vW2  = (const float*)d_in[14];
    const float* vb2  = (const float*)d_in[15];
    const float* eW1  = (const float*)d_in[16];
    const float* eb1  = (const float*)d_in[17];
    const float* eW2  = (const float*)d_in[18];
    const float* eb2  = (const float*)d_in[19];
    const float* aW1  = (const float*)d_in[20];
    const float* ab1  = (const float*)d_in[21];
    const float* aW2  = (const float*)d_in[22];
    const float* ab2  = (const float*)d_in[23];
    const float* oW1  = (const float*)d_in[24];
    const float* ob1  = (const float*)d_in[25];
    const float* oW2  = (const float*)d_in[26];
    const float* ob2  = (const float*)d_in[27];
    const float* gW   = (const float*)d_in[28];
    const float* gb   = (const float*)d_in[29];
    float* out = (float*)d_out;

    char* w = (char*)d_ws;
    short* ApA = (short*)(w + 0);                      // 4.0 MB each
    short* BpA = (short*)(w + (4u << 20));
    short* ApB = (short*)(w + (8u << 20));
    short* BpB = (short*)(w + (12u << 20));
    float* nv  = (float*)(w + (16u << 20));            // 8.0 MB
    float* vt  = (float*)(w + (25u << 20));            // 2.8 MB
    float* fv  = (float*)(w + (28u << 20));            // 256 KB
    char*  wpk = w + (28u << 20) + (512u << 10);       // 48 KB
    int* deg    = (int*)(w + (29u << 20));
    int* offs   = deg + 1024;
    int* cursor = offs + 1024;
    int* cntA   = cursor + 1024;
    int* adj    = cntA + 1024;                         // 32000 ints

    hipMemsetAsync(deg, 0, NN * sizeof(int), stream);
    k_tr<<<NN / 4, 256, 0, stream>>>(vert, vt);
    k_deg<<<(NE + 255) / 256, 256, 0, stream>>>(edges, deg);
    k_scan<<<1, 1024, 0, stream>>>(deg, offs, cursor);
    k_fillA<<<(NE + 255) / 256, 256, 0, stream>>>(edges, cursor, adj);
    k_sort<<<NN / 4, 256, 0, stream>>>(offs, adj, cntA);
    k_wsetup2<<<1, 64, 0, stream>>>(eW2, eb2, aW1, ab1, aW2, ab2, eW1, eb1, oW1, ob1, wpk);

    k_prep0<<<(NB * NN) / 256, 256, 0, stream>>>(vt, xW, xb, yW, yb, tW, tb,
                                                 cW1, cb1, cW2, cb2, vW1, vb1, vW2, vb2,
                                                 eW1, eb1, ApA, BpA);

    short* bufs[2][2] = {{ApA, BpA}, {ApB, BpB}};
    for (int p = 0; p < 6; p++) {
        int rb = p & 1, wb = rb ^ 1;
        int mode = (p == 5) ? 1 : 0;
        int pass0 = (p == 0) ? 1 : 0;
        k_edge<<<NN, 256, 0, stream>>>(bufs[rb][0], bufs[rb][1],
                                       bufs[wb][0], bufs[wb][1],
                                       offs, cntA, adj, wpk, vt, nv, fv,
                                       oW2, ob2, pass0, mode);
    }

    k_final2<<<NB, 256, 0, stream>>>(fv, gW, gb, out);
}

// Round 8
// 303.280 us; speedup vs baseline: 10.6856x; 1.2961x over previous
//
#include <hip/hip_runtime.h>
#include <hip/hip_bf16.h>
#include <cstdint>
#include <cstddef>

#define NB 64      // batch
#define NN 1000    // nodes
#define NE 16000   // edges
#define ADJCAP 256

typedef __attribute__((ext_vector_type(8))) short short8;
typedef __attribute__((ext_vector_type(16))) float f32x16;

__device__ __forceinline__ float lrelu(float x) { return fmaxf(x, 0.01f * x); }

__device__ __forceinline__ float bf2f(short s) {
    unsigned int u = ((unsigned int)(unsigned short)s) << 16;
    return __builtin_bit_cast(float, u);
}
__device__ __forceinline__ short f2bf(float f) {
    __hip_bfloat16 h = __float2bfloat16(f);
    return __builtin_bit_cast(short, h);
}

union S8 { short8 v; short e[8]; };

// Fragment layout per node (2048 bf16 = 4KB):
//   value (k 0..31, b 0..63): fragment f=kh*2+bh; short8 index = n*256 + f*64 + lane
//   lane holds k=kh*16+(lane>>5)*8+j, b=bh*32+(lane&31)
// C layout (32x32 mfma): col=lane&31, row(r)=(r&3)+8*(r>>2)+4*(lane>>5)

// wpk byte offsets:
//  0     W2f     2048   eW2 A-frags
//  2048  aW1f    2048
//  4096  aW2f    2048
//  6144  eAf     2048   eW1[:,0:32]
//  8192  eBf     2048   eW1[:,34:66]
//  10240 vo1f    2048
//  12288 B2f     4096   eb2 C-layout
//  16384 aB1c    4096
//  20480 aB2c    4096
//  24576 eB1c    4096
//  28672 vo1bc   4096
//  32768 Ea32    4096
//  36864 Ea33    4096
//  40960 Eb32    4096
//  45056 Eb33    4096
//  49152 cW1f    2048   (K=24 zero-padded)
//  51200 cW2f    2048
//  53248 vW1h0f  2048
//  55296 vW1h1f  2048
//  57344 vW2f    2048
//  59392 axW0    4096   per-slot axis weights [kh*512 + lane*8 + j]
//  63488 axW1    4096
//  67584 axb     4096
//  71680 cb1c    4096
//  75776 cb2c    4096
//  79872 vb1c    4096
//  83968 vb2c    4096

// ---------------- vert transpose: [b][n][11] -> vt[n][i][b] ----------------
__global__ void k_tr(const float* __restrict__ vert, float* __restrict__ vt) {
    __shared__ float s[2816];
    int n0 = blockIdx.x * 4;
    int t = threadIdx.x;
    int b = t >> 2, r = t & 3;
    const float* vp = vert + ((size_t)b * NN + n0 + r) * 11;
#pragma unroll
    for (int i = 0; i < 11; i++) s[r * 704 + i * 64 + b] = vp[i];
    __syncthreads();
    float* o = vt + (size_t)n0 * 704;
#pragma unroll
    for (int j = 0; j < 11; j++) o[j * 256 + t] = s[j * 256 + t];
}

// ---------------- CSR build ----------------
__global__ void k_deg(const int* __restrict__ edges, int* __restrict__ deg) {
    int e = blockIdx.x * 256 + threadIdx.x;
    if (e < NE) {
        atomicAdd(&deg[edges[e]], 1);
        atomicAdd(&deg[edges[NE + e]], 1);
    }
}

__global__ void k_scan(const int* __restrict__ deg, int* __restrict__ offs,
                       int* __restrict__ cursor) {
    __shared__ int s[1024];
    int t = threadIdx.x;
    int d = (t < NN) ? deg[t] : 0;
    s[t] = d;
    __syncthreads();
    for (int k = 1; k < 1024; k <<= 1) {
        int v = (t >= k) ? s[t - k] : 0;
        __syncthreads();
        s[t] += v;
        __syncthreads();
    }
    if (t < NN) {
        offs[t + 1] = s[t];
        cursor[t] = s[t] - d;
    }
    if (t == 0) offs[0] = 0;
}

__global__ void k_fillA(const int* __restrict__ edges, int* __restrict__ cursor,
                        int* __restrict__ adj) {
    int e = blockIdx.x * 256 + threadIdx.x;
    if (e < NE) {
        int s = edges[e], d = edges[NE + e];
        int p1 = atomicAdd(&cursor[s], 1);
        adj[p1] = (e << 10) | d;
        int p2 = atomicAdd(&cursor[d], 1);
        adj[p2] = (1 << 30) | (e << 10) | s;
    }
}

// wave-parallel canonical rank sort (keys unique -> deterministic order)
__global__ void k_sort(const int* __restrict__ offs, int* __restrict__ adj,
                       int* __restrict__ cntA) {
    __shared__ int keys[4][ADJCAP];
    int w = threadIdx.x >> 6;
    int lane = threadIdx.x & 63;
    int n = blockIdx.x * 4 + w;
    int o0 = offs[n], o1 = offs[n + 1];
    int deg = o1 - o0;
    int cap = (deg < ADJCAP) ? deg : ADJCAP;
    for (int i = lane; i < cap; i += 64) keys[w][i] = adj[o0 + i];
    __syncthreads();
    if (deg <= ADJCAP) {
        for (int i = lane; i < deg; i += 64) {
            int k = keys[w][i];
            int r = 0;
            for (int j = 0; j < deg; j++) r += (keys[w][j] < k) ? 1 : 0;
            adj[o0 + r] = k;
        }
        if (lane == 0) {
            int c = 0;
            for (int j = 0; j < deg; j++) c += ((keys[w][j] >> 30) & 1) ? 0 : 1;
            cntA[n] = c;
        }
    } else if (lane == 0) {
        for (int i = o0 + 1; i < o1; i++) {
            int key = adj[i];
            int j = i - 1;
            while (j >= o0 && adj[j] > key) { adj[j + 1] = adj[j]; j--; }
            adj[j + 1] = key;
        }
        int c = 0;
        for (int i = o0; i < o1; i++) c += ((adj[i] >> 30) & 1) ? 0 : 1;
        cntA[n] = c;
    }
}

// ---------------- weight pre-pack (one wave) ----------------
__global__ void k_wsetup2(const float* __restrict__ eW2, const float* __restrict__ eb2,
                          const float* __restrict__ aW1, const float* __restrict__ ab1,
                          const float* __restrict__ aW2, const float* __restrict__ ab2,
                          const float* __restrict__ eW1, const float* __restrict__ eb1,
                          const float* __restrict__ oW1, const float* __restrict__ ob1,
                          const float* __restrict__ xW, const float* __restrict__ xb,
                          const float* __restrict__ yW, const float* __restrict__ yb,
                          const float* __restrict__ tW, const float* __restrict__ tb,
                          const float* __restrict__ cW1, const float* __restrict__ cb1,
                          const float* __restrict__ cW2, const float* __restrict__ cb2,
                          const float* __restrict__ vW1, const float* __restrict__ vb1,
                          const float* __restrict__ vW2, const float* __restrict__ vb2,
                          char* __restrict__ wpk) {
    int l = threadIdx.x;  // 64
    int row = l & 31, kg = l >> 5;

    auto packAK = [&](const float* W, int ldw, int coff, int K, short8* dst) {
#pragma unroll
        for (int kh = 0; kh < 2; kh++) {
            S8 a;
#pragma unroll
            for (int j = 0; j < 8; j++) {
                int k = kh * 16 + kg * 8 + j;
                a.e[j] = (k < K) ? f2bf(W[row * ldw + coff + k]) : (short)0;
            }
            dst[kh * 64 + l] = a.v;
        }
    };
    packAK(eW2, 32, 0, 32, (short8*)(wpk + 0));
    packAK(aW1, 32, 0, 32, (short8*)(wpk + 2048));
    packAK(aW2, 32, 0, 32, (short8*)(wpk + 4096));
    packAK(eW1, 68, 0, 32, (short8*)(wpk + 6144));
    packAK(eW1, 68, 34, 32, (short8*)(wpk + 8192));
    packAK(oW1, 32, 0, 32, (short8*)(wpk + 10240));
    packAK(cW1, 24, 0, 24, (short8*)(wpk + 49152));
    packAK(cW2, 32, 0, 32, (short8*)(wpk + 51200));
    packAK(vW1, 64, 0, 32, (short8*)(wpk + 53248));
    packAK(vW1, 64, 32, 32, (short8*)(wpk + 55296));
    packAK(vW2, 32, 0, 32, (short8*)(wpk + 57344));

    float* B2f   = (float*)(wpk + 12288);
    float* aB1c  = (float*)(wpk + 16384);
    float* aB2c  = (float*)(wpk + 20480);
    float* eB1c  = (float*)(wpk + 24576);
    float* vo1bc = (float*)(wpk + 28672);
    float* Ea32  = (float*)(wpk + 32768);
    float* Ea33  = (float*)(wpk + 36864);
    float* Eb32  = (float*)(wpk + 40960);
    float* Eb33  = (float*)(wpk + 45056);
    float* cb1c  = (float*)(wpk + 71680);
    float* cb2c  = (float*)(wpk + 75776);
    float* vb1c  = (float*)(wpk + 79872);
    float* vb2c  = (float*)(wpk + 83968);
#pragma unroll
    for (int r = 0; r < 16; r++) {
        int rr = (r & 3) + 8 * (r >> 2) + 4 * kg;
        B2f[l * 16 + r]   = eb2[rr];
        aB1c[l * 16 + r]  = ab1[rr];
        aB2c[l * 16 + r]  = ab2[rr];
        eB1c[l * 16 + r]  = eb1[rr];
        vo1bc[l * 16 + r] = ob1[rr];
        Ea32[l * 16 + r]  = eW1[rr * 68 + 32];
        Ea33[l * 16 + r]  = eW1[rr * 68 + 33];
        Eb32[l * 16 + r]  = eW1[rr * 68 + 66];
        Eb33[l * 16 + r]  = eW1[rr * 68 + 67];
        cb1c[l * 16 + r]  = cb1[rr];
        cb2c[l * 16 + r]  = cb2[rr];
        vb1c[l * 16 + r]  = vb1[rr];
        vb2c[l * 16 + r]  = vb2[rr];
    }

    // axis tables: slot (kh, lane, j) -> k=kh*16+kg*8+j, axis i=k>>3, chan c=k&7
    float* axW0 = (float*)(wpk + 59392);
    float* axW1 = (float*)(wpk + 63488);
    float* axb  = (float*)(wpk + 67584);
#pragma unroll
    for (int kh = 0; kh < 2; kh++) {
#pragma unroll
        for (int j = 0; j < 8; j++) {
            int k = kh * 16 + kg * 8 + j;
            int i = k >> 3, c = k & 7;
            float w0 = 0.f, w1 = 0.f, bb = 0.f;
            if (i < 3) {
                const float* W = (i == 0) ? xW : ((i == 1) ? yW : tW);
                const float* B = (i == 0) ? xb : ((i == 1) ? yb : tb);
                w0 = W[c * 2]; w1 = W[c * 2 + 1]; bb = B[c];
            }
            axW0[kh * 512 + l * 8 + j] = w0;
            axW1[kh * 512 + l * 8 + j] = w1;
            axb[kh * 512 + l * 8 + j]  = bb;
        }
    }
}

// ---------------- MFMA pass-0 prep: 1 wave per (node, batch-half) ----------------
__global__ __launch_bounds__(256) void k_prep0f(
    const float* __restrict__ vt, const char* __restrict__ wpk,
    short* __restrict__ Ap, short* __restrict__ Bp) {
    __shared__ float loc4[4][1056];
    int w = threadIdx.x >> 6;
    int lane = threadIdx.x & 63;
    int lane31 = lane & 31, kg = lane >> 5, g8 = kg * 8;
    int n = blockIdx.x * 2 + (w >> 1);
    int bh = w & 1;
    int col = bh * 32 + lane31;
    float* loc = loc4[w];
    const float* vn = vt + (size_t)n * 704;

    const short8* cW1f = (const short8*)(wpk + 49152);
    const short8* cW2f = (const short8*)(wpk + 51200);
    const short8* vW1f0 = (const short8*)(wpk + 53248);
    const short8* vW1f1 = (const short8*)(wpk + 55296);
    const short8* vW2f = (const short8*)(wpk + 57344);
    const short8* eAf = (const short8*)(wpk + 6144);
    const short8* eBf = (const short8*)(wpk + 8192);
    const float* axW0 = (const float*)(wpk + 59392);
    const float* axW1 = (const float*)(wpk + 63488);
    const float* axb  = (const float*)(wpk + 67584);
    const float* cb1c = (const float*)(wpk + 71680) + lane * 16;
    const float* cb2c = (const float*)(wpk + 75776) + lane * 16;
    const float* vb1c = (const float*)(wpk + 79872) + lane * 16;
    const float* vb2c = (const float*)(wpk + 83968) + lane * 16;

    const f32x16 zero = {};

#define C2FRAG(Creg, F0, F1) do {                                              \
    _Pragma("unroll") for (int r = 0; r < 16; r++)                             \
        loc[lane31 * 33 + ((r & 3) + 8 * (r >> 2) + 4 * kg)] = Creg[r];        \
    _Pragma("unroll") for (int j = 0; j < 8; j++) {                            \
        F0.e[j] = f2bf(loc[lane31 * 33 + g8 + j]);                             \
        F1.e[j] = f2bf(loc[lane31 * 33 + 16 + g8 + j]); }                      \
} while (0)

    f32x16 V1;
#pragma unroll
    for (int r = 0; r < 16; r++) V1[r] = vb1c[r];

#pragma unroll
    for (int half = 0; half < 2; half++) {
        // axis-feature B-fragments, built directly in registers
        S8 ff0, ff1;
#pragma unroll
        for (int kh = 0; kh < 2; kh++) {
            int i = kh * 2 + kg;
            float p0 = vn[i * 64 + col];
            float p1 = vn[((half ? 6 : 3) + i) * 64 + col];
            const float* w0p = axW0 + kh * 512 + lane * 8;
            const float* w1p = axW1 + kh * 512 + lane * 8;
            const float* bp  = axb  + kh * 512 + lane * 8;
            S8 f;
#pragma unroll
            for (int j = 0; j < 8; j++) {
                float x = w0p[j] * p0 + w1p[j] * p1 + bp[j];
                f.e[j] = f2bf(fmaxf(x, 0.01f * x));
            }
            if (kh == 0) ff0 = f; else ff1 = f;
        }
        // cfg layer 1 (K=24 padded to 32)
        f32x16 C = __builtin_amdgcn_mfma_f32_32x32x16_bf16(cW1f[lane], ff0.v, zero, 0, 0, 0);
        C = __builtin_amdgcn_mfma_f32_32x32x16_bf16(cW1f[64 + lane], ff1.v, C, 0, 0, 0);
#pragma unroll
        for (int r = 0; r < 16; r++) { float m = C[r] + cb1c[r]; C[r] = fmaxf(m, 0.01f * m); }
        S8 hf0, hf1;
        C2FRAG(C, hf0, hf1);
        // cfg layer 2
        C = __builtin_amdgcn_mfma_f32_32x32x16_bf16(cW2f[lane], hf0.v, zero, 0, 0, 0);
        C = __builtin_amdgcn_mfma_f32_32x32x16_bf16(cW2f[64 + lane], hf1.v, C, 0, 0, 0);
#pragma unroll
        for (int r = 0; r < 16; r++) { float m = C[r] + cb2c[r]; C[r] = fmaxf(m, 0.01f * m); }
        S8 cf0, cf1;
        C2FRAG(C, cf0, cf1);
        // accumulate v1 += vW1[:, half*32:+32] * cfg_half
        const short8* vf = half ? vW1f1 : vW1f0;
        V1 = __builtin_amdgcn_mfma_f32_32x32x16_bf16(vf[lane], cf0.v, V1, 0, 0, 0);
        V1 = __builtin_amdgcn_mfma_f32_32x32x16_bf16(vf[64 + lane], cf1.v, V1, 0, 0, 0);
    }
#pragma unroll
    for (int r = 0; r < 16; r++) V1[r] = fmaxf(V1[r], 0.01f * V1[r]);
    S8 v1f0, v1f1;
    C2FRAG(V1, v1f0, v1f1);
    // vtx layer 2
    f32x16 V2 = __builtin_amdgcn_mfma_f32_32x32x16_bf16(vW2f[lane], v1f0.v, zero, 0, 0, 0);
    V2 = __builtin_amdgcn_mfma_f32_32x32x16_bf16(vW2f[64 + lane], v1f1.v, V2, 0, 0, 0);
#pragma unroll
    for (int r = 0; r < 16; r++) { float m = V2[r] + vb2c[r]; V2[r] = fmaxf(m, 0.01f * m); }
    S8 vf0, vf1;
    C2FRAG(V2, vf0, vf1);

    float c0 = vn[9 * 64 + col];
    float c1 = vn[10 * 64 + col];

    // sa = eW1[:,0:32] vf + eW1[:,32]*c0 + eW1[:,33]*c1 + eb1
    f32x16 SA = __builtin_amdgcn_mfma_f32_32x32x16_bf16(eAf[lane], vf0.v, zero, 0, 0, 0);
    SA = __builtin_amdgcn_mfma_f32_32x32x16_bf16(eAf[64 + lane], vf1.v, SA, 0, 0, 0);
    {
        const float* eb = (const float*)(wpk + 24576) + lane * 16;
        const float* e2 = (const float*)(wpk + 32768) + lane * 16;
        const float* e3 = (const float*)(wpk + 36864) + lane * 16;
#pragma unroll
        for (int r = 0; r < 16; r++) SA[r] += eb[r] + e2[r] * c0 + e3[r] * c1;
    }
    S8 p0, p1;
    C2FRAG(SA, p0, p1);
    ((short8*)(Ap + (size_t)n * 2048))[bh * 64 + lane] = p0.v;
    ((short8*)(Ap + (size_t)n * 2048))[(2 + bh) * 64 + lane] = p1.v;

    // sb = eW1[:,34:66] vf + eW1[:,66]*c0 + eW1[:,67]*c1
    f32x16 SB = __builtin_amdgcn_mfma_f32_32x32x16_bf16(eBf[lane], vf0.v, zero, 0, 0, 0);
    SB = __builtin_amdgcn_mfma_f32_32x32x16_bf16(eBf[64 + lane], vf1.v, SB, 0, 0, 0);
    {
        const float* e2 = (const float*)(wpk + 40960) + lane * 16;
        const float* e3 = (const float*)(wpk + 45056) + lane * 16;
#pragma unroll
        for (int r = 0; r < 16; r++) SB[r] += e2[r] * c0 + e3[r] * c1;
    }
    C2FRAG(SB, p0, p1);
    ((short8*)(Bp + (size_t)n * 2048))[bh * 64 + lane] = p0.v;
    ((short8*)(Bp + (size_t)n * 2048))[(2 + bh) * 64 + lane] = p1.v;
#undef C2FRAG
}

// ---------------- fused edge pass + node prep (or vo readout) ----------------
#define VISIT(C0, C1, C2, C3) do {                                                        \
    S8 h10, h11;                                                                          \
    _Pragma("unroll") for (int j = 0; j < 8; j++) {                                       \
        float x0 = bfv[0][j] + bf2f(C0.e[j]); h10.e[j] = f2bf(fmaxf(x0, 0.01f * x0)); }   \
    _Pragma("unroll") for (int j = 0; j < 8; j++) {                                       \
        float x1 = bfv[2][j] + bf2f(C2.e[j]); h11.e[j] = f2bf(fmaxf(x1, 0.01f * x1)); }   \
    f32x16 d = __builtin_amdgcn_mfma_f32_32x32x16_bf16(w2f0.v, h10.v, zero, 0, 0, 0);     \
    d = __builtin_amdgcn_mfma_f32_32x32x16_bf16(w2f1.v, h11.v, d, 0, 0, 0);               \
    _Pragma("unroll") for (int r = 0; r < 16; r++) {                                      \
        float m = d[r] + b2v[r]; acc0[r] += fmaxf(m, 0.01f * m); }                        \
    _Pragma("unroll") for (int j = 0; j < 8; j++) {                                       \
        float x0 = bfv[1][j] + bf2f(C1.e[j]); h10.e[j] = f2bf(fmaxf(x0, 0.01f * x0)); }   \
    _Pragma("unroll") for (int j = 0; j < 8; j++) {                                       \
        float x1 = bfv[3][j] + bf2f(C3.e[j]); h11.e[j] = f2bf(fmaxf(x1, 0.01f * x1)); }   \
    d = __builtin_amdgcn_mfma_f32_32x32x16_bf16(w2f0.v, h10.v, zero, 0, 0, 0);            \
    d = __builtin_amdgcn_mfma_f32_32x32x16_bf16(w2f1.v, h11.v, d, 0, 0, 0);               \
    _Pragma("unroll") for (int r = 0; r < 16; r++) {                                      \
        float m = d[r] + b2v[r]; acc1[r] += fmaxf(m, 0.01f * m); }                        \
} while (0)

__global__ __launch_bounds__(256) void k_edge(
    const short* __restrict__ Apr, const short* __restrict__ Bpr,
    short* __restrict__ Apw, short* __restrict__ Bpw,
    const int* __restrict__ offs, const int* __restrict__ cntA,
    const int* __restrict__ adjg, const char* __restrict__ wpk,
    const float* __restrict__ vt, float* __restrict__ nv, float* __restrict__ fv,
    const float* __restrict__ oW2, const float* __restrict__ ob2,
    int pass0, int mode) {
    __shared__ float red[4][2112];
    __shared__ int adjl[ADJCAP];
    int n = blockIdx.x;
    int w = threadIdx.x >> 6;
    int lane = threadIdx.x & 63;
    int row = lane & 31, kg = lane >> 5;

    int off0 = offs[n], off1 = offs[n + 1];
    int deg = off1 - off0;
    int cA = cntA[n];

    for (int i = threadIdx.x; i < deg && i < ADJCAP; i += 256)
        adjl[i] = adjg[off0 + i] & 1023;
    __syncthreads();

    // ---- edge accumulation ----
    S8 w2f0, w2f1;
    w2f0.v = ((const short8*)wpk)[lane];
    w2f1.v = ((const short8*)wpk)[64 + lane];
    float b2v[16];
    {
        const float4* bp4 = (const float4*)((const float*)(wpk + 12288) + lane * 16);
#pragma unroll
        for (int q = 0; q < 4; q++) {
            float4 v = bp4[q];
            b2v[q * 4] = v.x; b2v[q * 4 + 1] = v.y;
            b2v[q * 4 + 2] = v.z; b2v[q * 4 + 3] = v.w;
        }
    }

    f32x16 acc0 = {};
    f32x16 acc1 = {};
    const f32x16 zero = {};

#pragma unroll
    for (int phase = 0; phase < 2; phase++) {
        const short* basePtr = phase ? Bpr : Apr;
        const short8* ogBase = (const short8*)(phase ? Apr : Bpr);
        int lstart = phase ? cA : 0;
        int lend   = phase ? deg : cA;

        float bfv[4][8];
        {
            const short8* np = (const short8*)(basePtr + (size_t)n * 2048);
#pragma unroll
            for (int f = 0; f < 4; f++) {
                S8 t; t.v = np[f * 64 + lane];
#pragma unroll
                for (int j = 0; j < 8; j++) bfv[f][j] = bf2f(t.e[j]);
            }
        }

        int li = lstart + w;
        S8 c0 = {}, c1 = {}, c2 = {}, c3 = {};
        if (li < lend) {
            int o = (li < ADJCAP) ? adjl[li] : (adjg[off0 + li] & 1023);
            const short8* op = ogBase + (size_t)o * 256;
            c0.v = op[lane]; c1.v = op[64 + lane];
            c2.v = op[128 + lane]; c3.v = op[192 + lane];
        }
        while (li < lend) {
            int ln = li + 4;
            S8 n0 = {}, n1 = {}, n2 = {}, n3 = {};
            if (ln < lend) {
                int o = (ln < ADJCAP) ? adjl[ln] : (adjg[off0 + ln] & 1023);
                const short8* op = ogBase + (size_t)o * 256;
                n0.v = op[lane]; n1.v = op[64 + lane];
                n2.v = op[128 + lane]; n3.v = op[192 + lane];
            }
            VISIT(c0, c1, c2, c3);
            c0 = n0; c1 = n1; c2 = n2; c3 = n3;
            li = ln;
        }
    }

    // ---- cross-wave reduce, nv update, stash new nv in red[0] as (b,oc) ----
#pragma unroll
    for (int bh = 0; bh < 2; bh++) {
        int b = bh * 32 + row;
#pragma unroll
        for (int r = 0; r < 16; r++) {
            int oc = (r & 3) + 8 * (r >> 2) + 4 * kg;
            red[w][b * 33 + oc] = bh ? acc1[r] : acc0[r];
        }
    }
    __syncthreads();

    {
        int t = threadIdx.x;
        size_t nb = (size_t)n * (NB * 32);
        float inv = (deg > 0) ? 1.f / (float)deg : 0.f;
#pragma unroll
        for (int j = 0; j < 8; j++) {
            int idx = t * 8 + j;
            int bb = idx >> 5, cc = idx & 31;
            float s;
            if (deg > 0) {
                s = (red[0][bb * 33 + cc] + red[1][bb * 33 + cc] +
                     red[2][bb * 33 + cc] + red[3][bb * 33 + cc]) * inv;
                if (!pass0) s += nv[nb + idx];
            } else {
                s = pass0 ? 0.f : nv[nb + idx];
            }
            nv[nb + idx] = s;
            red[0][bb * 33 + cc] = s;
        }
    }
    __syncthreads();

    // ---- fused node prep (waves 0,1; each owns one 32-col half) ----
    if (w < 2) {
        int bh = w;
        int lane31 = lane & 31;
        int g8 = (lane >> 5) * 8;
        float* loc = red[2 + w];
        const float* cb;
        S8 a0, a1;

        S8 xf0, xf1;
#pragma unroll
        for (int j = 0; j < 8; j++) {
            xf0.e[j] = f2bf(red[0][(bh * 32 + lane31) * 33 + g8 + j]);
            xf1.e[j] = f2bf(red[0][(bh * 32 + lane31) * 33 + 16 + g8 + j]);
        }

        if (mode == 0) {
            a0.v = ((const short8*)(wpk + 2048))[lane];
            a1.v = ((const short8*)(wpk + 2048))[64 + lane];
            f32x16 C = {};
            C = __builtin_amdgcn_mfma_f32_32x32x16_bf16(a0.v, xf0.v, C, 0, 0, 0);
            C = __builtin_amdgcn_mfma_f32_32x32x16_bf16(a1.v, xf1.v, C, 0, 0, 0);
            cb = (const float*)(wpk + 16384) + lane * 16;
#pragma unroll
            for (int r = 0; r < 16; r++) { float m = C[r] + cb[r]; C[r] = fmaxf(m, 0.01f * m); }
#pragma unroll
            for (int r = 0; r < 16; r++) {
                int oc = (r & 3) + 8 * (r >> 2) + 4 * kg;
                loc[lane31 * 33 + oc] = C[r];
            }
            S8 hf0, hf1;
#pragma unroll
            for (int j = 0; j < 8; j++) {
                hf0.e[j] = f2bf(loc[lane31 * 33 + g8 + j]);
                hf1.e[j] = f2bf(loc[lane31 * 33 + 16 + g8 + j]);
            }
            a0.v = ((const short8*)(wpk + 4096))[lane];
            a1.v = ((const short8*)(wpk + 4096))[64 + lane];
            f32x16 V = {};
            V = __builtin_amdgcn_mfma_f32_32x32x16_bf16(a0.v, hf0.v, V, 0, 0, 0);
            V = __builtin_amdgcn_mfma_f32_32x32x16_bf16(a1.v, hf1.v, V, 0, 0, 0);
            cb = (const float*)(wpk + 20480) + lane * 16;
#pragma unroll
            for (int r = 0; r < 16; r++) { float m = V[r] + cb[r]; V[r] = fmaxf(m, 0.01f * m); }
#pragma unroll
            for (int r = 0; r < 16; r++) {
                int oc = (r & 3) + 8 * (r >> 2) + 4 * kg;
                loc[lane31 * 33 + oc] = V[r];
            }
            S8 vf0, vf1;
#pragma unroll
            for (int j = 0; j < 8; j++) {
                vf0.e[j] = f2bf(loc[lane31 * 33 + g8 + j]);
                vf1.e[j] = f2bf(loc[lane31 * 33 + 16 + g8 + j]);
            }
            float c0 = vt[(size_t)n * 704 + 9 * 64 + bh * 32 + lane31];
            float c1 = vt[(size_t)n * 704 + 10 * 64 + bh * 32 + lane31];

            a0.v = ((const short8*)(wpk + 6144))[lane];
            a1.v = ((const short8*)(wpk + 6144))[64 + lane];
            f32x16 SA = {};
            SA = __builtin_amdgcn_mfma_f32_32x32x16_bf16(a0.v, vf0.v, SA, 0, 0, 0);
            SA = __builtin_amdgcn_mfma_f32_32x32x16_bf16(a1.v, vf1.v, SA, 0, 0, 0);
            {
                const float* eb = (const float*)(wpk + 24576) + lane * 16;
                const float* e2 = (const float*)(wpk + 32768) + lane * 16;
                const float* e3 = (const float*)(wpk + 36864) + lane * 16;
#pragma unroll
                for (int r = 0; r < 16; r++) SA[r] += eb[r] + e2[r] * c0 + e3[r] * c1;
            }
#pragma unroll
            for (int r = 0; r < 16; r++) {
                int oc = (r & 3) + 8 * (r >> 2) + 4 * kg;
                loc[lane31 * 33 + oc] = SA[r];
            }
            {
                S8 p0, p1;
#pragma unroll
                for (int j = 0; j < 8; j++) {
                    p0.e[j] = f2bf(loc[lane31 * 33 + g8 + j]);
                    p1.e[j] = f2bf(loc[lane31 * 33 + 16 + g8 + j]);
                }
                ((short8*)(Apw + (size_t)n * 2048))[bh * 64 + lane] = p0.v;
                ((short8*)(Apw + (size_t)n * 2048))[(2 + bh) * 64 + lane] = p1.v;
            }
            a0.v = ((const short8*)(wpk + 8192))[lane];
            a1.v = ((const short8*)(wpk + 8192))[64 + lane];
            f32x16 SB = {};
            SB = __builtin_amdgcn_mfma_f32_32x32x16_bf16(a0.v, vf0.v, SB, 0, 0, 0);
            SB = __builtin_amdgcn_mfma_f32_32x32x16_bf16(a1.v, vf1.v, SB, 0, 0, 0);
            {
                const float* e2 = (const float*)(wpk + 40960) + lane * 16;
                const float* e3 = (const float*)(wpk + 45056) + lane * 16;
#pragma unroll
                for (int r = 0; r < 16; r++) SB[r] += e2[r] * c0 + e3[r] * c1;
            }
#pragma unroll
            for (int r = 0; r < 16; r++) {
                int oc = (r & 3) + 8 * (r >> 2) + 4 * kg;
                loc[lane31 * 33 + oc] = SB[r];
            }
            {
                S8 p0, p1;
#pragma unroll
                for (int j = 0; j < 8; j++) {
                    p0.e[j] = f2bf(loc[lane31 * 33 + g8 + j]);
                    p1.e[j] = f2bf(loc[lane31 * 33 + 16 + g8 + j]);
                }
                ((short8*)(Bpw + (size_t)n * 2048))[bh * 64 + lane] = p0.v;
                ((short8*)(Bpw + (size_t)n * 2048))[(2 + bh) * 64 + lane] = p1.v;
            }
        } else {
            a0.v = ((const short8*)(wpk + 10240))[lane];
            a1.v = ((const short8*)(wpk + 10240))[64 + lane];
            f32x16 C = {};
            C = __builtin_amdgcn_mfma_f32_32x32x16_bf16(a0.v, xf0.v, C, 0, 0, 0);
            C = __builtin_amdgcn_mfma_f32_32x32x16_bf16(a1.v, xf1.v, C, 0, 0, 0);
            cb = (const float*)(wpk + 28672) + lane * 16;
#pragma unroll
            for (int r = 0; r < 16; r++) { float m = C[r] + cb[r]; C[r] = fmaxf(m, 0.01f * m); }
#pragma unroll
            for (int r = 0; r < 16; r++) {
                int oc = (r & 3) + 8 * (r >> 2) + 4 * kg;
                loc[lane31 * 33 + oc] = C[r];
            }
            float s = 0.f;
#pragma unroll
            for (int o = 0; o < 16; o++) {
                int oc = (lane >> 5) * 16 + o;
                s += oW2[oc] * loc[lane31 * 33 + oc];
            }
            s += __shfl_xor(s, 32);
            if (lane < 32) {
                float v = s + ob2[0];
                fv[n * 64 + bh * 32 + lane31] = fmaxf(v, 0.01f * v);
            }
        }
    }
}

// ---------------- final reduce over nodes ----------------
__global__ void k_final2(const float* __restrict__ fv, const float* __restrict__ gW,
                         const float* __restrict__ gb, float* __restrict__ out) {
    int b = blockIdx.x;
    int t = threadIdx.x;
    float part = 0.f;
    for (int n = t; n < NN; n += 256) part += fv[n * 64 + b] * gW[n];
    __shared__ float rs[256];
    rs[t] = part;
    __syncthreads();
    for (int d = 128; d > 0; d >>= 1) {
        if (t < d) rs[t] += rs[t + d];
        __syncthreads();
    }
    if (t == 0) out[b] = 1.f / (1.f + expf(-(rs[0] + gb[0])));
}

extern "C" void kernel_launch(void* const* d_in, const int* in_sizes, int n_in,
                              void* d_out, int out_size, void* d_ws, size_t ws_size,
                              hipStream_t stream) {
    (void)in_sizes; (void)n_in; (void)out_size; (void)ws_size;
    const float* vert = (const float*)d_in[0];
    const int* edges  = (const int*)d_in[1];
    const float* xW   = (const float*)d_in[2];
    const float* xb   = (const float*)d_in[3];
    const float* yW   = (const float*)d_in[4];
    const float* yb   = (const float*)d_in[5];
    const float* tW   = (const float*)d_in[6];
    const float* tb   = (const float*)d_in[7];
    const float* cW1  = (const float*)d_in[8];
    const float* cb1  = (const float*)d_in[9];
    const float* cW2  = (const float*)d_in[10];
    const float* cb2  = (const float*)d_in[11];
    const float* vW1  = (const float*)d_in[12];
    const float* vb1  = (const float*)d_in[13];
    const float* vW2  = (const float*)d_in[14];
    const float* vb2  = (const float*)d_in[15];
    const float* eW1  = (const float*)d_in[16];
    const float* eb1  = (const float*)d_in[17];
    const float* eW2  = (const float*)d_in[18];
    const float* eb2  = (const float*)d_in[19];
    const float* aW1  = (const float*)d_in[20];
    const float* ab1  = (const float*)d_in[21];
    const float* aW2  = (const float*)d_in[22];
    const float* ab2  = (const float*)d_in[23];
    const float* oW1  = (const float*)d_in[24];
    const float* ob1  = (const float*)d_in[25];
    const float* oW2  = (const float*)d_in[26];
    const float* ob2  = (const float*)d_in[27];
    const float* gW   = (const float*)d_in[28];
    const float* gb   = (const float*)d_in[29];
    float* out = (float*)d_out;

    char* w = (char*)d_ws;
    short* ApA = (short*)(w + 0);
    short* BpA = (short*)(w + (4u << 20));
    short* ApB = (short*)(w + (8u << 20));
    short* BpB = (short*)(w + (12u << 20));
    float* nv  = (float*)(w + (16u << 20));
    float* vt  = (float*)(w + (25u << 20));
    float* fv  = (float*)(w + (28u << 20));
    char*  wpk = w + (28u << 20) + (512u << 10);       // 128 KB
    int* deg    = (int*)(w + (29u << 20));
    int* offs   = deg + 1024;
    int* cursor = offs + 1024;
    int* cntA   = cursor + 1024;
    int* adj    = cntA + 1024;

    hipMemsetAsync(deg, 0, NN * sizeof(int), stream);
    k_tr<<<NN / 4, 256, 0, stream>>>(vert, vt);
    k_deg<<<(NE + 255) / 256, 256, 0, stream>>>(edges, deg);
    k_scan<<<1, 1024, 0, stream>>>(deg, offs, cursor);
    k_fillA<<<(NE + 255) / 256, 256, 0, stream>>>(edges, cursor, adj);
    k_sort<<<NN / 4, 256, 0, stream>>>(offs, adj, cntA);
    k_wsetup2<<<1, 64, 0, stream>>>(eW2, eb2, aW1, ab1, aW2, ab2, eW1, eb1, oW1, ob1,
                                    xW, xb, yW, yb, tW, tb, cW1, cb1, cW2, cb2,
                                    vW1, vb1, vW2, vb2, wpk);

    k_prep0f<<<NN / 2, 256, 0, stream>>>(vt, wpk, ApA, BpA);

    short* bufs[2][2] = {{ApA, BpA}, {ApB, BpB}};
    for (int p = 0; p < 6; p++) {
        int rb = p & 1, wb = rb ^ 1;
        int mode = (p == 5) ? 1 : 0;
        int pass0 = (p == 0) ? 1 : 0;
        k_edge<<<NN, 256, 0, stream>>>(bufs[rb][0], bufs[rb][1],
                                       bufs[wb][0], bufs[wb][1],
                                       offs, cntA, adj, wpk, vt, nv, fv,
                                       oW2, ob2, pass0, mode);
    }

    k_final2<<<NB, 256, 0, stream>>>(fv, gW, gb, out);
}

// Round 10
// 291.816 us; speedup vs baseline: 11.1053x; 1.0393x over previous
//
#include <hip/hip_runtime.h>
#include <hip/hip_fp16.h>
#include <cstdint>
#include <cstddef>

#define NB 64      // batch
#define NN 1000    // nodes
#define NE 16000   // edges
#define ADJCAP 256

typedef __attribute__((ext_vector_type(8))) short short8;
typedef __attribute__((ext_vector_type(8))) _Float16 half8;
typedef __attribute__((ext_vector_type(16))) float f32x16;

__device__ __forceinline__ float lrelu(float x) { return fmaxf(x, 0.01f * x); }

union S8 { short8 v; half8 h; _Float16 e[8]; unsigned int u[4]; };

// packed fp16 lrelu(a+b) on 8 lanes: lowers to v_pk_add/mul/max_f16
__device__ __forceinline__ half8 h8lreluadd(half8 a, half8 b) {
    half8 x = a + b;
    half8 y = x * (_Float16)0.01f;
    return __builtin_elementwise_max(x, y);
}

// Fragment layout per node (2048 fp16 = 4KB):
//   value (k 0..31, b 0..63): fragment f=kh*2+bh; short8 index = n*256 + f*64 + lane
//   lane holds k=kh*16+(lane>>5)*8+j, b=bh*32+(lane&31)
// C layout (32x32 mfma): col=lane&31, row(r)=(r&3)+8*(r>>2)+4*(lane>>5)

// wpk byte offsets:
//  0 W2f | 2048 aW1f | 4096 aW2f | 6144 eAf | 8192 eBf | 10240 vo1f
//  12288 B2f | 16384 aB1c | 20480 aB2c | 24576 eB1c | 28672 vo1bc
//  32768 Ea32 | 36864 Ea33 | 40960 Eb32 | 45056 Eb33
//  49152 cW1f | 51200 cW2f | 53248 vW1h0f | 55296 vW1h1f | 57344 vW2f
//  59392 axW0 | 63488 axW1 | 67584 axb
//  71680 cb1c | 75776 cb2c | 79872 vb1c | 83968 vb2c

// ---------------- vert transpose + deg zero ----------------
__global__ void k_tr(const float* __restrict__ vert, float* __restrict__ vt,
                     int* __restrict__ deg) {
    __shared__ float s[2816];
    int n0 = blockIdx.x * 4;
    int t = threadIdx.x;
    if (blockIdx.x == 0)
        for (int i = t; i < 1024; i += 256) deg[i] = 0;
    int b = t >> 2, r = t & 3;
    const float* vp = vert + ((size_t)b * NN + n0 + r) * 11;
#pragma unroll
    for (int i = 0; i < 11; i++) s[r * 704 + i * 64 + b] = vp[i];
    __syncthreads();
    float* o = vt + (size_t)n0 * 704;
#pragma unroll
    for (int j = 0; j < 11; j++) o[j * 256 + t] = s[j * 256 + t];
}

// ---------------- CSR build ----------------
__global__ void k_deg(const int* __restrict__ edges, int* __restrict__ deg) {
    int e = blockIdx.x * 256 + threadIdx.x;
    if (e < NE) {
        atomicAdd(&deg[edges[e]], 1);
        atomicAdd(&deg[edges[NE + e]], 1);
    }
}

__global__ void k_scan(const int* __restrict__ deg, int* __restrict__ offs,
                       int* __restrict__ cursor) {
    __shared__ int s[1024];
    int t = threadIdx.x;
    int d = (t < NN) ? deg[t] : 0;
    s[t] = d;
    __syncthreads();
    for (int k = 1; k < 1024; k <<= 1) {
        int v = (t >= k) ? s[t - k] : 0;
        __syncthreads();
        s[t] += v;
        __syncthreads();
    }
    if (t < NN) {
        offs[t + 1] = s[t];
        cursor[t] = s[t] - d;
    }
    if (t == 0) offs[0] = 0;
}

__global__ void k_fillA(const int* __restrict__ edges, int* __restrict__ cursor,
                        int* __restrict__ adj) {
    int e = blockIdx.x * 256 + threadIdx.x;
    if (e < NE) {
        int s = edges[e], d = edges[NE + e];
        int p1 = atomicAdd(&cursor[s], 1);
        adj[p1] = (e << 10) | d;
        int p2 = atomicAdd(&cursor[d], 1);
        adj[p2] = (1 << 30) | (e << 10) | s;
    }
}

// wave-parallel canonical rank sort (keys unique -> deterministic order)
__global__ void k_sort(const int* __restrict__ offs, int* __restrict__ adj,
                       int* __restrict__ cntA) {
    __shared__ int keys[4][ADJCAP];
    int w = threadIdx.x >> 6;
    int lane = threadIdx.x & 63;
    int n = blockIdx.x * 4 + w;
    int o0 = offs[n], o1 = offs[n + 1];
    int deg = o1 - o0;
    int cap = (deg < ADJCAP) ? deg : ADJCAP;
    for (int i = lane; i < cap; i += 64) keys[w][i] = adj[o0 + i];
    __syncthreads();
    if (deg <= ADJCAP) {
        for (int i = lane; i < deg; i += 64) {
            int k = keys[w][i];
            int r = 0;
            for (int j = 0; j < deg; j++) r += (keys[w][j] < k) ? 1 : 0;
            adj[o0 + r] = k;
        }
        if (lane == 0) {
            int c = 0;
            for (int j = 0; j < deg; j++) c += ((keys[w][j] >> 30) & 1) ? 0 : 1;
            cntA[n] = c;
        }
    } else if (lane == 0) {
        for (int i = o0 + 1; i < o1; i++) {
            int key = adj[i];
            int j = i - 1;
            while (j >= o0 && adj[j] > key) { adj[j + 1] = adj[j]; j--; }
            adj[j + 1] = key;
        }
        int c = 0;
        for (int i = o0; i < o1; i++) c += ((adj[i] >> 30) & 1) ? 0 : 1;
        cntA[n] = c;
    }
}

// ---------------- weight pre-pack (one wave) ----------------
__global__ void k_wsetup2(const float* __restrict__ eW2, const float* __restrict__ eb2,
                          const float* __restrict__ aW1, const float* __restrict__ ab1,
                          const float* __restrict__ aW2, const float* __restrict__ ab2,
                          const float* __restrict__ eW1, const float* __restrict__ eb1,
                          const float* __restrict__ oW1, const float* __restrict__ ob1,
                          const float* __restrict__ xW, const float* __restrict__ xb,
                          const float* __restrict__ yW, const float* __restrict__ yb,
                          const float* __restrict__ tW, const float* __restrict__ tb,
                          const float* __restrict__ cW1, const float* __restrict__ cb1,
                          const float* __restrict__ cW2, const float* __restrict__ cb2,
                          const float* __restrict__ vW1, const float* __restrict__ vb1,
                          const float* __restrict__ vW2, const float* __restrict__ vb2,
                          char* __restrict__ wpk) {
    int l = threadIdx.x;  // 64
    int row = l & 31, kg = l >> 5;

    auto packAK = [&](const float* W, int ldw, int coff, int K, short8* dst) {
#pragma unroll
        for (int kh = 0; kh < 2; kh++) {
            S8 a;
#pragma unroll
            for (int j = 0; j < 8; j++) {
                int k = kh * 16 + kg * 8 + j;
                a.e[j] = (k < K) ? (_Float16)W[row * ldw + coff + k] : (_Float16)0.f;
            }
            dst[kh * 64 + l] = a.v;
        }
    };
    packAK(eW2, 32, 0, 32, (short8*)(wpk + 0));
    packAK(aW1, 32, 0, 32, (short8*)(wpk + 2048));
    packAK(aW2, 32, 0, 32, (short8*)(wpk + 4096));
    packAK(eW1, 68, 0, 32, (short8*)(wpk + 6144));
    packAK(eW1, 68, 34, 32, (short8*)(wpk + 8192));
    packAK(oW1, 32, 0, 32, (short8*)(wpk + 10240));
    packAK(cW1, 24, 0, 24, (short8*)(wpk + 49152));
    packAK(cW2, 32, 0, 32, (short8*)(wpk + 51200));
    packAK(vW1, 64, 0, 32, (short8*)(wpk + 53248));
    packAK(vW1, 64, 32, 32, (short8*)(wpk + 55296));
    packAK(vW2, 32, 0, 32, (short8*)(wpk + 57344));

    float* B2f   = (float*)(wpk + 12288);
    float* aB1c  = (float*)(wpk + 16384);
    float* aB2c  = (float*)(wpk + 20480);
    float* eB1c  = (float*)(wpk + 24576);
    float* vo1bc = (float*)(wpk + 28672);
    float* Ea32  = (float*)(wpk + 32768);
    float* Ea33  = (float*)(wpk + 36864);
    float* Eb32  = (float*)(wpk + 40960);
    float* Eb33  = (float*)(wpk + 45056);
    float* cb1c  = (float*)(wpk + 71680);
    float* cb2c  = (float*)(wpk + 75776);
    float* vb1c  = (float*)(wpk + 79872);
    float* vb2c  = (float*)(wpk + 83968);
#pragma unroll
    for (int r = 0; r < 16; r++) {
        int rr = (r & 3) + 8 * (r >> 2) + 4 * kg;
        B2f[l * 16 + r]   = eb2[rr];
        aB1c[l * 16 + r]  = ab1[rr];
        aB2c[l * 16 + r]  = ab2[rr];
        eB1c[l * 16 + r]  = eb1[rr];
        vo1bc[l * 16 + r] = ob1[rr];
        Ea32[l * 16 + r]  = eW1[rr * 68 + 32];
        Ea33[l * 16 + r]  = eW1[rr * 68 + 33];
        Eb32[l * 16 + r]  = eW1[rr * 68 + 66];
        Eb33[l * 16 + r]  = eW1[rr * 68 + 67];
        cb1c[l * 16 + r]  = cb1[rr];
        cb2c[l * 16 + r]  = cb2[rr];
        vb1c[l * 16 + r]  = vb1[rr];
        vb2c[l * 16 + r]  = vb2[rr];
    }

    float* axW0 = (float*)(wpk + 59392);
    float* axW1 = (float*)(wpk + 63488);
    float* axb  = (float*)(wpk + 67584);
#pragma unroll
    for (int kh = 0; kh < 2; kh++) {
#pragma unroll
        for (int j = 0; j < 8; j++) {
            int k = kh * 16 + kg * 8 + j;
            int i = k >> 3, c = k & 7;
            float w0 = 0.f, w1 = 0.f, bb = 0.f;
            if (i < 3) {
                const float* W = (i == 0) ? xW : ((i == 1) ? yW : tW);
                const float* B = (i == 0) ? xb : ((i == 1) ? yb : tb);
                w0 = W[c * 2]; w1 = W[c * 2 + 1]; bb = B[c];
            }
            axW0[kh * 512 + l * 8 + j] = w0;
            axW1[kh * 512 + l * 8 + j] = w1;
            axb[kh * 512 + l * 8 + j]  = bb;
        }
    }
}

// ---------------- MFMA pass-0 prep: 1 wave per (node, batch-half) ----------------
__global__ __launch_bounds__(256) void k_prep0f(
    const float* __restrict__ vt, const char* __restrict__ wpk,
    short* __restrict__ Ap, short* __restrict__ Bp) {
    __shared__ float loc4[4][1056];
    int w = threadIdx.x >> 6;
    int lane = threadIdx.x & 63;
    int lane31 = lane & 31, kg = lane >> 5, g8 = kg * 8;
    int n = blockIdx.x * 2 + (w >> 1);
    int bh = w & 1;
    int col = bh * 32 + lane31;
    float* loc = loc4[w];
    const float* vn = vt + (size_t)n * 704;

    const short8* cW1f = (const short8*)(wpk + 49152);
    const short8* cW2f = (const short8*)(wpk + 51200);
    const short8* vW1f0 = (const short8*)(wpk + 53248);
    const short8* vW1f1 = (const short8*)(wpk + 55296);
    const short8* vW2f = (const short8*)(wpk + 57344);
    const short8* eAf = (const short8*)(wpk + 6144);
    const short8* eBf = (const short8*)(wpk + 8192);
    const float* axW0 = (const float*)(wpk + 59392);
    const float* axW1 = (const float*)(wpk + 63488);
    const float* axb  = (const float*)(wpk + 67584);
    const float* cb1c = (const float*)(wpk + 71680) + lane * 16;
    const float* cb2c = (const float*)(wpk + 75776) + lane * 16;
    const float* vb1c = (const float*)(wpk + 79872) + lane * 16;
    const float* vb2c = (const float*)(wpk + 83968) + lane * 16;

    const f32x16 zero = {};

#define C2FRAG(Creg, F0, F1) do {                                              \
    _Pragma("unroll") for (int r = 0; r < 16; r++)                             \
        loc[lane31 * 33 + ((r & 3) + 8 * (r >> 2) + 4 * kg)] = Creg[r];        \
    _Pragma("unroll") for (int j = 0; j < 8; j++) {                            \
        F0.e[j] = (_Float16)loc[lane31 * 33 + g8 + j];                         \
        F1.e[j] = (_Float16)loc[lane31 * 33 + 16 + g8 + j]; }                  \
} while (0)

    f32x16 V1;
#pragma unroll
    for (int r = 0; r < 16; r++) V1[r] = vb1c[r];

#pragma unroll
    for (int half = 0; half < 2; half++) {
        S8 ff0, ff1;
#pragma unroll
        for (int kh = 0; kh < 2; kh++) {
            int i = kh * 2 + kg;
            float p0 = vn[i * 64 + col];
            float p1 = vn[((half ? 6 : 3) + i) * 64 + col];
            const float* w0p = axW0 + kh * 512 + lane * 8;
            const float* w1p = axW1 + kh * 512 + lane * 8;
            const float* bp  = axb  + kh * 512 + lane * 8;
            S8 f;
#pragma unroll
            for (int j = 0; j < 8; j++) {
                float x = w0p[j] * p0 + w1p[j] * p1 + bp[j];
                f.e[j] = (_Float16)fmaxf(x, 0.01f * x);
            }
            if (kh == 0) ff0 = f; else ff1 = f;
        }
        S8 cw0, cw1; cw0.v = cW1f[lane]; cw1.v = cW1f[64 + lane];
        f32x16 C = __builtin_amdgcn_mfma_f32_32x32x16_f16(cw0.h, ff0.h, zero, 0, 0, 0);
        C = __builtin_amdgcn_mfma_f32_32x32x16_f16(cw1.h, ff1.h, C, 0, 0, 0);
#pragma unroll
        for (int r = 0; r < 16; r++) { float m = C[r] + cb1c[r]; C[r] = fmaxf(m, 0.01f * m); }
        S8 hf0, hf1;
        C2FRAG(C, hf0, hf1);
        cw0.v = cW2f[lane]; cw1.v = cW2f[64 + lane];
        C = __builtin_amdgcn_mfma_f32_32x32x16_f16(cw0.h, hf0.h, zero, 0, 0, 0);
        C = __builtin_amdgcn_mfma_f32_32x32x16_f16(cw1.h, hf1.h, C, 0, 0, 0);
#pragma unroll
        for (int r = 0; r < 16; r++) { float m = C[r] + cb2c[r]; C[r] = fmaxf(m, 0.01f * m); }
        S8 cf0, cf1;
        C2FRAG(C, cf0, cf1);
        const short8* vf = half ? vW1f1 : vW1f0;
        S8 vw0, vw1; vw0.v = vf[lane]; vw1.v = vf[64 + lane];
        V1 = __builtin_amdgcn_mfma_f32_32x32x16_f16(vw0.h, cf0.h, V1, 0, 0, 0);
        V1 = __builtin_amdgcn_mfma_f32_32x32x16_f16(vw1.h, cf1.h, V1, 0, 0, 0);
    }
#pragma unroll
    for (int r = 0; r < 16; r++) V1[r] = fmaxf(V1[r], 0.01f * V1[r]);
    S8 v1f0, v1f1;
    C2FRAG(V1, v1f0, v1f1);
    S8 vw0, vw1; vw0.v = vW2f[lane]; vw1.v = vW2f[64 + lane];
    f32x16 V2 = __builtin_amdgcn_mfma_f32_32x32x16_f16(vw0.h, v1f0.h, zero, 0, 0, 0);
    V2 = __builtin_amdgcn_mfma_f32_32x32x16_f16(vw1.h, v1f1.h, V2, 0, 0, 0);
#pragma unroll
    for (int r = 0; r < 16; r++) { float m = V2[r] + vb2c[r]; V2[r] = fmaxf(m, 0.01f * m); }
    S8 vf0, vf1;
    C2FRAG(V2, vf0, vf1);

    float c0 = vn[9 * 64 + col];
    float c1 = vn[10 * 64 + col];

    S8 ea0, ea1; ea0.v = eAf[lane]; ea1.v = eAf[64 + lane];
    f32x16 SA = __builtin_amdgcn_mfma_f32_32x32x16_f16(ea0.h, vf0.h, zero, 0, 0, 0);
    SA = __builtin_amdgcn_mfma_f32_32x32x16_f16(ea1.h, vf1.h, SA, 0, 0, 0);
    {
        const float* eb = (const float*)(wpk + 24576) + lane * 16;
        const float* e2 = (const float*)(wpk + 32768) + lane * 16;
        const float* e3 = (const float*)(wpk + 36864) + lane * 16;
#pragma unroll
        for (int r = 0; r < 16; r++) SA[r] += eb[r] + e2[r] * c0 + e3[r] * c1;
    }
    S8 p0, p1;
    C2FRAG(SA, p0, p1);
    ((short8*)(Ap + (size_t)n * 2048))[bh * 64 + lane] = p0.v;
    ((short8*)(Ap + (size_t)n * 2048))[(2 + bh) * 64 + lane] = p1.v;

    S8 eb0, eb1f; eb0.v = eBf[lane]; eb1f.v = eBf[64 + lane];
    f32x16 SB = __builtin_amdgcn_mfma_f32_32x32x16_f16(eb0.h, vf0.h, zero, 0, 0, 0);
    SB = __builtin_amdgcn_mfma_f32_32x32x16_f16(eb1f.h, vf1.h, SB, 0, 0, 0);
    {
        const float* e2 = (const float*)(wpk + 40960) + lane * 16;
        const float* e3 = (const float*)(wpk + 45056) + lane * 16;
#pragma unroll
        for (int r = 0; r < 16; r++) SB[r] += e2[r] * c0 + e3[r] * c1;
    }
    C2FRAG(SB, p0, p1);
    ((short8*)(Bp + (size_t)n * 2048))[bh * 64 + lane] = p0.v;
    ((short8*)(Bp + (size_t)n * 2048))[(2 + bh) * 64 + lane] = p1.v;
#undef C2FRAG
}

// ---------------- fused edge pass: packed-fp16 visit + 2-deep prefetch ----------------
#define VISITH(C0, C1, C2, C3) do {                                                       \
    S8 h10, h11;                                                                          \
    h10.h = h8lreluadd(ba0.h, C0.h);                                                      \
    h11.h = h8lreluadd(ba2.h, C2.h);                                                      \
    f32x16 d = __builtin_amdgcn_mfma_f32_32x32x16_f16(w2f0.h, h10.h, zero, 0, 0, 0);      \
    d = __builtin_amdgcn_mfma_f32_32x32x16_f16(w2f1.h, h11.h, d, 0, 0, 0);                \
    _Pragma("unroll") for (int r = 0; r < 16; r++) {                                      \
        float m = d[r] + b2v[r]; acc0[r] += fmaxf(m, 0.01f * m); }                        \
    h10.h = h8lreluadd(ba1.h, C1.h);                                                      \
    h11.h = h8lreluadd(ba3.h, C3.h);                                                      \
    d = __builtin_amdgcn_mfma_f32_32x32x16_f16(w2f0.h, h10.h, zero, 0, 0, 0);             \
    d = __builtin_amdgcn_mfma_f32_32x32x16_f16(w2f1.h, h11.h, d, 0, 0, 0);                \
    _Pragma("unroll") for (int r = 0; r < 16; r++) {                                      \
        float m = d[r] + b2v[r]; acc1[r] += fmaxf(m, 0.01f * m); }                        \
} while (0)

#define LOADO(P0, P1, P2, P3, idx) do {                                                   \
    int o_ = ((idx) < ADJCAP) ? adjl[idx] : (adjg[off0 + (idx)] & 1023);                  \
    const short8* op_ = ogBase + (size_t)o_ * 256;                                        \
    P0.v = op_[lane]; P1.v = op_[64 + lane];                                              \
    P2.v = op_[128 + lane]; P3.v = op_[192 + lane];                                       \
} while (0)

__global__ __launch_bounds__(256) void k_edge(
    const short* __restrict__ Apr, const short* __restrict__ Bpr,
    short* __restrict__ Apw, short* __restrict__ Bpw,
    const int* __restrict__ offs, const int* __restrict__ cntA,
    const int* __restrict__ adjg, const char* __restrict__ wpk,
    const float* __restrict__ vt, float* __restrict__ nv, float* __restrict__ fv,
    const float* __restrict__ oW2, const float* __restrict__ ob2,
    int pass0, int mode) {
    __shared__ float red[4][2112];
    __shared__ int adjl[ADJCAP];
    int n = blockIdx.x;
    int w = threadIdx.x >> 6;
    int lane = threadIdx.x & 63;
    int row = lane & 31, kg = lane >> 5;

    int off0 = offs[n], off1 = offs[n + 1];
    int deg = off1 - off0;
    int cA = cntA[n];

    for (int i = threadIdx.x; i < deg && i < ADJCAP; i += 256)
        adjl[i] = adjg[off0 + i] & 1023;
    __syncthreads();

    S8 w2f0, w2f1;
    w2f0.v = ((const short8*)wpk)[lane];
    w2f1.v = ((const short8*)wpk)[64 + lane];
    float b2v[16];
    {
        const float4* bp4 = (const float4*)((const float*)(wpk + 12288) + lane * 16);
#pragma unroll
        for (int q = 0; q < 4; q++) {
            float4 v = bp4[q];
            b2v[q * 4] = v.x; b2v[q * 4 + 1] = v.y;
            b2v[q * 4 + 2] = v.z; b2v[q * 4 + 3] = v.w;
        }
    }

    f32x16 acc0 = {};
    f32x16 acc1 = {};
    const f32x16 zero = {};

#pragma unroll
    for (int phase = 0; phase < 2; phase++) {
        const short* basePtr = phase ? Bpr : Apr;
        const short8* ogBase = (const short8*)(phase ? Apr : Bpr);
        int lstart = phase ? cA : 0;
        int lend   = phase ? deg : cA;

        S8 ba0, ba1, ba2, ba3;
        {
            const short8* np = (const short8*)(basePtr + (size_t)n * 2048);
            ba0.v = np[lane]; ba1.v = np[64 + lane];
            ba2.v = np[128 + lane]; ba3.v = np[192 + lane];
        }

        int li = lstart + w;
        S8 A0 = {}, A1 = {}, A2 = {}, A3 = {};
        S8 B0 = {}, B1 = {}, B2 = {}, B3 = {};
        if (li < lend) LOADO(A0, A1, A2, A3, li);
        if (li + 4 < lend) LOADO(B0, B1, B2, B3, li + 4);
        while (li < lend) {
            {
                int lp = li + 8;
                S8 n0 = {}, n1 = {}, n2 = {}, n3 = {};
                if (lp < lend) LOADO(n0, n1, n2, n3, lp);
                VISITH(A0, A1, A2, A3);
                A0 = n0; A1 = n1; A2 = n2; A3 = n3;
            }
            li += 4;
            if (li >= lend) break;
            {
                int lp = li + 8;
                S8 n0 = {}, n1 = {}, n2 = {}, n3 = {};
                if (lp < lend) LOADO(n0, n1, n2, n3, lp);
                VISITH(B0, B1, B2, B3);
                B0 = n0; B1 = n1; B2 = n2; B3 = n3;
            }
            li += 4;
        }
    }

    // ---- cross-wave reduce, nv update, stash new nv in red[0] as (b,oc) ----
#pragma unroll
    for (int bh = 0; bh < 2; bh++) {
        int b = bh * 32 + row;
#pragma unroll
        for (int r = 0; r < 16; r++) {
            int oc = (r & 3) + 8 * (r >> 2) + 4 * kg;
            red[w][b * 33 + oc] = bh ? acc1[r] : acc0[r];
        }
    }
    __syncthreads();

    {
        int t = threadIdx.x;
        size_t nb = (size_t)n * (NB * 32);
        float inv = (deg > 0) ? 1.f / (float)deg : 0.f;
#pragma unroll
        for (int j = 0; j < 8; j++) {
            int idx = t * 8 + j;
            int bb = idx >> 5, cc = idx & 31;
            float s;
            if (deg > 0) {
                s = (red[0][bb * 33 + cc] + red[1][bb * 33 + cc] +
                     red[2][bb * 33 + cc] + red[3][bb * 33 + cc]) * inv;
                if (!pass0) s += nv[nb + idx];
            } else {
                s = pass0 ? 0.f : nv[nb + idx];
            }
            nv[nb + idx] = s;
            red[0][bb * 33 + cc] = s;
        }
    }
    __syncthreads();

    // ---- fused node prep (waves 0,1; each owns one 32-col half) ----
    if (w < 2) {
        int bh = w;
        int lane31 = lane & 31;
        int g8 = (lane >> 5) * 8;
        float* loc = red[2 + w];
        const float* cb;
        S8 a0, a1;

        S8 xf0, xf1;
#pragma unroll
        for (int j = 0; j < 8; j++) {
            xf0.e[j] = (_Float16)red[0][(bh * 32 + lane31) * 33 + g8 + j];
            xf1.e[j] = (_Float16)red[0][(bh * 32 + lane31) * 33 + 16 + g8 + j];
        }

        if (mode == 0) {
            a0.v = ((const short8*)(wpk + 2048))[lane];
            a1.v = ((const short8*)(wpk + 2048))[64 + lane];
            f32x16 C = {};
            C = __builtin_amdgcn_mfma_f32_32x32x16_f16(a0.h, xf0.h, C, 0, 0, 0);
            C = __builtin_amdgcn_mfma_f32_32x32x16_f16(a1.h, xf1.h, C, 0, 0, 0);
            cb = (const float*)(wpk + 16384) + lane * 16;
#pragma unroll
            for (int r = 0; r < 16; r++) { float m = C[r] + cb[r]; C[r] = fmaxf(m, 0.01f * m); }
#pragma unroll
            for (int r = 0; r < 16; r++) {
                int oc = (r & 3) + 8 * (r >> 2) + 4 * kg;
                loc[lane31 * 33 + oc] = C[r];
            }
            S8 hf0, hf1;
#pragma unroll
            for (int j = 0; j < 8; j++) {
                hf0.e[j] = (_Float16)loc[lane31 * 33 + g8 + j];
                hf1.e[j] = (_Float16)loc[lane31 * 33 + 16 + g8 + j];
            }
            a0.v = ((const short8*)(wpk + 4096))[lane];
            a1.v = ((const short8*)(wpk + 4096))[64 + lane];
            f32x16 V = {};
            V = __builtin_amdgcn_mfma_f32_32x32x16_f16(a0.h, hf0.h, V, 0, 0, 0);
            V = __builtin_amdgcn_mfma_f32_32x32x16_f16(a1.h, hf1.h, V, 0, 0, 0);
            cb = (const float*)(wpk + 20480) + lane * 16;
#pragma unroll
            for (int r = 0; r < 16; r++) { float m = V[r] + cb[r]; V[r] = fmaxf(m, 0.01f * m); }
#pragma unroll
            for (int r = 0; r < 16; r++) {
                int oc = (r & 3) + 8 * (r >> 2) + 4 * kg;
                loc[lane31 * 33 + oc] = V[r];
            }
            S8 vf0, vf1;
#pragma unroll
            for (int j = 0; j < 8; j++) {
                vf0.e[j] = (_Float16)loc[lane31 * 33 + g8 + j];
                vf1.e[j] = (_Float16)loc[lane31 * 33 + 16 + g8 + j];
            }
            float c0 = vt[(size_t)n * 704 + 9 * 64 + bh * 32 + lane31];
            float c1 = vt[(size_t)n * 704 + 10 * 64 + bh * 32 + lane31];

            a0.v = ((const short8*)(wpk + 6144))[lane];
            a1.v = ((const short8*)(wpk + 6144))[64 + lane];
            f32x16 SA = {};
            SA = __builtin_amdgcn_mfma_f32_32x32x16_f16(a0.h, vf0.h, SA, 0, 0, 0);
            SA = __builtin_amdgcn_mfma_f32_32x32x16_f16(a1.h, vf1.h, SA, 0, 0, 0);
            {
                const float* eb = (const float*)(wpk + 24576) + lane * 16;
                const float* e2 = (const float*)(wpk + 32768) + lane * 16;
                const float* e3 = (const float*)(wpk + 36864) + lane * 16;
#pragma unroll
                for (int r = 0; r < 16; r++) SA[r] += eb[r] + e2[r] * c0 + e3[r] * c1;
            }
#pragma unroll
            for (int r = 0; r < 16; r++) {
                int oc = (r & 3) + 8 * (r >> 2) + 4 * kg;
                loc[lane31 * 33 + oc] = SA[r];
            }
            {
                S8 p0, p1;
#pragma unroll
                for (int j = 0; j < 8; j++) {
                    p0.e[j] = (_Float16)loc[lane31 * 33 + g8 + j];
                    p1.e[j] = (_Float16)loc[lane31 * 33 + 16 + g8 + j];
                }
                ((short8*)(Apw + (size_t)n * 2048))[bh * 64 + lane] = p0.v;
                ((short8*)(Apw + (size_t)n * 2048))[(2 + bh) * 64 + lane] = p1.v;
            }
            a0.v = ((const short8*)(wpk + 8192))[lane];
            a1.v = ((const short8*)(wpk + 8192))[64 + lane];
            f32x16 SB = {};
            SB = __builtin_amdgcn_mfma_f32_32x32x16_f16(a0.h, vf0.h, SB, 0, 0, 0);
            SB = __builtin_amdgcn_mfma_f32_32x32x16_f16(a1.h, vf1.h, SB, 0, 0, 0);
            {
                const float* e2 = (const float*)(wpk + 40960) + lane * 16;
                const float* e3 = (const float*)(wpk + 45056) + lane * 16;
#pragma unroll
                for (int r = 0; r < 16; r++) SB[r] += e2[r] * c0 + e3[r] * c1;
            }
#pragma unroll
            for (int r = 0; r < 16; r++) {
                int oc = (r & 3) + 8 * (r >> 2) + 4 * kg;
                loc[lane31 * 33 + oc] = SB[r];
            }
            {
                S8 p0, p1;
#pragma unroll
                for (int j = 0; j < 8; j++) {
                    p0.e[j] = (_Float16)loc[lane31 * 33 + g8 + j];
                    p1.e[j] = (_Float16)loc[lane31 * 33 + 16 + g8 + j];
                }
                ((short8*)(Bpw + (size_t)n * 2048))[bh * 64 + lane] = p0.v;
                ((short8*)(Bpw + (size_t)n * 2048))[(2 + bh) * 64 + lane] = p1.v;
            }
        } else {
            a0.v = ((const short8*)(wpk + 10240))[lane];
            a1.v = ((const short8*)(wpk + 10240))[64 + lane];
            f32x16 C = {};
            C = __builtin_amdgcn_mfma_f32_32x32x16_f16(a0.h, xf0.h, C, 0, 0, 0);
            C = __builtin_amdgcn_mfma_f32_32x32x16_f16(a1.h, xf1.h, C, 0, 0, 0);
            cb = (const float*)(wpk + 28672) + lane * 16;
#pragma unroll
            for (int r = 0; r < 16; r++) { float m = C[r] + cb[r]; C[r] = fmaxf(m, 0.01f * m); }
#pragma unroll
            for (int r = 0; r < 16; r++) {
                int oc = (r & 3) + 8 * (r >> 2) + 4 * kg;
                loc[lane31 * 33 + oc] = C[r];
            }
            float s = 0.f;
#pragma unroll
            for (int o = 0; o < 16; o++) {
                int oc = (lane >> 5) * 16 + o;
                s += oW2[oc] * loc[lane31 * 33 + oc];
            }
            s += __shfl_xor(s, 32);
            if (lane < 32) {
                float v = s + ob2[0];
                fv[n * 64 + bh * 32 + lane31] = fmaxf(v, 0.01f * v);
            }
        }
    }
}

// ---------------- final reduce over nodes ----------------
__global__ void k_final2(const float* __restrict__ fv, const float* __restrict__ gW,
                         const float* __restrict__ gb, float* __restrict__ out) {
    int b = blockIdx.x;
    int t = threadIdx.x;
    float part = 0.f;
    for (int n = t; n < NN; n += 256) part += fv[n * 64 + b] * gW[n];
    __shared__ float rs[256];
    rs[t] = part;
    __syncthreads();
    for (int d = 128; d > 0; d >>= 1) {
        if (t < d) rs[t] += rs[t + d];
        __syncthreads();
    }
    if (t == 0) out[b] = 1.f / (1.f + expf(-(rs[0] + gb[0])));
}

extern "C" void kernel_launch(void* const* d_in, const int* in_sizes, int n_in,
                              void* d_out, int out_size, void* d_ws, size_t ws_size,
                              hipStream_t stream) {
    (void)in_sizes; (void)n_in; (void)out_size; (void)ws_size;
    const float* vert = (const float*)d_in[0];
    const int* edges  = (const int*)d_in[1];
    const float* xW   = (const float*)d_in[2];
    const float* xb   = (const float*)d_in[3];
    const float* yW   = (const float*)d_in[4];
    const float* yb   = (const float*)d_in[5];
    const float* tW   = (const float*)d_in[6];
    const float* tb   = (const float*)d_in[7];
    const float* cW1  = (const float*)d_in[8];
    const float* cb1  = (const float*)d_in[9];
    const float* cW2  = (const float*)d_in[10];
    const float* cb2  = (const float*)d_in[11];
    const float* vW1  = (const float*)d_in[12];
    const float* vb1  = (const float*)d_in[13];
    const float* vW2  = (const float*)d_in[14];
    const float* vb2  = (const float*)d_in[15];
    const float* eW1  = (const float*)d_in[16];
    const float* eb1  = (const float*)d_in[17];
    const float* eW2  = (const float*)d_in[18];
    const float* eb2  = (const float*)d_in[19];
    const float* aW1  = (const float*)d_in[20];
    const float* ab1  = (const float*)d_in[21];
    const float* aW2  = (const float*)d_in[22];
    const float* ab2  = (const float*)d_in[23];
    const float* oW1  = (const float*)d_in[24];
    const float* ob1  = (const float*)d_in[25];
    const float* oW2  = (const float*)d_in[26];
    const float* ob2  = (const float*)d_in[27];
    const float* gW   = (const float*)d_in[28];
    const float* gb   = (const float*)d_in[29];
    float* out = (float*)d_out;

    char* w = (char*)d_ws;
    short* ApA = (short*)(w + 0);
    short* BpA = (short*)(w + (4u << 20));
    short* ApB = (short*)(w + (8u << 20));
    short* BpB = (short*)(w + (12u << 20));
    float* nv  = (float*)(w + (16u << 20));
    float* vt  = (float*)(w + (25u << 20));
    float* fv  = (float*)(w + (28u << 20));
    char*  wpk = w + (28u << 20) + (512u << 10);       // 128 KB
    int* deg    = (int*)(w + (29u << 20));
    int* offs   = deg + 1024;
    int* cursor = offs + 1024;
    int* cntA   = cursor + 1024;
    int* adj    = cntA + 1024;

    k_tr<<<NN / 4, 256, 0, stream>>>(vert, vt, deg);
    k_deg<<<(NE + 255) / 256, 256, 0, stream>>>(edges, deg);
    k_scan<<<1, 1024, 0, stream>>>(deg, offs, cursor);
    k_fillA<<<(NE + 255) / 256, 256, 0, stream>>>(edges, cursor, adj);
    k_sort<<<NN / 4, 256, 0, stream>>>(offs, adj, cntA);
    k_wsetup2<<<1, 64, 0, stream>>>(eW2, eb2, aW1, ab1, aW2, ab2, eW1, eb1, oW1, ob1,
                                    xW, xb, yW, yb, tW, tb, cW1, cb1, cW2, cb2,
                                    vW1, vb1, vW2, vb2, wpk);

    k_prep0f<<<NN / 2, 256, 0, stream>>>(vt, wpk, ApA, BpA);

    short* bufs[2][2] = {{ApA, BpA}, {ApB, BpB}};
    for (int p = 0; p < 6; p++) {
        int rb = p & 1, wb = rb ^ 1;
        int mode = (p == 5) ? 1 : 0;
        int pass0 = (p == 0) ? 1 : 0;
        k_edge<<<NN, 256, 0, stream>>>(bufs[rb][0], bufs[rb][1],
                                       bufs[wb][0], bufs[wb][1],
                                       offs, cntA, adj, wpk, vt, nv, fv,
                                       oW2, ob2, pass0, mode);
    }

    k_final2<<<NB, 256, 0, stream>>>(fv, gW, gb, out);
}

// Round 12
// 287.988 us; speedup vs baseline: 11.2529x; 1.0133x over previous
//
#include <hip/hip_runtime.h>
#include <hip/hip_fp16.h>
#include <cstdint>
#include <cstddef>

#define NB 64      // batch
#define NN 1000    // nodes
#define NE 16000   // edges
#define ADJCAP 256

typedef __attribute__((ext_vector_type(8))) short short8;
typedef __attribute__((ext_vector_type(8))) _Float16 half8;
typedef __attribute__((ext_vector_type(16))) float f32x16;

__device__ __forceinline__ float lrelu(float x) { return fmaxf(x, 0.01f * x); }

union S8 { short8 v; half8 h; _Float16 e[8]; unsigned int u[4]; };

// packed fp16 lrelu(a+b) on 8 lanes: lowers to v_pk_add/mul/max_f16
__device__ __forceinline__ half8 h8lreluadd(half8 a, half8 b) {
    half8 x = a + b;
    half8 y = x * (_Float16)0.01f;
    return __builtin_elementwise_max(x, y);
}

// Fragment layout per node (2048 fp16 = 4KB):
//   value (k 0..31, b 0..63): fragment f=kh*2+bh; short8 index = n*256 + f*64 + lane
//   lane holds k=kh*16+(lane>>5)*8+j, b=bh*32+(lane&31)
// C layout (32x32 mfma): col=lane&31, row(r)=(r&3)+8*(r>>2)+4*(lane>>5)

// wpk byte offsets:
//  0 W2f | 2048 aW1f | 4096 aW2f | 6144 eAf | 8192 eBf | 10240 vo1f
//  12288 B2f | 16384 aB1c | 20480 aB2c | 24576 eB1c | 28672 vo1bc
//  32768 Ea32 | 36864 Ea33 | 40960 Eb32 | 45056 Eb33
//  49152 cW1f | 51200 cW2f | 53248 vW1h0f | 55296 vW1h1f | 57344 vW2f
//  59392 axW0 | 63488 axW1 | 67584 axb
//  71680 cb1c | 75776 cb2c | 79872 vb1c | 83968 vb2c

// ---------------- vert transpose + deg zero ----------------
__global__ void k_tr(const float* __restrict__ vert, float* __restrict__ vt,
                     int* __restrict__ deg) {
    __shared__ float s[2816];
    int n0 = blockIdx.x * 4;
    int t = threadIdx.x;
    if (blockIdx.x == 0)
        for (int i = t; i < 1024; i += 256) deg[i] = 0;
    int b = t >> 2, r = t & 3;
    const float* vp = vert + ((size_t)b * NN + n0 + r) * 11;
#pragma unroll
    for (int i = 0; i < 11; i++) s[r * 704 + i * 64 + b] = vp[i];
    __syncthreads();
    float* o = vt + (size_t)n0 * 704;
#pragma unroll
    for (int j = 0; j < 11; j++) o[j * 256 + t] = s[j * 256 + t];
}

// ---------------- CSR build ----------------
__global__ void k_deg(const int* __restrict__ edges, int* __restrict__ deg) {
    int e = blockIdx.x * 256 + threadIdx.x;
    if (e < NE) {
        atomicAdd(&deg[edges[e]], 1);
        atomicAdd(&deg[edges[NE + e]], 1);
    }
}

__global__ void k_scan(const int* __restrict__ deg, int* __restrict__ offs,
                       int* __restrict__ cursor) {
    __shared__ int s[1024];
    int t = threadIdx.x;
    int d = (t < NN) ? deg[t] : 0;
    s[t] = d;
    __syncthreads();
    for (int k = 1; k < 1024; k <<= 1) {
        int v = (t >= k) ? s[t - k] : 0;
        __syncthreads();
        s[t] += v;
        __syncthreads();
    }
    if (t < NN) {
        offs[t + 1] = s[t];
        cursor[t] = s[t] - d;
    }
    if (t == 0) offs[0] = 0;
}

__global__ void k_fillA(const int* __restrict__ edges, int* __restrict__ cursor,
                        int* __restrict__ adj) {
    int e = blockIdx.x * 256 + threadIdx.x;
    if (e < NE) {
        int s = edges[e], d = edges[NE + e];
        int p1 = atomicAdd(&cursor[s], 1);
        adj[p1] = (e << 10) | d;
        int p2 = atomicAdd(&cursor[d], 1);
        adj[p2] = (1 << 30) | (e << 10) | s;
    }
}

// wave-parallel canonical rank sort (keys unique -> deterministic order)
__global__ void k_sort(const int* __restrict__ offs, int* __restrict__ adj,
                       int* __restrict__ cntA) {
    __shared__ int keys[4][ADJCAP];
    int w = threadIdx.x >> 6;
    int lane = threadIdx.x & 63;
    int n = blockIdx.x * 4 + w;
    int o0 = offs[n], o1 = offs[n + 1];
    int deg = o1 - o0;
    int cap = (deg < ADJCAP) ? deg : ADJCAP;
    for (int i = lane; i < cap; i += 64) keys[w][i] = adj[o0 + i];
    __syncthreads();
    if (deg <= ADJCAP) {
        for (int i = lane; i < deg; i += 64) {
            int k = keys[w][i];
            int r = 0;
            for (int j = 0; j < deg; j++) r += (keys[w][j] < k) ? 1 : 0;
            adj[o0 + r] = k;
        }
        if (lane == 0) {
            int c = 0;
            for (int j = 0; j < deg; j++) c += ((keys[w][j] >> 30) & 1) ? 0 : 1;
            cntA[n] = c;
        }
    } else if (lane == 0) {
        for (int i = o0 + 1; i < o1; i++) {
            int key = adj[i];
            int j = i - 1;
            while (j >= o0 && adj[j] > key) { adj[j + 1] = adj[j]; j--; }
            adj[j + 1] = key;
        }
        int c = 0;
        for (int i = o0; i < o1; i++) c += ((adj[i] >> 30) & 1) ? 0 : 1;
        cntA[n] = c;
    }
}

// ---------------- weight pre-pack (one wave) ----------------
__global__ void k_wsetup2(const float* __restrict__ eW2, const float* __restrict__ eb2,
                          const float* __restrict__ aW1, const float* __restrict__ ab1,
                          const float* __restrict__ aW2, const float* __restrict__ ab2,
                          const float* __restrict__ eW1, const float* __restrict__ eb1,
                          const float* __restrict__ oW1, const float* __restrict__ ob1,
                          const float* __restrict__ xW, const float* __restrict__ xb,
                          const float* __restrict__ yW, const float* __restrict__ yb,
                          const float* __restrict__ tW, const float* __restrict__ tb,
                          const float* __restrict__ cW1, const float* __restrict__ cb1,
                          const float* __restrict__ cW2, const float* __restrict__ cb2,
                          const float* __restrict__ vW1, const float* __restrict__ vb1,
                          const float* __restrict__ vW2, const float* __restrict__ vb2,
                          char* __restrict__ wpk) {
    int l = threadIdx.x;  // 64
    int row = l & 31, kg = l >> 5;

    auto packAK = [&](const float* W, int ldw, int coff, int K, short8* dst) {
#pragma unroll
        for (int kh = 0; kh < 2; kh++) {
            S8 a;
#pragma unroll
            for (int j = 0; j < 8; j++) {
                int k = kh * 16 + kg * 8 + j;
                a.e[j] = (k < K) ? (_Float16)W[row * ldw + coff + k] : (_Float16)0.f;
            }
            dst[kh * 64 + l] = a.v;
        }
    };
    packAK(eW2, 32, 0, 32, (short8*)(wpk + 0));
    packAK(aW1, 32, 0, 32, (short8*)(wpk + 2048));
    packAK(aW2, 32, 0, 32, (short8*)(wpk + 4096));
    packAK(eW1, 68, 0, 32, (short8*)(wpk + 6144));
    packAK(eW1, 68, 34, 32, (short8*)(wpk + 8192));
    packAK(oW1, 32, 0, 32, (short8*)(wpk + 10240));
    packAK(cW1, 24, 0, 24, (short8*)(wpk + 49152));
    packAK(cW2, 32, 0, 32, (short8*)(wpk + 51200));
    packAK(vW1, 64, 0, 32, (short8*)(wpk + 53248));
    packAK(vW1, 64, 32, 32, (short8*)(wpk + 55296));
    packAK(vW2, 32, 0, 32, (short8*)(wpk + 57344));

    float* B2f   = (float*)(wpk + 12288);
    float* aB1c  = (float*)(wpk + 16384);
    float* aB2c  = (float*)(wpk + 20480);
    float* eB1c  = (float*)(wpk + 24576);
    float* vo1bc = (float*)(wpk + 28672);
    float* Ea32  = (float*)(wpk + 32768);
    float* Ea33  = (float*)(wpk + 36864);
    float* Eb32  = (float*)(wpk + 40960);
    float* Eb33  = (float*)(wpk + 45056);
    float* cb1c  = (float*)(wpk + 71680);
    float* cb2c  = (float*)(wpk + 75776);
    float* vb1c  = (float*)(wpk + 79872);
    float* vb2c  = (float*)(wpk + 83968);
#pragma unroll
    for (int r = 0; r < 16; r++) {
        int rr = (r & 3) + 8 * (r >> 2) + 4 * kg;
        B2f[l * 16 + r]   = eb2[rr];
        aB1c[l * 16 + r]  = ab1[rr];
        aB2c[l * 16 + r]  = ab2[rr];
        eB1c[l * 16 + r]  = eb1[rr];
        vo1bc[l * 16 + r] = ob1[rr];
        Ea32[l * 16 + r]  = eW1[rr * 68 + 32];
        Ea33[l * 16 + r]  = eW1[rr * 68 + 33];
        Eb32[l * 16 + r]  = eW1[rr * 68 + 66];
        Eb33[l * 16 + r]  = eW1[rr * 68 + 67];
        cb1c[l * 16 + r]  = cb1[rr];
        cb2c[l * 16 + r]  = cb2[rr];
        vb1c[l * 16 + r]  = vb1[rr];
        vb2c[l * 16 + r]  = vb2[rr];
    }

    float* axW0 = (float*)(wpk + 59392);
    float* axW1 = (float*)(wpk + 63488);
    float* axb  = (float*)(wpk + 67584);
#pragma unroll
    for (int kh = 0; kh < 2; kh++) {
#pragma unroll
        for (int j = 0; j < 8; j++) {
            int k = kh * 16 + kg * 8 + j;
            int i = k >> 3, c = k & 7;
            float w0 = 0.f, w1 = 0.f, bb = 0.f;
            if (i < 3) {
                const float* W = (i == 0) ? xW : ((i == 1) ? yW : tW);
                const float* B = (i == 0) ? xb : ((i == 1) ? yb : tb);
                w0 = W[c * 2]; w1 = W[c * 2 + 1]; bb = B[c];
            }
            axW0[kh * 512 + l * 8 + j] = w0;
            axW1[kh * 512 + l * 8 + j] = w1;
            axb[kh * 512 + l * 8 + j]  = bb;
        }
    }
}

// ---------------- MFMA pass-0 prep: 1 wave per (node, batch-half) ----------------
__global__ __launch_bounds__(256) void k_prep0f(
    const float* __restrict__ vt, const char* __restrict__ wpk,
    short* __restrict__ Ap, short* __restrict__ Bp) {
    __shared__ float loc4[4][1056];
    int w = threadIdx.x >> 6;
    int lane = threadIdx.x & 63;
    int lane31 = lane & 31, kg = lane >> 5, g8 = kg * 8;
    int n = blockIdx.x * 2 + (w >> 1);
    int bh = w & 1;
    int col = bh * 32 + lane31;
    float* loc = loc4[w];
    const float* vn = vt + (size_t)n * 704;

    const short8* cW1f = (const short8*)(wpk + 49152);
    const short8* cW2f = (const short8*)(wpk + 51200);
    const short8* vW1f0 = (const short8*)(wpk + 53248);
    const short8* vW1f1 = (const short8*)(wpk + 55296);
    const short8* vW2f = (const short8*)(wpk + 57344);
    const short8* eAf = (const short8*)(wpk + 6144);
    const short8* eBf = (const short8*)(wpk + 8192);
    const float* axW0 = (const float*)(wpk + 59392);
    const float* axW1 = (const float*)(wpk + 63488);
    const float* axb  = (const float*)(wpk + 67584);
    const float* cb1c = (const float*)(wpk + 71680) + lane * 16;
    const float* cb2c = (const float*)(wpk + 75776) + lane * 16;
    const float* vb1c = (const float*)(wpk + 79872) + lane * 16;
    const float* vb2c = (const float*)(wpk + 83968) + lane * 16;

    const f32x16 zero = {};

#define C2FRAG(Creg, F0, F1) do {                                              \
    _Pragma("unroll") for (int r = 0; r < 16; r++)                             \
        loc[lane31 * 33 + ((r & 3) + 8 * (r >> 2) + 4 * kg)] = Creg[r];        \
    _Pragma("unroll") for (int j = 0; j < 8; j++) {                            \
        F0.e[j] = (_Float16)loc[lane31 * 33 + g8 + j];                         \
        F1.e[j] = (_Float16)loc[lane31 * 33 + 16 + g8 + j]; }                  \
} while (0)

    f32x16 V1;
#pragma unroll
    for (int r = 0; r < 16; r++) V1[r] = vb1c[r];

#pragma unroll
    for (int half = 0; half < 2; half++) {
        S8 ff0, ff1;
#pragma unroll
        for (int kh = 0; kh < 2; kh++) {
            int i = kh * 2 + kg;
            float p0 = vn[i * 64 + col];
            float p1 = vn[((half ? 6 : 3) + i) * 64 + col];
            const float* w0p = axW0 + kh * 512 + lane * 8;
            const float* w1p = axW1 + kh * 512 + lane * 8;
            const float* bp  = axb  + kh * 512 + lane * 8;
            S8 f;
#pragma unroll
            for (int j = 0; j < 8; j++) {
                float x = w0p[j] * p0 + w1p[j] * p1 + bp[j];
                f.e[j] = (_Float16)fmaxf(x, 0.01f * x);
            }
            if (kh == 0) ff0 = f; else ff1 = f;
        }
        S8 cw0, cw1; cw0.v = cW1f[lane]; cw1.v = cW1f[64 + lane];
        f32x16 C = __builtin_amdgcn_mfma_f32_32x32x16_f16(cw0.h, ff0.h, zero, 0, 0, 0);
        C = __builtin_amdgcn_mfma_f32_32x32x16_f16(cw1.h, ff1.h, C, 0, 0, 0);
#pragma unroll
        for (int r = 0; r < 16; r++) { float m = C[r] + cb1c[r]; C[r] = fmaxf(m, 0.01f * m); }
        S8 hf0, hf1;
        C2FRAG(C, hf0, hf1);
        cw0.v = cW2f[lane]; cw1.v = cW2f[64 + lane];
        C = __builtin_amdgcn_mfma_f32_32x32x16_f16(cw0.h, hf0.h, zero, 0, 0, 0);
        C = __builtin_amdgcn_mfma_f32_32x32x16_f16(cw1.h, hf1.h, C, 0, 0, 0);
#pragma unroll
        for (int r = 0; r < 16; r++) { float m = C[r] + cb2c[r]; C[r] = fmaxf(m, 0.01f * m); }
        S8 cf0, cf1;
        C2FRAG(C, cf0, cf1);
        const short8* vf = half ? vW1f1 : vW1f0;
        S8 vw0, vw1; vw0.v = vf[lane]; vw1.v = vf[64 + lane];
        V1 = __builtin_amdgcn_mfma_f32_32x32x16_f16(vw0.h, cf0.h, V1, 0, 0, 0);
        V1 = __builtin_amdgcn_mfma_f32_32x32x16_f16(vw1.h, cf1.h, V1, 0, 0, 0);
    }
#pragma unroll
    for (int r = 0; r < 16; r++) V1[r] = fmaxf(V1[r], 0.01f * V1[r]);
    S8 v1f0, v1f1;
    C2FRAG(V1, v1f0, v1f1);
    S8 vw0, vw1; vw0.v = vW2f[lane]; vw1.v = vW2f[64 + lane];
    f32x16 V2 = __builtin_amdgcn_mfma_f32_32x32x16_f16(vw0.h, v1f0.h, zero, 0, 0, 0);
    V2 = __builtin_amdgcn_mfma_f32_32x32x16_f16(vw1.h, v1f1.h, V2, 0, 0, 0);
#pragma unroll
    for (int r = 0; r < 16; r++) { float m = V2[r] + vb2c[r]; V2[r] = fmaxf(m, 0.01f * m); }
    S8 vf0, vf1;
    C2FRAG(V2, vf0, vf1);

    float c0 = vn[9 * 64 + col];
    float c1 = vn[10 * 64 + col];

    S8 ea0, ea1; ea0.v = eAf[lane]; ea1.v = eAf[64 + lane];
    f32x16 SA = __builtin_amdgcn_mfma_f32_32x32x16_f16(ea0.h, vf0.h, zero, 0, 0, 0);
    SA = __builtin_amdgcn_mfma_f32_32x32x16_f16(ea1.h, vf1.h, SA, 0, 0, 0);
    {
        const float* eb = (const float*)(wpk + 24576) + lane * 16;
        const float* e2 = (const float*)(wpk + 32768) + lane * 16;
        const float* e3 = (const float*)(wpk + 36864) + lane * 16;
#pragma unroll
        for (int r = 0; r < 16; r++) SA[r] += eb[r] + e2[r] * c0 + e3[r] * c1;
    }
    S8 p0, p1;
    C2FRAG(SA, p0, p1);
    ((short8*)(Ap + (size_t)n * 2048))[bh * 64 + lane] = p0.v;
    ((short8*)(Ap + (size_t)n * 2048))[(2 + bh) * 64 + lane] = p1.v;

    S8 eb0, eb1f; eb0.v = eBf[lane]; eb1f.v = eBf[64 + lane];
    f32x16 SB = __builtin_amdgcn_mfma_f32_32x32x16_f16(eb0.h, vf0.h, zero, 0, 0, 0);
    SB = __builtin_amdgcn_mfma_f32_32x32x16_f16(eb1f.h, vf1.h, SB, 0, 0, 0);
    {
        const float* e2 = (const float*)(wpk + 40960) + lane * 16;
        const float* e3 = (const float*)(wpk + 45056) + lane * 16;
#pragma unroll
        for (int r = 0; r < 16; r++) SB[r] += e2[r] * c0 + e3[r] * c1;
    }
    C2FRAG(SB, p0, p1);
    ((short8*)(Bp + (size_t)n * 2048))[bh * 64 + lane] = p0.v;
    ((short8*)(Bp + (size_t)n * 2048))[(2 + bh) * 64 + lane] = p1.v;
#undef C2FRAG
}

// ---------------- fused edge pass: 4 waves, phase-per-wave-pair, 2-deep prefetch ----------------
#define VISITH(C0, C1, C2, C3) do {                                                       \
    S8 h10, h11;                                                                          \
    h10.h = h8lreluadd(ba0.h, C0.h);                                                      \
    h11.h = h8lreluadd(ba2.h, C2.h);                                                      \
    f32x16 d = __builtin_amdgcn_mfma_f32_32x32x16_f16(w2f0.h, h10.h, zero, 0, 0, 0);      \
    d = __builtin_amdgcn_mfma_f32_32x32x16_f16(w2f1.h, h11.h, d, 0, 0, 0);                \
    {                                                                                     \
        f32x16 m = d + b2vv;                                                              \
        acc0 = acc0 + __builtin_elementwise_max(m, m * 0.01f);                            \
    }                                                                                     \
    h10.h = h8lreluadd(ba1.h, C1.h);                                                      \
    h11.h = h8lreluadd(ba3.h, C3.h);                                                      \
    d = __builtin_amdgcn_mfma_f32_32x32x16_f16(w2f0.h, h10.h, zero, 0, 0, 0);             \
    d = __builtin_amdgcn_mfma_f32_32x32x16_f16(w2f1.h, h11.h, d, 0, 0, 0);                \
    {                                                                                     \
        f32x16 m = d + b2vv;                                                              \
        acc1 = acc1 + __builtin_elementwise_max(m, m * 0.01f);                            \
    }                                                                                     \
} while (0)

#define LOADO(P0, P1, P2, P3, idx) do {                                                   \
    int o_ = ((idx) < ADJCAP) ? adjl[idx] : (adjg[off0 + (idx)] & 1023);                  \
    const short8* op_ = ogBase + (size_t)o_ * 256;                                        \
    P0.v = op_[lane]; P1.v = op_[64 + lane];                                              \
    P2.v = op_[128 + lane]; P3.v = op_[192 + lane];                                       \
} while (0)

__global__ __launch_bounds__(256) void k_edge(
    const short* __restrict__ Apr, const short* __restrict__ Bpr,
    short* __restrict__ Apw, short* __restrict__ Bpw,
    const int* __restrict__ offs, const int* __restrict__ cntA,
    const int* __restrict__ adjg, const char* __restrict__ wpk,
    const float* __restrict__ vt, float* __restrict__ nv, float* __restrict__ fv,
    const float* __restrict__ oW2, const float* __restrict__ ob2,
    int pass0, int mode) {
    __shared__ float red[4][2112];
    __shared__ int adjl[ADJCAP];
    int n = blockIdx.x;
    int w = threadIdx.x >> 6;     // 0..3
    int lane = threadIdx.x & 63;
    int row = lane & 31, kg = lane >> 5;

    int off0 = offs[n], off1 = offs[n + 1];
    int deg = off1 - off0;
    int cA = cntA[n];

    for (int i = threadIdx.x; i < deg && i < ADJCAP; i += 256)
        adjl[i] = adjg[off0 + i] & 1023;
    __syncthreads();

    S8 w2f0, w2f1;
    w2f0.v = ((const short8*)wpk)[lane];
    w2f1.v = ((const short8*)wpk)[64 + lane];
    f32x16 b2vv;
    {
        const float4* bp4 = (const float4*)((const float*)(wpk + 12288) + lane * 16);
#pragma unroll
        for (int q = 0; q < 4; q++) {
            float4 v = bp4[q];
            b2vv[q * 4] = v.x; b2vv[q * 4 + 1] = v.y;
            b2vv[q * 4 + 2] = v.z; b2vv[q * 4 + 3] = v.w;
        }
    }

    f32x16 acc0 = {};
    f32x16 acc1 = {};
    const f32x16 zero = {};

    // waves 0,1 -> phase 0 (n is src; base=A[n], other uses B)
    // waves 2,3 -> phase 1 (n is dst; base=B[n], other uses A)
    {
        int myP = w >> 1;
        const short* basePtr = myP ? Bpr : Apr;
        const short8* ogBase = (const short8*)(myP ? Apr : Bpr);
        int lstart = myP ? cA : 0;
        int lend   = myP ? deg : cA;

        S8 ba0, ba1, ba2, ba3;
        {
            const short8* np = (const short8*)(basePtr + (size_t)n * 2048);
            ba0.v = np[lane]; ba1.v = np[64 + lane];
            ba2.v = np[128 + lane]; ba3.v = np[192 + lane];
        }

        int li = lstart + (w & 1);   // stride 2 within the phase
        S8 A0 = {}, A1 = {}, A2 = {}, A3 = {};
        S8 B0 = {}, B1 = {}, B2 = {}, B3 = {};
        if (li < lend) LOADO(A0, A1, A2, A3, li);
        if (li + 2 < lend) LOADO(B0, B1, B2, B3, li + 2);
        while (li < lend) {
            {
                int lp = li + 4;
                S8 n0 = {}, n1 = {}, n2 = {}, n3 = {};
                if (lp < lend) LOADO(n0, n1, n2, n3, lp);
                VISITH(A0, A1, A2, A3);
                A0 = n0; A1 = n1; A2 = n2; A3 = n3;
            }
            li += 2;
            if (li >= lend) break;
            {
                int lp = li + 4;
                S8 n0 = {}, n1 = {}, n2 = {}, n3 = {};
                if (lp < lend) LOADO(n0, n1, n2, n3, lp);
                VISITH(B0, B1, B2, B3);
                B0 = n0; B1 = n1; B2 = n2; B3 = n3;
            }
            li += 2;
        }
    }

    // ---- cross-wave reduce, nv update, stash new nv in red[0] as (b,oc) ----
#pragma unroll
    for (int bh = 0; bh < 2; bh++) {
        int b = bh * 32 + row;
#pragma unroll
        for (int r = 0; r < 16; r++) {
            int oc = (r & 3) + 8 * (r >> 2) + 4 * kg;
            red[w][b * 33 + oc] = bh ? acc1[r] : acc0[r];
        }
    }
    __syncthreads();

    {
        int t = threadIdx.x;
        size_t nb = (size_t)n * (NB * 32);
        float inv = (deg > 0) ? 1.f / (float)deg : 0.f;
#pragma unroll
        for (int j = 0; j < 8; j++) {
            int idx = t * 8 + j;
            int bb = idx >> 5, cc = idx & 31;
            float s;
            if (deg > 0) {
                s = (red[0][bb * 33 + cc] + red[1][bb * 33 + cc] +
                     red[2][bb * 33 + cc] + red[3][bb * 33 + cc]) * inv;
                if (!pass0) s += nv[nb + idx];
            } else {
                s = pass0 ? 0.f : nv[nb + idx];
            }
            nv[nb + idx] = s;
            red[0][bb * 33 + cc] = s;
        }
    }
    __syncthreads();

    // ---- fused node prep (waves 0,1; each owns one 32-col half) ----
    if (w < 2) {
        int bh = w;
        int lane31 = lane & 31;
        int g8 = (lane >> 5) * 8;
        float* loc = red[2 + w];
        const float* cb;
        S8 a0, a1;

        S8 xf0, xf1;
#pragma unroll
        for (int j = 0; j < 8; j++) {
            xf0.e[j] = (_Float16)red[0][(bh * 32 + lane31) * 33 + g8 + j];
            xf1.e[j] = (_Float16)red[0][(bh * 32 + lane31) * 33 + 16 + g8 + j];
        }

        if (mode == 0) {
            a0.v = ((const short8*)(wpk + 2048))[lane];
            a1.v = ((const short8*)(wpk + 2048))[64 + lane];
            f32x16 C = {};
            C = __builtin_amdgcn_mfma_f32_32x32x16_f16(a0.h, xf0.h, C, 0, 0, 0);
            C = __builtin_amdgcn_mfma_f32_32x32x16_f16(a1.h, xf1.h, C, 0, 0, 0);
            cb = (const float*)(wpk + 16384) + lane * 16;
#pragma unroll
            for (int r = 0; r < 16; r++) { float m = C[r] + cb[r]; C[r] = fmaxf(m, 0.01f * m); }
#pragma unroll
            for (int r = 0; r < 16; r++) {
                int oc = (r & 3) + 8 * (r >> 2) + 4 * kg;
                loc[lane31 * 33 + oc] = C[r];
            }
            S8 hf0, hf1;
#pragma unroll
            for (int j = 0; j < 8; j++) {
                hf0.e[j] = (_Float16)loc[lane31 * 33 + g8 + j];
                hf1.e[j] = (_Float16)loc[lane31 * 33 + 16 + g8 + j];
            }
            a0.v = ((const short8*)(wpk + 4096))[lane];
            a1.v = ((const short8*)(wpk + 4096))[64 + lane];
            f32x16 V = {};
            V = __builtin_amdgcn_mfma_f32_32x32x16_f16(a0.h, hf0.h, V, 0, 0, 0);
            V = __builtin_amdgcn_mfma_f32_32x32x16_f16(a1.h, hf1.h, V, 0, 0, 0);
            cb = (const float*)(wpk + 20480) + lane * 16;
#pragma unroll
            for (int r = 0; r < 16; r++) { float m = V[r] + cb[r]; V[r] = fmaxf(m, 0.01f * m); }
#pragma unroll
            for (int r = 0; r < 16; r++) {
                int oc = (r & 3) + 8 * (r >> 2) + 4 * kg;
                loc[lane31 * 33 + oc] = V[r];
            }
            S8 vf0, vf1;
#pragma unroll
            for (int j = 0; j < 8; j++) {
                vf0.e[j] = (_Float16)loc[lane31 * 33 + g8 + j];
                vf1.e[j] = (_Float16)loc[lane31 * 33 + 16 + g8 + j];
            }
            float c0 = vt[(size_t)n * 704 + 9 * 64 + bh * 32 + lane31];
            float c1 = vt[(size_t)n * 704 + 10 * 64 + bh * 32 + lane31];

            a0.v = ((const short8*)(wpk + 6144))[lane];
            a1.v = ((const short8*)(wpk + 6144))[64 + lane];
            f32x16 SA = {};
            SA = __builtin_amdgcn_mfma_f32_32x32x16_f16(a0.h, vf0.h, SA, 0, 0, 0);
            SA = __builtin_amdgcn_mfma_f32_32x32x16_f16(a1.h, vf1.h, SA, 0, 0, 0);
            {
                const float* eb = (const float*)(wpk + 24576) + lane * 16;
                const float* e2 = (const float*)(wpk + 32768) + lane * 16;
                const float* e3 = (const float*)(wpk + 36864) + lane * 16;
#pragma unroll
                for (int r = 0; r < 16; r++) SA[r] += eb[r] + e2[r] * c0 + e3[r] * c1;
            }
#pragma unroll
            for (int r = 0; r < 16; r++) {
                int oc = (r & 3) + 8 * (r >> 2) + 4 * kg;
                loc[lane31 * 33 + oc] = SA[r];
            }
            {
                S8 p0, p1;
#pragma unroll
                for (int j = 0; j < 8; j++) {
                    p0.e[j] = (_Float16)loc[lane31 * 33 + g8 + j];
                    p1.e[j] = (_Float16)loc[lane31 * 33 + 16 + g8 + j];
                }
                ((short8*)(Apw + (size_t)n * 2048))[bh * 64 + lane] = p0.v;
                ((short8*)(Apw + (size_t)n * 2048))[(2 + bh) * 64 + lane] = p1.v;
            }
            a0.v = ((const short8*)(wpk + 8192))[lane];
            a1.v = ((const short8*)(wpk + 8192))[64 + lane];
            f32x16 SB = {};
            SB = __builtin_amdgcn_mfma_f32_32x32x16_f16(a0.h, vf0.h, SB, 0, 0, 0);
            SB = __builtin_amdgcn_mfma_f32_32x32x16_f16(a1.h, vf1.h, SB, 0, 0, 0);
            {
                const float* e2 = (const float*)(wpk + 40960) + lane * 16;
                const float* e3 = (const float*)(wpk + 45056) + lane * 16;
#pragma unroll
                for (int r = 0; r < 16; r++) SB[r] += e2[r] * c0 + e3[r] * c1;
            }
#pragma unroll
            for (int r = 0; r < 16; r++) {
                int oc = (r & 3) + 8 * (r >> 2) + 4 * kg;
                loc[lane31 * 33 + oc] = SB[r];
            }
            {
                S8 p0, p1;
#pragma unroll
                for (int j = 0; j < 8; j++) {
                    p0.e[j] = (_Float16)loc[lane31 * 33 + g8 + j];
                    p1.e[j] = (_Float16)loc[lane31 * 33 + 16 + g8 + j];
                }
                ((short8*)(Bpw + (size_t)n * 2048))[bh * 64 + lane] = p0.v;
                ((short8*)(Bpw + (size_t)n * 2048))[(2 + bh) * 64 + lane] = p1.v;
            }
        } else {
            a0.v = ((const short8*)(wpk + 10240))[lane];
            a1.v = ((const short8*)(wpk + 10240))[64 + lane];
            f32x16 C = {};
            C = __builtin_amdgcn_mfma_f32_32x32x16_f16(a0.h, xf0.h, C, 0, 0, 0);
            C = __builtin_amdgcn_mfma_f32_32x32x16_f16(a1.h, xf1.h, C, 0, 0, 0);
            cb = (const float*)(wpk + 28672) + lane * 16;
#pragma unroll
            for (int r = 0; r < 16; r++) { float m = C[r] + cb[r]; C[r] = fmaxf(m, 0.01f * m); }
#pragma unroll
            for (int r = 0; r < 16; r++) {
                int oc = (r & 3) + 8 * (r >> 2) + 4 * kg;
                loc[lane31 * 33 + oc] = C[r];
            }
            float s = 0.f;
#pragma unroll
            for (int o = 0; o < 16; o++) {
                int oc = (lane >> 5) * 16 + o;
                s += oW2[oc] * loc[lane31 * 33 + oc];
            }
            s += __shfl_xor(s, 32);
            if (lane < 32) {
                float v = s + ob2[0];
                fv[n * 64 + bh * 32 + lane31] = fmaxf(v, 0.01f * v);
            }
        }
    }
}

// ---------------- final reduce over nodes ----------------
__global__ void k_final2(const float* __restrict__ fv, const float* __restrict__ gW,
                         const float* __restrict__ gb, float* __restrict__ out) {
    int b = blockIdx.x;
    int t = threadIdx.x;
    float part = 0.f;
    for (int n = t; n < NN; n += 256) part += fv[n * 64 + b] * gW[n];
    __shared__ float rs[256];
    rs[t] = part;
    __syncthreads();
    for (int d = 128; d > 0; d >>= 1) {
        if (t < d) rs[t] += rs[t + d];
        __syncthreads();
    }
    if (t == 0) out[b] = 1.f / (1.f + expf(-(rs[0] + gb[0])));
}

extern "C" void kernel_launch(void* const* d_in, const int* in_sizes, int n_in,
                              void* d_out, int out_size, void* d_ws, size_t ws_size,
                              hipStream_t stream) {
    (void)in_sizes; (void)n_in; (void)out_size; (void)ws_size;
    const float* vert = (const float*)d_in[0];
    const int* edges  = (const int*)d_in[1];
    const float* xW   = (const float*)d_in[2];
    const float* xb   = (const float*)d_in[3];
    const float* yW   = (const float*)d_in[4];
    const float* yb   = (const float*)d_in[5];
    const float* tW   = (const float*)d_in[6];
    const float* tb   = (const float*)d_in[7];
    const float* cW1  = (const float*)d_in[8];
    const float* cb1  = (const float*)d_in[9];
    const float* cW2  = (const float*)d_in[10];
    const float* cb2  = (const float*)d_in[11];
    const float* vW1  = (const float*)d_in[12];
    const float* vb1  = (const float*)d_in[13];
    const float* vW2  = (const float*)d_in[14];
    const float* vb2  = (const float*)d_in[15];
    const float* eW1  = (const float*)d_in[16];
    const float* eb1  = (const float*)d_in[17];
    const float* eW2  = (const float*)d_in[18];
    const float* eb2  = (const float*)d_in[19];
    const float* aW1  = (const float*)d_in[20];
    const float* ab1  = (const float*)d_in[21];
    const float* aW2  = (const float*)d_in[22];
    const float* ab2  = (const float*)d_in[23];
    const float* oW1  = (const float*)d_in[24];
    const float* ob1  = (const float*)d_in[25];
    const float* oW2  = (const float*)d_in[26];
    const float* ob2  = (const float*)d_in[27];
    const float* gW   = (const float*)d_in[28];
    const float* gb   = (const float*)d_in[29];
    float* out = (float*)d_out;

    char* w = (char*)d_ws;
    short* ApA = (short*)(w + 0);
    short* BpA = (short*)(w + (4u << 20));
    short* ApB = (short*)(w + (8u << 20));
    short* BpB = (short*)(w + (12u << 20));
    float* nv  = (float*)(w + (16u << 20));
    float* vt  = (float*)(w + (25u << 20));
    float* fv  = (float*)(w + (28u << 20));
    char*  wpk = w + (28u << 20) + (512u << 10);       // 128 KB
    int* deg    = (int*)(w + (29u << 20));
    int* offs   = deg + 1024;
    int* cursor = offs + 1024;
    int* cntA   = cursor + 1024;
    int* adj    = cntA + 1024;

    k_tr<<<NN / 4, 256, 0, stream>>>(vert, vt, deg);
    k_deg<<<(NE + 255) / 256, 256, 0, stream>>>(edges, deg);
    k_scan<<<1, 1024, 0, stream>>>(deg, offs, cursor);
    k_fillA<<<(NE + 255) / 256, 256, 0, stream>>>(edges, cursor, adj);
    k_sort<<<NN / 4, 256, 0, stream>>>(offs, adj, cntA);
    k_wsetup2<<<1, 64, 0, stream>>>(eW2, eb2, aW1, ab1, aW2, ab2, eW1, eb1, oW1, ob1,
                                    xW, xb, yW, yb, tW, tb, cW1, cb1, cW2, cb2,
                                    vW1, vb1, vW2, vb2, wpk);

    k_prep0f<<<NN / 2, 256, 0, stream>>>(vt, wpk, ApA, BpA);

    short* bufs[2][2] = {{ApA, BpA}, {ApB, BpB}};
    for (int p = 0; p < 6; p++) {
        int rb = p & 1, wb = rb ^ 1;
        int mode = (p == 5) ? 1 : 0;
        int pass0 = (p == 0) ? 1 : 0;
        k_edge<<<NN, 256, 0, stream>>>(bufs[rb][0], bufs[rb][1],
                                       bufs[wb][0], bufs[wb][1],
                                       offs, cntA, adj, wpk, vt, nv, fv,
                                       oW2, ob2, pass0, mode);
    }

    k_final2<<<NB, 256, 0, stream>>>(fv, gW, gb, out);
}

// Round 14
// 268.962 us; speedup vs baseline: 12.0490x; 1.0707x over previous
//
#include <hip/hip_runtime.h>
#include <hip/hip_fp16.h>
#include <cstdint>
#include <cstddef>

#define NB 64      // batch
#define NN 1000    // nodes
#define NE 16000   // edges
#define ADJCAP 256

typedef __attribute__((ext_vector_type(8))) short short8;
typedef __attribute__((ext_vector_type(8))) _Float16 half8;
typedef __attribute__((ext_vector_type(16))) float f32x16;

__device__ __forceinline__ float lrelu(float x) { return fmaxf(x, 0.01f * x); }

union S8 { short8 v; half8 h; _Float16 e[8]; unsigned int u[4]; };

// packed fp16 lrelu(a+b) on 8 lanes: lowers to v_pk_add/mul/max_f16
__device__ __forceinline__ half8 h8lreluadd(half8 a, half8 b) {
    half8 x = a + b;
    half8 y = x * (_Float16)0.01f;
    return __builtin_elementwise_max(x, y);
}

// Fragment layout per node (2048 fp16 = 4KB):
//   value (k 0..31, b 0..63): fragment f=kh*2+bh; short8 index = n*256 + f*64 + lane
//   lane holds k=kh*16+(lane>>5)*8+j, b=bh*32+(lane&31)
// C layout (32x32 mfma): col=lane&31, row(r)=(r&3)+8*(r>>2)+4*(lane>>5)

// wpk byte offsets:
//  0 W2f | 2048 aW1f | 4096 aW2f | 6144 eAf | 8192 eBf | 10240 vo1f
//  12288 B2f | 16384 aB1c | 20480 aB2c | 24576 eB1c | 28672 vo1bc
//  32768 Ea32 | 36864 Ea33 | 40960 Eb32 | 45056 Eb33
//  49152 cW1f | 51200 cW2f | 53248 vW1h0f | 55296 vW1h1f | 57344 vW2f
//  59392 axW0 | 63488 axW1 | 67584 axb
//  71680 cb1c | 75776 cb2c | 79872 vb1c | 83968 vb2c

// ---------------- vert transpose + deg zero ----------------
__global__ void k_tr(const float* __restrict__ vert, float* __restrict__ vt,
                     int* __restrict__ deg) {
    __shared__ float s[2816];
    int n0 = blockIdx.x * 4;
    int t = threadIdx.x;
    if (blockIdx.x == 0)
        for (int i = t; i < 1024; i += 256) deg[i] = 0;
    int b = t >> 2, r = t & 3;
    const float* vp = vert + ((size_t)b * NN + n0 + r) * 11;
#pragma unroll
    for (int i = 0; i < 11; i++) s[r * 704 + i * 64 + b] = vp[i];
    __syncthreads();
    float* o = vt + (size_t)n0 * 704;
#pragma unroll
    for (int j = 0; j < 11; j++) o[j * 256 + t] = s[j * 256 + t];
}

// ---------------- CSR build ----------------
__global__ void k_deg(const int* __restrict__ edges, int* __restrict__ deg) {
    int e = blockIdx.x * 256 + threadIdx.x;
    if (e < NE) {
        atomicAdd(&deg[edges[e]], 1);
        atomicAdd(&deg[edges[NE + e]], 1);
    }
}

__global__ void k_scan(const int* __restrict__ deg, int* __restrict__ offs,
                       int* __restrict__ cursor) {
    __shared__ int s[1024];
    int t = threadIdx.x;
    int d = (t < NN) ? deg[t] : 0;
    s[t] = d;
    __syncthreads();
    for (int k = 1; k < 1024; k <<= 1) {
        int v = (t >= k) ? s[t - k] : 0;
        __syncthreads();
        s[t] += v;
        __syncthreads();
    }
    if (t < NN) {
        offs[t + 1] = s[t];
        cursor[t] = s[t] - d;
    }
    if (t == 0) offs[0] = 0;
}

__global__ void k_fillA(const int* __restrict__ edges, int* __restrict__ cursor,
                        int* __restrict__ adj) {
    int e = blockIdx.x * 256 + threadIdx.x;
    if (e < NE) {
        int s = edges[e], d = edges[NE + e];
        int p1 = atomicAdd(&cursor[s], 1);
        adj[p1] = (e << 10) | d;
        int p2 = atomicAdd(&cursor[d], 1);
        adj[p2] = (1 << 30) | (e << 10) | s;
    }
}

// wave-parallel canonical rank sort (blocks 0..249) + weight pre-pack (block 250)
__global__ void k_sortw(const int* __restrict__ offs, int* __restrict__ adj,
                        int* __restrict__ cntA,
                        const float* __restrict__ eW2, const float* __restrict__ eb2,
                        const float* __restrict__ aW1, const float* __restrict__ ab1,
                        const float* __restrict__ aW2, const float* __restrict__ ab2,
                        const float* __restrict__ eW1, const float* __restrict__ eb1,
                        const float* __restrict__ oW1, const float* __restrict__ ob1,
                        const float* __restrict__ xW, const float* __restrict__ xb,
                        const float* __restrict__ yW, const float* __restrict__ yb,
                        const float* __restrict__ tW, const float* __restrict__ tb,
                        const float* __restrict__ cW1, const float* __restrict__ cb1,
                        const float* __restrict__ cW2, const float* __restrict__ cb2,
                        const float* __restrict__ vW1, const float* __restrict__ vb1,
                        const float* __restrict__ vW2, const float* __restrict__ vb2,
                        char* __restrict__ wpk) {
    if (blockIdx.x == NN / 4) {
        // ---- weight pre-pack, one wave ----
        int l = threadIdx.x;
        if (l >= 64) return;
        int row = l & 31, kg = l >> 5;

        auto packAK = [&](const float* W, int ldw, int coff, int K, short8* dst) {
#pragma unroll
            for (int kh = 0; kh < 2; kh++) {
                S8 a;
#pragma unroll
                for (int j = 0; j < 8; j++) {
                    int k = kh * 16 + kg * 8 + j;
                    a.e[j] = (k < K) ? (_Float16)W[row * ldw + coff + k] : (_Float16)0.f;
                }
                dst[kh * 64 + l] = a.v;
            }
        };
        packAK(eW2, 32, 0, 32, (short8*)(wpk + 0));
        packAK(aW1, 32, 0, 32, (short8*)(wpk + 2048));
        packAK(aW2, 32, 0, 32, (short8*)(wpk + 4096));
        packAK(eW1, 68, 0, 32, (short8*)(wpk + 6144));
        packAK(eW1, 68, 34, 32, (short8*)(wpk + 8192));
        packAK(oW1, 32, 0, 32, (short8*)(wpk + 10240));
        packAK(cW1, 24, 0, 24, (short8*)(wpk + 49152));
        packAK(cW2, 32, 0, 32, (short8*)(wpk + 51200));
        packAK(vW1, 64, 0, 32, (short8*)(wpk + 53248));
        packAK(vW1, 64, 32, 32, (short8*)(wpk + 55296));
        packAK(vW2, 32, 0, 32, (short8*)(wpk + 57344));

        float* B2f   = (float*)(wpk + 12288);
        float* aB1c  = (float*)(wpk + 16384);
        float* aB2c  = (float*)(wpk + 20480);
        float* eB1c  = (float*)(wpk + 24576);
        float* vo1bc = (float*)(wpk + 28672);
        float* Ea32  = (float*)(wpk + 32768);
        float* Ea33  = (float*)(wpk + 36864);
        float* Eb32  = (float*)(wpk + 40960);
        float* Eb33  = (float*)(wpk + 45056);
        float* cb1c  = (float*)(wpk + 71680);
        float* cb2c  = (float*)(wpk + 75776);
        float* vb1c  = (float*)(wpk + 79872);
        float* vb2c  = (float*)(wpk + 83968);
#pragma unroll
        for (int r = 0; r < 16; r++) {
            int rr = (r & 3) + 8 * (r >> 2) + 4 * kg;
            B2f[l * 16 + r]   = eb2[rr];
            aB1c[l * 16 + r]  = ab1[rr];
            aB2c[l * 16 + r]  = ab2[rr];
            eB1c[l * 16 + r]  = eb1[rr];
            vo1bc[l * 16 + r] = ob1[rr];
            Ea32[l * 16 + r]  = eW1[rr * 68 + 32];
            Ea33[l * 16 + r]  = eW1[rr * 68 + 33];
            Eb32[l * 16 + r]  = eW1[rr * 68 + 66];
            Eb33[l * 16 + r]  = eW1[rr * 68 + 67];
            cb1c[l * 16 + r]  = cb1[rr];
            cb2c[l * 16 + r]  = cb2[rr];
            vb1c[l * 16 + r]  = vb1[rr];
            vb2c[l * 16 + r]  = vb2[rr];
        }

        float* axW0 = (float*)(wpk + 59392);
        float* axW1 = (float*)(wpk + 63488);
        float* axb  = (float*)(wpk + 67584);
#pragma unroll
        for (int kh = 0; kh < 2; kh++) {
#pragma unroll
            for (int j = 0; j < 8; j++) {
                int k = kh * 16 + kg * 8 + j;
                int i = k >> 3, c = k & 7;
                float w0 = 0.f, w1 = 0.f, bb = 0.f;
                if (i < 3) {
                    const float* W = (i == 0) ? xW : ((i == 1) ? yW : tW);
                    const float* B = (i == 0) ? xb : ((i == 1) ? yb : tb);
                    w0 = W[c * 2]; w1 = W[c * 2 + 1]; bb = B[c];
                }
                axW0[kh * 512 + l * 8 + j] = w0;
                axW1[kh * 512 + l * 8 + j] = w1;
                axb[kh * 512 + l * 8 + j]  = bb;
            }
        }
        return;
    }

    __shared__ int keys[4][ADJCAP];
    int w = threadIdx.x >> 6;
    int lane = threadIdx.x & 63;
    int n = blockIdx.x * 4 + w;
    int o0 = offs[n], o1 = offs[n + 1];
    int deg = o1 - o0;
    int cap = (deg < ADJCAP) ? deg : ADJCAP;
    for (int i = lane; i < cap; i += 64) keys[w][i] = adj[o0 + i];
    __syncthreads();
    if (deg <= ADJCAP) {
        for (int i = lane; i < deg; i += 64) {
            int k = keys[w][i];
            int r = 0;
            for (int j = 0; j < deg; j++) r += (keys[w][j] < k) ? 1 : 0;
            adj[o0 + r] = k;
        }
        if (lane == 0) {
            int c = 0;
            for (int j = 0; j < deg; j++) c += ((keys[w][j] >> 30) & 1) ? 0 : 1;
            cntA[n] = c;
        }
    } else if (lane == 0) {
        for (int i = o0 + 1; i < o1; i++) {
            int key = adj[i];
            int j = i - 1;
            while (j >= o0 && adj[j] > key) { adj[j + 1] = adj[j]; j--; }
            adj[j + 1] = key;
        }
        int c = 0;
        for (int i = o0; i < o1; i++) c += ((adj[i] >> 30) & 1) ? 0 : 1;
        cntA[n] = c;
    }
}

// ---------------- MFMA pass-0 prep: 1 wave per (node, batch-half) ----------------
__global__ __launch_bounds__(256) void k_prep0f(
    const float* __restrict__ vt, const char* __restrict__ wpk,
    short* __restrict__ Ap, short* __restrict__ Bp) {
    __shared__ float loc4[4][1056];
    int w = threadIdx.x >> 6;
    int lane = threadIdx.x & 63;
    int lane31 = lane & 31, kg = lane >> 5, g8 = kg * 8;
    int n = blockIdx.x * 2 + (w >> 1);
    int bh = w & 1;
    int col = bh * 32 + lane31;
    float* loc = loc4[w];
    const float* vn = vt + (size_t)n * 704;

    const short8* cW1f = (const short8*)(wpk + 49152);
    const short8* cW2f = (const short8*)(wpk + 51200);
    const short8* vW1f0 = (const short8*)(wpk + 53248);
    const short8* vW1f1 = (const short8*)(wpk + 55296);
    const short8* vW2f = (const short8*)(wpk + 57344);
    const short8* eAf = (const short8*)(wpk + 6144);
    const short8* eBf = (const short8*)(wpk + 8192);
    const float* axW0 = (const float*)(wpk + 59392);
    const float* axW1 = (const float*)(wpk + 63488);
    const float* axb  = (const float*)(wpk + 67584);
    const float* cb1c = (const float*)(wpk + 71680) + lane * 16;
    const float* cb2c = (const float*)(wpk + 75776) + lane * 16;
    const float* vb1c = (const float*)(wpk + 79872) + lane * 16;
    const float* vb2c = (const float*)(wpk + 83968) + lane * 16;

    const f32x16 zero = {};

#define C2FRAG(Creg, F0, F1) do {                                              \
    _Pragma("unroll") for (int r = 0; r < 16; r++)                             \
        loc[lane31 * 33 + ((r & 3) + 8 * (r >> 2) + 4 * kg)] = Creg[r];        \
    _Pragma("unroll") for (int j = 0; j < 8; j++) {                            \
        F0.e[j] = (_Float16)loc[lane31 * 33 + g8 + j];                         \
        F1.e[j] = (_Float16)loc[lane31 * 33 + 16 + g8 + j]; }                  \
} while (0)

    f32x16 V1;
#pragma unroll
    for (int r = 0; r < 16; r++) V1[r] = vb1c[r];

#pragma unroll
    for (int half = 0; half < 2; half++) {
        S8 ff0, ff1;
#pragma unroll
        for (int kh = 0; kh < 2; kh++) {
            int i = kh * 2 + kg;
            float p0 = vn[i * 64 + col];
            float p1 = vn[((half ? 6 : 3) + i) * 64 + col];
            const float* w0p = axW0 + kh * 512 + lane * 8;
            const float* w1p = axW1 + kh * 512 + lane * 8;
            const float* bp  = axb  + kh * 512 + lane * 8;
            S8 f;
#pragma unroll
            for (int j = 0; j < 8; j++) {
                float x = w0p[j] * p0 + w1p[j] * p1 + bp[j];
                f.e[j] = (_Float16)fmaxf(x, 0.01f * x);
            }
            if (kh == 0) ff0 = f; else ff1 = f;
        }
        S8 cw0, cw1; cw0.v = cW1f[lane]; cw1.v = cW1f[64 + lane];
        f32x16 C = __builtin_amdgcn_mfma_f32_32x32x16_f16(cw0.h, ff0.h, zero, 0, 0, 0);
        C = __builtin_amdgcn_mfma_f32_32x32x16_f16(cw1.h, ff1.h, C, 0, 0, 0);
#pragma unroll
        for (int r = 0; r < 16; r++) { float m = C[r] + cb1c[r]; C[r] = fmaxf(m, 0.01f * m); }
        S8 hf0, hf1;
        C2FRAG(C, hf0, hf1);
        cw0.v = cW2f[lane]; cw1.v = cW2f[64 + lane];
        C = __builtin_amdgcn_mfma_f32_32x32x16_f16(cw0.h, hf0.h, zero, 0, 0, 0);
        C = __builtin_amdgcn_mfma_f32_32x32x16_f16(cw1.h, hf1.h, C, 0, 0, 0);
#pragma unroll
        for (int r = 0; r < 16; r++) { float m = C[r] + cb2c[r]; C[r] = fmaxf(m, 0.01f * m); }
        S8 cf0, cf1;
        C2FRAG(C, cf0, cf1);
        const short8* vf = half ? vW1f1 : vW1f0;
        S8 vw0, vw1; vw0.v = vf[lane]; vw1.v = vf[64 + lane];
        V1 = __builtin_amdgcn_mfma_f32_32x32x16_f16(vw0.h, cf0.h, V1, 0, 0, 0);
        V1 = __builtin_amdgcn_mfma_f32_32x32x16_f16(vw1.h, cf1.h, V1, 0, 0, 0);
    }
#pragma unroll
    for (int r = 0; r < 16; r++) V1[r] = fmaxf(V1[r], 0.01f * V1[r]);
    S8 v1f0, v1f1;
    C2FRAG(V1, v1f0, v1f1);
    S8 vw0, vw1; vw0.v = vW2f[lane]; vw1.v = vW2f[64 + lane];
    f32x16 V2 = __builtin_amdgcn_mfma_f32_32x32x16_f16(vw0.h, v1f0.h, zero, 0, 0, 0);
    V2 = __builtin_amdgcn_mfma_f32_32x32x16_f16(vw1.h, v1f1.h, V2, 0, 0, 0);
#pragma unroll
    for (int r = 0; r < 16; r++) { float m = V2[r] + vb2c[r]; V2[r] = fmaxf(m, 0.01f * m); }
    S8 vf0, vf1;
    C2FRAG(V2, vf0, vf1);

    float c0 = vn[9 * 64 + col];
    float c1 = vn[10 * 64 + col];

    S8 ea0, ea1; ea0.v = eAf[lane]; ea1.v = eAf[64 + lane];
    f32x16 SA = __builtin_amdgcn_mfma_f32_32x32x16_f16(ea0.h, vf0.h, zero, 0, 0, 0);
    SA = __builtin_amdgcn_mfma_f32_32x32x16_f16(ea1.h, vf1.h, SA, 0, 0, 0);
    {
        const float* eb = (const float*)(wpk + 24576) + lane * 16;
        const float* e2 = (const float*)(wpk + 32768) + lane * 16;
        const float* e3 = (const float*)(wpk + 36864) + lane * 16;
#pragma unroll
        for (int r = 0; r < 16; r++) SA[r] += eb[r] + e2[r] * c0 + e3[r] * c1;
    }
    S8 p0, p1;
    C2FRAG(SA, p0, p1);
    ((short8*)(Ap + (size_t)n * 2048))[bh * 64 + lane] = p0.v;
    ((short8*)(Ap + (size_t)n * 2048))[(2 + bh) * 64 + lane] = p1.v;

    S8 eb0, eb1f; eb0.v = eBf[lane]; eb1f.v = eBf[64 + lane];
    f32x16 SB = __builtin_amdgcn_mfma_f32_32x32x16_f16(eb0.h, vf0.h, zero, 0, 0, 0);
    SB = __builtin_amdgcn_mfma_f32_32x32x16_f16(eb1f.h, vf1.h, SB, 0, 0, 0);
    {
        const float* e2 = (const float*)(wpk + 40960) + lane * 16;
        const float* e3 = (const float*)(wpk + 45056) + lane * 16;
#pragma unroll
        for (int r = 0; r < 16; r++) SB[r] += e2[r] * c0 + e3[r] * c1;
    }
    C2FRAG(SB, p0, p1);
    ((short8*)(Bp + (size_t)n * 2048))[bh * 64 + lane] = p0.v;
    ((short8*)(Bp + (size_t)n * 2048))[(2 + bh) * 64 + lane] = p1.v;
#undef C2FRAG
}

// ---------------- fused edge pass: 4 waves, phase-per-wave-pair, 3-deep prefetch ----------------
#define VISITH(C0, C1, C2, C3) do {                                                       \
    S8 h10, h11;                                                                          \
    h10.h = h8lreluadd(ba0.h, C0.h);                                                      \
    h11.h = h8lreluadd(ba2.h, C2.h);                                                      \
    f32x16 d = __builtin_amdgcn_mfma_f32_32x32x16_f16(w2f0.h, h10.h, zero, 0, 0, 0);      \
    d = __builtin_amdgcn_mfma_f32_32x32x16_f16(w2f1.h, h11.h, d, 0, 0, 0);                \
    {                                                                                     \
        f32x16 m = d + b2vv;                                                              \
        acc0 = acc0 + __builtin_elementwise_max(m, m * 0.01f);                            \
    }                                                                                     \
    h10.h = h8lreluadd(ba1.h, C1.h);                                                      \
    h11.h = h8lreluadd(ba3.h, C3.h);                                                      \
    d = __builtin_amdgcn_mfma_f32_32x32x16_f16(w2f0.h, h10.h, zero, 0, 0, 0);             \
    d = __builtin_amdgcn_mfma_f32_32x32x16_f16(w2f1.h, h11.h, d, 0, 0, 0);                \
    {                                                                                     \
        f32x16 m = d + b2vv;                                                              \
        acc1 = acc1 + __builtin_elementwise_max(m, m * 0.01f);                            \
    }                                                                                     \
} while (0)

#define LOADO(P0, P1, P2, P3, idx) do {                                                   \
    int o_ = ((idx) < ADJCAP) ? adjl[idx] : (adjg[off0 + (idx)] & 1023);                  \
    const short8* op_ = ogBase + (size_t)o_ * 256;                                        \
    P0.v = op_[lane]; P1.v = op_[64 + lane];                                              \
    P2.v = op_[128 + lane]; P3.v = op_[192 + lane];                                       \
} while (0)

__global__ __launch_bounds__(256) void k_edge(
    const short* __restrict__ Apr, const short* __restrict__ Bpr,
    short* __restrict__ Apw, short* __restrict__ Bpw,
    const int* __restrict__ offs, const int* __restrict__ cntA,
    const int* __restrict__ adjg, const char* __restrict__ wpk,
    const float* __restrict__ vt, float* __restrict__ nv, float* __restrict__ fv,
    const float* __restrict__ oW2, const float* __restrict__ ob2,
    int pass0, int mode) {
    __shared__ float red[4][2112];
    __shared__ int adjl[ADJCAP];
    int n = blockIdx.x;
    int w = threadIdx.x >> 6;     // 0..3
    int lane = threadIdx.x & 63;
    int row = lane & 31, kg = lane >> 5;

    int off0 = offs[n], off1 = offs[n + 1];
    int deg = off1 - off0;
    int cA = cntA[n];

    for (int i = threadIdx.x; i < deg && i < ADJCAP; i += 256)
        adjl[i] = adjg[off0 + i] & 1023;
    __syncthreads();

    S8 w2f0, w2f1;
    w2f0.v = ((const short8*)wpk)[lane];
    w2f1.v = ((const short8*)wpk)[64 + lane];
    f32x16 b2vv;
    {
        const float4* bp4 = (const float4*)((const float*)(wpk + 12288) + lane * 16);
#pragma unroll
        for (int q = 0; q < 4; q++) {
            float4 v = bp4[q];
            b2vv[q * 4] = v.x; b2vv[q * 4 + 1] = v.y;
            b2vv[q * 4 + 2] = v.z; b2vv[q * 4 + 3] = v.w;
        }
    }

    f32x16 acc0 = {};
    f32x16 acc1 = {};
    const f32x16 zero = {};

    // waves 0,1 -> phase 0 (n is src; base=A[n], other uses B)
    // waves 2,3 -> phase 1 (n is dst; base=B[n], other uses A)
    {
        int myP = w >> 1;
        const short* basePtr = myP ? Bpr : Apr;
        const short8* ogBase = (const short8*)(myP ? Apr : Bpr);
        int lstart = myP ? cA : 0;
        int lend   = myP ? deg : cA;

        S8 ba0, ba1, ba2, ba3;
        {
            const short8* np = (const short8*)(basePtr + (size_t)n * 2048);
            ba0.v = np[lane]; ba1.v = np[64 + lane];
            ba2.v = np[128 + lane]; ba3.v = np[192 + lane];
        }

        int li = lstart + (w & 1);   // stride 2 within the phase
        S8 A0 = {}, A1 = {}, A2 = {}, A3 = {};
        S8 B0 = {}, B1 = {}, B2 = {}, B3 = {};
        S8 C0 = {}, C1 = {}, C2 = {}, C3 = {};
        if (li < lend) LOADO(A0, A1, A2, A3, li);
        if (li + 2 < lend) LOADO(B0, B1, B2, B3, li + 2);
        if (li + 4 < lend) LOADO(C0, C1, C2, C3, li + 4);
        while (li < lend) {
            {
                int lp = li + 6;
                S8 n0 = {}, n1 = {}, n2 = {}, n3 = {};
                if (lp < lend) LOADO(n0, n1, n2, n3, lp);
                VISITH(A0, A1, A2, A3);
                A0 = n0; A1 = n1; A2 = n2; A3 = n3;
            }
            li += 2;
            if (li >= lend) break;
            {
                int lp = li + 6;
                S8 n0 = {}, n1 = {}, n2 = {}, n3 = {};
                if (lp < lend) LOADO(n0, n1, n2, n3, lp);
                VISITH(B0, B1, B2, B3);
                B0 = n0; B1 = n1; B2 = n2; B3 = n3;
            }
            li += 2;
            if (li >= lend) break;
            {
                int lp = li + 6;
                S8 n0 = {}, n1 = {}, n2 = {}, n3 = {};
                if (lp < lend) LOADO(n0, n1, n2, n3, lp);
                VISITH(C0, C1, C2, C3);
                C0 = n0; C1 = n1; C2 = n2; C3 = n3;
            }
            li += 2;
        }
    }

    // ---- cross-wave reduce, nv update, stash new nv in red[0] as (b,oc) ----
#pragma unroll
    for (int bh = 0; bh < 2; bh++) {
        int b = bh * 32 + row;
#pragma unroll
        for (int r = 0; r < 16; r++) {
            int oc = (r & 3) + 8 * (r >> 2) + 4 * kg;
            red[w][b * 33 + oc] = bh ? acc1[r] : acc0[r];
        }
    }
    __syncthreads();

    {
        int t = threadIdx.x;
        size_t nb = (size_t)n * (NB * 32);
        float inv = (deg > 0) ? 1.f / (float)deg : 0.f;
#pragma unroll
        for (int j = 0; j < 8; j++) {
            int idx = t * 8 + j;
            int bb = idx >> 5, cc = idx & 31;
            float s;
            if (deg > 0) {
                s = (red[0][bb * 33 + cc] + red[1][bb * 33 + cc] +
                     red[2][bb * 33 + cc] + red[3][bb * 33 + cc]) * inv;
                if (!pass0) s += nv[nb + idx];
            } else {
                s = pass0 ? 0.f : nv[nb + idx];
            }
            nv[nb + idx] = s;
            red[0][bb * 33 + cc] = s;
        }
    }
    __syncthreads();

    // ---- fused node prep (waves 0,1; each owns one 32-col half) ----
    if (w < 2) {
        int bh = w;
        int lane31 = lane & 31;
        int g8 = (lane >> 5) * 8;
        float* loc = red[2 + w];
        const float* cb;
        S8 a0, a1;

        S8 xf0, xf1;
#pragma unroll
        for (int j = 0; j < 8; j++) {
            xf0.e[j] = (_Float16)red[0][(bh * 32 + lane31) * 33 + g8 + j];
            xf1.e[j] = (_Float16)red[0][(bh * 32 + lane31) * 33 + 16 + g8 + j];
        }

        if (mode == 0) {
            a0.v = ((const short8*)(wpk + 2048))[lane];
            a1.v = ((const short8*)(wpk + 2048))[64 + lane];
            f32x16 C = {};
            C = __builtin_amdgcn_mfma_f32_32x32x16_f16(a0.h, xf0.h, C, 0, 0, 0);
            C = __builtin_amdgcn_mfma_f32_32x32x16_f16(a1.h, xf1.h, C, 0, 0, 0);
            cb = (const float*)(wpk + 16384) + lane * 16;
#pragma unroll
            for (int r = 0; r < 16; r++) { float m = C[r] + cb[r]; C[r] = fmaxf(m, 0.01f * m); }
#pragma unroll
            for (int r = 0; r < 16; r++) {
                int oc = (r & 3) + 8 * (r >> 2) + 4 * kg;
                loc[lane31 * 33 + oc] = C[r];
            }
            S8 hf0, hf1;
#pragma unroll
            for (int j = 0; j < 8; j++) {
                hf0.e[j] = (_Float16)loc[lane31 * 33 + g8 + j];
                hf1.e[j] = (_Float16)loc[lane31 * 33 + 16 + g8 + j];
            }
            a0.v = ((const short8*)(wpk + 4096))[lane];
            a1.v = ((const short8*)(wpk + 4096))[64 + lane];
            f32x16 V = {};
            V = __builtin_amdgcn_mfma_f32_32x32x16_f16(a0.h, hf0.h, V, 0, 0, 0);
            V = __builtin_amdgcn_mfma_f32_32x32x16_f16(a1.h, hf1.h, V, 0, 0, 0);
            cb = (const float*)(wpk + 20480) + lane * 16;
#pragma unroll
            for (int r = 0; r < 16; r++) { float m = V[r] + cb[r]; V[r] = fmaxf(m, 0.01f * m); }
#pragma unroll
            for (int r = 0; r < 16; r++) {
                int oc = (r & 3) + 8 * (r >> 2) + 4 * kg;
                loc[lane31 * 33 + oc] = V[r];
            }
            S8 vf0, vf1;
#pragma unroll
            for (int j = 0; j < 8; j++) {
                vf0.e[j] = (_Float16)loc[lane31 * 33 + g8 + j];
                vf1.e[j] = (_Float16)loc[lane31 * 33 + 16 + g8 + j];
            }
            float c0 = vt[(size_t)n * 704 + 9 * 64 + bh * 32 + lane31];
            float c1 = vt[(size_t)n * 704 + 10 * 64 + bh * 32 + lane31];

            a0.v = ((const short8*)(wpk + 6144))[lane];
            a1.v = ((const short8*)(wpk + 6144))[64 + lane];
            f32x16 SA = {};
            SA = __builtin_amdgcn_mfma_f32_32x32x16_f16(a0.h, vf0.h, SA, 0, 0, 0);
            SA = __builtin_amdgcn_mfma_f32_32x32x16_f16(a1.h, vf1.h, SA, 0, 0, 0);
            {
                const float* eb = (const float*)(wpk + 24576) + lane * 16;
                const float* e2 = (const float*)(wpk + 32768) + lane * 16;
                const float* e3 = (const float*)(wpk + 36864) + lane * 16;
#pragma unroll
                for (int r = 0; r < 16; r++) SA[r] += eb[r] + e2[r] * c0 + e3[r] * c1;
            }
#pragma unroll
            for (int r = 0; r < 16; r++) {
                int oc = (r & 3) + 8 * (r >> 2) + 4 * kg;
                loc[lane31 * 33 + oc] = SA[r];
            }
            {
                S8 p0, p1;
#pragma unroll
                for (int j = 0; j < 8; j++) {
                    p0.e[j] = (_Float16)loc[lane31 * 33 + g8 + j];
                    p1.e[j] = (_Float16)loc[lane31 * 33 + 16 + g8 + j];
                }
                ((short8*)(Apw + (size_t)n * 2048))[bh * 64 + lane] = p0.v;
                ((short8*)(Apw + (size_t)n * 2048))[(2 + bh) * 64 + lane] = p1.v;
            }
            a0.v = ((const short8*)(wpk + 8192))[lane];
            a1.v = ((const short8*)(wpk + 8192))[64 + lane];
            f32x16 SB = {};
            SB = __builtin_amdgcn_mfma_f32_32x32x16_f16(a0.h, vf0.h, SB, 0, 0, 0);
            SB = __builtin_amdgcn_mfma_f32_32x32x16_f16(a1.h, vf1.h, SB, 0, 0, 0);
            {
                const float* e2 = (const float*)(wpk + 40960) + lane * 16;
                const float* e3 = (const float*)(wpk + 45056) + lane * 16;
#pragma unroll
                for (int r = 0; r < 16; r++) SB[r] += e2[r] * c0 + e3[r] * c1;
            }
#pragma unroll
            for (int r = 0; r < 16; r++) {
                int oc = (r & 3) + 8 * (r >> 2) + 4 * kg;
                loc[lane31 * 33 + oc] = SB[r];
            }
            {
                S8 p0, p1;
#pragma unroll
                for (int j = 0; j < 8; j++) {
                    p0.e[j] = (_Float16)loc[lane31 * 33 + g8 + j];
                    p1.e[j] = (_Float16)loc[lane31 * 33 + 16 + g8 + j];
                }
                ((short8*)(Bpw + (size_t)n * 2048))[bh * 64 + lane] = p0.v;
                ((short8*)(Bpw + (size_t)n * 2048))[(2 + bh) * 64 + lane] = p1.v;
            }
        } else {
            a0.v = ((const short8*)(wpk + 10240))[lane];
            a1.v = ((const short8*)(wpk + 10240))[64 + lane];
            f32x16 C = {};
            C = __builtin_amdgcn_mfma_f32_32x32x16_f16(a0.h, xf0.h, C, 0, 0, 0);
            C = __builtin_amdgcn_mfma_f32_32x32x16_f16(a1.h, xf1.h, C, 0, 0, 0);
            cb = (const float*)(wpk + 28672) + lane * 16;
#pragma unroll
            for (int r = 0; r < 16; r++) { float m = C[r] + cb[r]; C[r] = fmaxf(m, 0.01f * m); }
#pragma unroll
            for (int r = 0; r < 16; r++) {
                int oc = (r & 3) + 8 * (r >> 2) + 4 * kg;
                loc[lane31 * 33 + oc] = C[r];
            }
            float s = 0.f;
#pragma unroll
            for (int o = 0; o < 16; o++) {
                int oc = (lane >> 5) * 16 + o;
                s += oW2[oc] * loc[lane31 * 33 + oc];
            }
            s += __shfl_xor(s, 32);
            if (lane < 32) {
                float v = s + ob2[0];
                fv[n * 64 + bh * 32 + lane31] = fmaxf(v, 0.01f * v);
            }
        }
    }
}

// ---------------- final reduce over nodes ----------------
__global__ void k_final2(const float* __restrict__ fv, const float* __restrict__ gW,
                         const float* __restrict__ gb, float* __restrict__ out) {
    int b = blockIdx.x;
    int t = threadIdx.x;
    float part = 0.f;
    for (int n = t; n < NN; n += 256) part += fv[n * 64 + b] * gW[n];
    __shared__ float rs[256];
    rs[t] = part;
    __syncthreads();
    for (int d = 128; d > 0; d >>= 1) {
        if (t < d) rs[t] += rs[t + d];
        __syncthreads();
    }
    if (t == 0) out[b] = 1.f / (1.f + expf(-(rs[0] + gb[0])));
}

extern "C" void kernel_launch(void* const* d_in, const int* in_sizes, int n_in,
                              void* d_out, int out_size, void* d_ws, size_t ws_size,
                              hipStream_t stream) {
    (void)in_sizes; (void)n_in; (void)out_size; (void)ws_size;
    const float* vert = (const float*)d_in[0];
    const int* edges  = (const int*)d_in[1];
    const float* xW   = (const float*)d_in[2];
    const float* xb   = (const float*)d_in[3];
    const float* yW   = (const float*)d_in[4];
    const float* yb   = (const float*)d_in[5];
    const float* tW   = (const float*)d_in[6];
    const float* tb   = (const float*)d_in[7];
    const float* cW1  = (const float*)d_in[8];
    const float* cb1  = (const float*)d_in[9];
    const float* cW2  = (const float*)d_in[10];
    const float* cb2  = (const float*)d_in[11];
    const float* vW1  = (const float*)d_in[12];
    const float* vb1  = (const float*)d_in[13];
    const float* vW2  = (const float*)d_in[14];
    const float* vb2  = (const float*)d_in[15];
    const float* eW1  = (const float*)d_in[16];
    const float* eb1  = (const float*)d_in[17];
    const float* eW2  = (const float*)d_in[18];
    const float* eb2  = (const float*)d_in[19];
    const float* aW1  = (const float*)d_in[20];
    const float* ab1  = (const float*)d_in[21];
    const float* aW2  = (const float*)d_in[22];
    const float* ab2  = (const float*)d_in[23];
    const float* oW1  = (const float*)d_in[24];
    const float* ob1  = (const float*)d_in[25];
    const float* oW2  = (const float*)d_in[26];
    const float* ob2  = (const float*)d_in[27];
    const float* gW   = (const float*)d_in[28];
    const float* gb   = (const float*)d_in[29];
    float* out = (float*)d_out;

    char* w = (char*)d_ws;
    short* ApA = (short*)(w + 0);
    short* BpA = (short*)(w + (4u << 20));
    short* ApB = (short*)(w + (8u << 20));
    short* BpB = (short*)(w + (12u << 20));
    float* nv  = (float*)(w + (16u << 20));
    float* vt  = (float*)(w + (25u << 20));
    float* fv  = (float*)(w + (28u << 20));
    char*  wpk = w + (28u << 20) + (512u << 10);       // 128 KB
    int* deg    = (int*)(w + (29u << 20));
    int* offs   = deg + 1024;
    int* cursor = offs + 1024;
    int* cntA   = cursor + 1024;
    int* adj    = cntA + 1024;

    k_tr<<<NN / 4, 256, 0, stream>>>(vert, vt, deg);
    k_deg<<<(NE + 255) / 256, 256, 0, stream>>>(edges, deg);
    k_scan<<<1, 1024, 0, stream>>>(deg, offs, cursor);
    k_fillA<<<(NE + 255) / 256, 256, 0, stream>>>(edges, cursor, adj);
    k_sortw<<<NN / 4 + 1, 256, 0, stream>>>(offs, adj, cntA,
                                            eW2, eb2, aW1, ab1, aW2, ab2, eW1, eb1,
                                            oW1, ob1, xW, xb, yW, yb, tW, tb,
                                            cW1, cb1, cW2, cb2, vW1, vb1, vW2, vb2, wpk);

    k_prep0f<<<NN / 2, 256, 0, stream>>>(vt, wpk, ApA, BpA);

    short* bufs[2][2] = {{ApA, BpA}, {ApB, BpB}};
    for (int p = 0; p < 6; p++) {
        int rb = p & 1, wb = rb ^ 1;
        int mode = (p == 5) ? 1 : 0;
        int pass0 = (p == 0) ? 1 : 0;
        k_edge<<<NN, 256, 0, stream>>>(bufs[rb][0], bufs[rb][1],
                                       bufs[wb][0], bufs[wb][1],
                                       offs, cntA, adj, wpk, vt, nv, fv,
                                       oW2, ob2, pass0, mode);
    }

    k_final2<<<NB, 256, 0, stream>>>(fv, gW, gb, out);
}